// Round 17
// baseline (2240.535 us; speedup 1.0000x reference)
//
#include <hip/hip_runtime.h>
#include <hip/hip_bf16.h>
#include <math.h>

typedef __hip_bfloat16 bf16;
typedef __attribute__((ext_vector_type(8))) short bf16x8;   // 8 bf16 = 4 VGPR
typedef __attribute__((ext_vector_type(4))) float f32x4;
typedef long i64t;                                          // 8 fp8 = 2 VGPR

#define NW   16384
#define LC   20
#define EDIM 64
#define HC   256
#define HW   512
#define SEQ  128
#define NOUT 50
#define NWB  32      // word-kernel blocks (both dirs per block), co-resident
#define FPAD 16      // ints per flag (64B line)

// ---- fast transcendentals ----
#define LOG2E 1.4426950408889634f
__device__ __forceinline__ float fex2(float x) {
  float r; asm("v_exp_f32 %0, %1" : "=v"(r) : "v"(x)); return r;
}
__device__ __forceinline__ float frcp(float x) {
  float r; asm("v_rcp_f32 %0, %1" : "=v"(r) : "v"(x)); return r;
}
__device__ __forceinline__ float flog2(float x) {
  float r; asm("v_log_f32 %0, %1" : "=v"(r) : "v"(x)); return r;
}
__device__ __forceinline__ float fsig(float x) { return frcp(1.f + fex2(-LOG2E * x)); }
__device__ __forceinline__ float ftanh(float x) {
  return 1.f - 2.f * frcp(1.f + fex2(2.f * LOG2E * x));
}

__device__ __forceinline__ unsigned short f2bu(float f) {
  bf16 h = __float2bfloat16(f);
  return *reinterpret_cast<unsigned short*>(&h);
}
__device__ __forceinline__ bf16x8 ld8(const unsigned short* p) {
  return *reinterpret_cast<const bf16x8*>(p);
}
// Coherent (cross-XCD) plain ops: sc0 sc1 -> bypass L1+L2, hit LLC.
__device__ __forceinline__ i64t ld8sc8(const unsigned char* p) {   // 8B load
  i64t r;
  asm volatile("global_load_dwordx2 %0, %1, off sc0 sc1" : "=v"(r) : "v"(p));
  return r;
}
__device__ __forceinline__ void st8sc8(unsigned char* p, i64t v) { // 8B store
  asm volatile("global_store_dwordx2 %0, %1, off sc0 sc1" :: "v"(p), "v"(v) : "memory");
}
#define MFMA(a, b, c)  __builtin_amdgcn_mfma_f32_16x16x32_bf16(a, b, c, 0, 0, 0)
#define MFMA8(a, b, c) __builtin_amdgcn_mfma_f32_16x16x32_fp8_fp8(a, b, c, 0, 0, 0)

// ---------------------------------------------------------------------------
// Persistent char LSTM, TRANSPOSED compute, 64 words/block, 512 THREADS
// (8 waves x 2 chunks -> 2 waves/SIMD for latency hiding). c-state in LDS.
// ---------------------------------------------------------------------------
__global__ __launch_bounds__(512, 1) void char_lstm(
    const int* __restrict__ x, const unsigned short* __restrict__ embb,
    const unsigned short* __restrict__ Wc, const float* __restrict__ bcT,
    unsigned short* __restrict__ lastT, const int* __restrict__ len) {
  __shared__ unsigned short Hs[2][64][264];   // 67.6 KB
  __shared__ float Cs[256][66];               // 67.6 KB c-state
  const int tid = threadIdx.x;
  const int w = tid >> 6, l = tid & 63;       // w 0..7
  const int l16 = l & 15, lk8 = (l >> 4) * 8, q = l >> 4;
  const int w0 = blockIdx.x * 64;
  int lenw[4], lroww[4];
#pragma unroll
  for (int wh = 0; wh < 4; ++wh) {
    const int n = w0 + wh * 16 + l16;
    lenw[wh] = len[n];
    lroww[wh] = ((n & 127) * 128 + (n >> 7)) * HC;   // time-major row base
  }

  for (int t = 0; t < LC; ++t) {
    const int cur = t & 1, nxt = cur ^ 1;
    int xi[4];
#pragma unroll
    for (int wh = 0; wh < 4; ++wh) xi[wh] = x[(w0 + wh * 16 + l16) * LC + t];
#pragma unroll
    for (int c = 0; c < 2; ++c) {
      const int chg = w * 2 + c;                // chunk 0..15
      const int cc0 = chg * 64;                 // gate-col base
      f32x4 acc[4][4] = {};                     // [wh][gate]
#pragma unroll
      for (int kk = 0; kk < 2; ++kk) {          // K 0..63: embedding
        const int k = kk * 32 + lk8;
        const unsigned short* wp = Wc + (size_t)(cc0 + l16) * 320 + k;
        bf16x8 bv[4];
#pragma unroll
        for (int g = 0; g < 4; ++g) bv[g] = ld8(wp + g * 16 * 320);
#pragma unroll
        for (int wh = 0; wh < 4; ++wh) {
          bf16x8 a = ld8(embb + (size_t)xi[wh] * EDIM + k);
#pragma unroll
          for (int g = 0; g < 4; ++g) acc[wh][g] = MFMA(bv[g], a, acc[wh][g]);
        }
      }
      if (t > 0) {
#pragma unroll
        for (int kk = 2; kk < 10; ++kk) {       // K 64..319: h(t-1) from LDS
          const int k = kk * 32 + lk8;
          const unsigned short* wp = Wc + (size_t)(cc0 + l16) * 320 + k;
          bf16x8 bv[4];
#pragma unroll
          for (int g = 0; g < 4; ++g) bv[g] = ld8(wp + g * 16 * 320);
#pragma unroll
          for (int wh = 0; wh < 4; ++wh) {
            bf16x8 a = ld8(&Hs[cur][wh * 16 + l16][k - 64]);
#pragma unroll
            for (int g = 0; g < 4; ++g) acc[wh][g] = MFMA(bv[g], a, acc[wh][g]);
          }
        }
      }
      // ---- update: lane owns units chg*16+q*4+e, words wh*16+l16; c in LDS ----
      union { unsigned short s[4]; uint2 v; } hp[4];
#pragma unroll
      for (int e = 0; e < 4; ++e) {
        const int ug = chg * 16 + q * 4 + e;    // global unit
        const float4 bb = *reinterpret_cast<const float4*>(bcT + ug * 4);
#pragma unroll
        for (int wh = 0; wh < 4; ++wh) {
          const int wd = wh * 16 + l16;
          const float gi = acc[wh][0][e] + bb.x;
          const float gf = acc[wh][1][e] + bb.y;
          const float gg = acc[wh][2][e] + bb.z;
          const float go = acc[wh][3][e] + bb.w;
          const float cprev = t ? Cs[ug][wd] : 0.f;
          const float ccv = fsig(gf) * cprev + fsig(gi) * ftanh(gg);
          Cs[ug][wd] = ccv;
          hp[wh].s[e] = f2bu(fsig(go) * ftanh(ccv));
        }
      }
      const int uoff = chg * 16 + q * 4;        // 4-short aligned
#pragma unroll
      for (int wh = 0; wh < 4; ++wh) {
        *reinterpret_cast<uint2*>(&Hs[nxt][wh * 16 + l16][uoff]) = hp[wh].v;
        if (t == lenw[wh] - 1)
          *reinterpret_cast<uint2*>(lastT + lroww[wh] + uoff) = hp[wh].v;
        else if (lenw[wh] == 0 && t == 0)
          *reinterpret_cast<uint2*>(lastT + lroww[wh] + uoff) = make_uint2(0, 0);
      }
    }
    __syncthreads();   // Hs[nxt] complete before next step reads it
  }
}

// ---------------------------------------------------------------------------
// Persistent word BiLSTM, BOTH DIRS PER BLOCK: 32 blocks, each owns 16 units
// of fwd AND bwd. Halves barrier participants (skew) and amortizes per-step
// fixed costs (poll, drains, flag) over 2x work; dir1's h-MFMA overlaps
// dir0's load latency. x-weights bf16 + h-weights fp8 in LDS; h exchanged
// fp8 via sc0sc1 at LLC; padded flag barrier (count 32).
// ---------------------------------------------------------------------------
__global__ __launch_bounds__(256, 1) void word_lstm(
    const unsigned short* __restrict__ lastT,   // [pos][128][HC] bf16
    const unsigned short* __restrict__ W16f, const unsigned short* __restrict__ W16b,
    const unsigned char* __restrict__ W8f, const unsigned char* __restrict__ W8b,
    const float* __restrict__ bfi, const float* __restrict__ bbi,
    unsigned char* __restrict__ hbL8,   // [2][2][32][128][16] fp8
    unsigned short* __restrict__ hsW,   // [2][32][128 pos][128 b][16] bf16
    int* __restrict__ aflag) {          // [SEQ][32][FPAD]
  __shared__ unsigned short Wlds16[2][64 * 256];   // 64 KB x-part bf16
  __shared__ unsigned char  Wlds8[2][64 * 512];    // 64 KB h-part fp8
  __shared__ unsigned short ht[2][128][24];        // 12 KB bf16 transpose
  __shared__ unsigned char  ht8[2][128][24];       // 6 KB fp8 transpose
  const int tid = threadIdx.x;
  const int w = tid >> 6, l = tid & 63;
  const int l16 = l & 15, lk8 = (l >> 4) * 8, q = l >> 4;
  const int nb = blockIdx.x;
  const int c0 = nb * 64;
  // ---- stage x-part (bf16) both dirs ----
  for (int ci = tid; ci < 2 * 64 * 32; ci += 256) {
    const int d = ci >> 11, r = ci & 2047;
    const int col = r >> 5, kc = (r & 31) * 8;
    const int kcs = kc ^ ((col & 15) * 8);
    const unsigned short* Wx = d ? W16b : W16f;
    *reinterpret_cast<bf16x8*>(&Wlds16[d][col * 256 + kcs]) =
        ld8(Wx + (size_t)(c0 + col) * 768 + kc);
  }
  // ---- stage h-part (fp8) both dirs ----
  for (int ci = tid; ci < 2 * 64 * 64; ci += 256) {
    const int d = ci >> 12, r = ci & 4095;
    const int col = r >> 6, kb = (r & 63) * 8;
    const int kbs = kb ^ ((col & 15) * 8);
    const unsigned char* Wh = d ? W8b : W8f;
    *reinterpret_cast<i64t*>(&Wlds8[d][col * 512 + kbs]) =
        *reinterpret_cast<const i64t*>(Wh + (size_t)(c0 + col) * 512 + kb);
  }
  float bx[2][4];
#pragma unroll
  for (int g = 0; g < 4; ++g) {
    bx[0][g] = bfi[c0 + g * 16 + l16];
    bx[1][g] = bbi[c0 + g * 16 + l16];
  }
  const int ksw = l16 * 8;
  float cst[2][8];
#pragma unroll
  for (int d = 0; d < 2; ++d)
#pragma unroll
    for (int i = 0; i < 8; ++i) cst[d][i] = 0.f;
  __syncthreads();                      // LDS weights ready

  for (int t = 0; t < SEQ; ++t) {
    const int cur = t & 1;
    int posd[2]; posd[0] = t; posd[1] = SEQ - 1 - t;
    // ---- x-part both dirs: plain cached lastT, bf16 MFMA ----
    f32x4 acc[2][2][4] = {};
#pragma unroll
    for (int d = 0; d < 2; ++d) {
      const int pos = posd[d];
#pragma unroll
      for (int kk = 0; kk < 8; ++kk) {
        const int k = kk * 32 + lk8;
        bf16x8 a0 = ld8(lastT + ((size_t)pos * 128 + w * 32 + l16) * HC + k);
        bf16x8 a1 = ld8(lastT + ((size_t)pos * 128 + w * 32 + l16 + 16) * HC + k);
        const int ks = k ^ ksw;
#pragma unroll
        for (int nn = 0; nn < 4; ++nn) {
          bf16x8 bv = ld8(&Wlds16[d][(l16 + nn * 16) * 256 + ks]);
          acc[d][0][nn] = MFMA(a0, bv, acc[d][0][nn]);
          acc[d][1][nn] = MFMA(a1, bv, acc[d][1][nn]);
        }
      }
    }
    if (t > 0) {
      if (w == 0) {                      // flag-barrier wait for step t-1
        const int* fp = aflag + (size_t)(t - 1) * 32 * FPAD;
        for (;;) {
          int v = 1;
          if (l < 32)
            v = __hip_atomic_load(fp + l * FPAD, __ATOMIC_RELAXED,
                                  __HIP_MEMORY_SCOPE_AGENT);
          if (__ballot(v != 0) == ~0ull) break;
          __builtin_amdgcn_s_sleep(1);
        }
      }
      __syncthreads();
      // ---- h loads (fp8, coherent 8B) both dirs, then fp8 MFMA ----
      i64t af8[2][16][2];
#pragma unroll
      for (int d = 0; d < 2; ++d) {
        const unsigned char* hp =
            hbL8 + (size_t)(((cur ^ 1) * 2 + d) * 32) * 128 * 16;
#pragma unroll
        for (int kk = 0; kk < 16; ++kk) {
          const int u = kk * 32 + lk8;
          const int nbs = u >> 4, ul = u & 15;
#pragma unroll
          for (int r = 0; r < 2; ++r) {
            const int bt = w * 32 + l16 + r * 16;
            af8[d][kk][r] = ld8sc8(hp + ((size_t)nbs * 128 + bt) * 16 + ul);
          }
        }
      }
      asm volatile("s_waitcnt vmcnt(0)" ::: "memory");
      __builtin_amdgcn_sched_barrier(0);   // rule #18
#pragma unroll
      for (int d = 0; d < 2; ++d)
#pragma unroll
        for (int kk = 0; kk < 16; ++kk) {
          const int ks8 = (kk * 32 + lk8) ^ ksw;
#pragma unroll
          for (int nn = 0; nn < 4; ++nn) {
            i64t w8 = *reinterpret_cast<const i64t*>(
                &Wlds8[d][(l16 + nn * 16) * 512 + ks8]);
            acc[d][0][nn] = MFMA8(af8[d][kk][0], w8, acc[d][0][nn]);
            acc[d][1][nn] = MFMA8(af8[d][kk][1], w8, acc[d][1][nn]);
          }
        }
    }
    // ---- in-register LSTM update, both dirs ----
#pragma unroll
    for (int d = 0; d < 2; ++d) {
      float hvf[8];
      int bats[8];
#pragma unroll
      for (int m = 0; m < 2; ++m)
#pragma unroll
        for (int e = 0; e < 4; ++e) {
          const int j = m * 4 + e;
          const float gi = acc[d][m][0][e] + bx[d][0];
          const float gf = acc[d][m][1][e] + bx[d][1];
          const float gg = acc[d][m][2][e] + bx[d][2];
          const float go = acc[d][m][3][e] + bx[d][3];
          const float ccv = fsig(gf) * cst[d][j] + fsig(gi) * ftanh(gg);
          cst[d][j] = ccv;
          const float hv = fsig(go) * ftanh(ccv);
          const int bat = w * 32 + q * 4 + e + m * 16;    // 0..127
          ht[d][bat][l16] = f2bu(hv);
          hvf[j] = hv; bats[j] = bat;
        }
      const int d0 = __builtin_amdgcn_cvt_pk_fp8_f32(hvf[0], hvf[1], 0, false);
      const int d1 = __builtin_amdgcn_cvt_pk_fp8_f32(hvf[2], hvf[3], 0, false);
      const int d2 = __builtin_amdgcn_cvt_pk_fp8_f32(hvf[4], hvf[5], 0, false);
      const int d3 = __builtin_amdgcn_cvt_pk_fp8_f32(hvf[6], hvf[7], 0, false);
      ht8[d][bats[0]][l16] = (unsigned char)(d0 & 255);
      ht8[d][bats[1]][l16] = (unsigned char)((d0 >> 8) & 255);
      ht8[d][bats[2]][l16] = (unsigned char)(d1 & 255);
      ht8[d][bats[3]][l16] = (unsigned char)((d1 >> 8) & 255);
      ht8[d][bats[4]][l16] = (unsigned char)(d2 & 255);
      ht8[d][bats[5]][l16] = (unsigned char)((d2 >> 8) & 255);
      ht8[d][bats[6]][l16] = (unsigned char)(d3 & 255);
      ht8[d][bats[7]][l16] = (unsigned char)((d3 >> 8) & 255);
    }
    __syncthreads();
    // ---- coalesced write-back; flag chain: hbL8 stores -> drain -> flag ----
    const int ub = tid >> 1, uh = tid & 1;
#pragma unroll
    for (int d = 0; d < 2; ++d) {
      i64t hv8 = *reinterpret_cast<const i64t*>(&ht8[d][ub][uh * 8]);
      st8sc8(hbL8 + (size_t)((cur * 2 + d) * 32 + nb) * 128 * 16
                 + ub * 16 + uh * 8, hv8);
    }
    if (t < SEQ - 1) {
      asm volatile("s_waitcnt vmcnt(0)" ::: "memory");
      __syncthreads();
      if (tid == 0)
        __hip_atomic_store(aflag + ((size_t)t * 32 + nb) * FPAD, 1,
                           __ATOMIC_RELAXED, __HIP_MEMORY_SCOPE_AGENT);
    }
    // hsW stores AFTER the flag: off the cross-block critical chain
#pragma unroll
    for (int d = 0; d < 2; ++d) {
      bf16x8 hv = ld8(&ht[d][ub][uh * 8]);
      *reinterpret_cast<bf16x8*>(
          hsW + (((size_t)(d * 32 + nb) * 128 + posd[d]) * 128 + ub) * 16 + uh * 8) = hv;
    }
  }
}

// ---------------------------------------------------------------------------
// MLP layer 1: A gathered from hsW layout. out = relu(A @ W1^T + b1).
// ---------------------------------------------------------------------------
__global__ __launch_bounds__(256) void mlp1_gemm(
    const unsigned short* __restrict__ hsW, const unsigned short* __restrict__ W1b,
    const float* __restrict__ bias, unsigned short* __restrict__ out) {
  const int tid = threadIdx.x;
  const int w = tid >> 6, l = tid & 63;
  const int l16 = l & 15, lk8 = (l >> 4) * 8;
  const int by = blockIdx.y;                   // batch
  const int row0 = by * 128 + w * 32;
  const int col0 = blockIdx.x * 64;
  f32x4 acc[2][4] = {};
  for (int kk = 0; kk < 32; ++kk) {
    const int k = kk * 32 + lk8;               // 0..1023
    const int dirk = k >> 9, u = k & 511, nbs = u >> 4, ul = u & 15;
    const int p0 = w * 32 + l16, p1 = p0 + 16; // pos within batch
    bf16x8 a0 = ld8(hsW + (((size_t)(dirk * 32 + nbs) * 128 + p0) * 128 + by) * 16 + ul);
    bf16x8 a1 = ld8(hsW + (((size_t)(dirk * 32 + nbs) * 128 + p1) * 128 + by) * 16 + ul);
    const unsigned short* wp = W1b + (size_t)(col0 + l16) * 1024 + k;
#pragma unroll
    for (int nn = 0; nn < 4; ++nn) {
      bf16x8 bv = ld8(wp + nn * 16 * 1024);
      acc[0][nn] = MFMA(a0, bv, acc[0][nn]);
      acc[1][nn] = MFMA(a1, bv, acc[1][nn]);
    }
  }
  const int cr = (l >> 4) * 4;
#pragma unroll
  for (int m = 0; m < 2; ++m)
#pragma unroll
    for (int nn = 0; nn < 4; ++nn)
#pragma unroll
      for (int e = 0; e < 4; ++e) {
        const int r = row0 + m * 16 + cr + e;
        const int c = col0 + nn * 16 + l16;
        out[(size_t)r * 256 + c] = f2bu(fmaxf(acc[m][nn][e] + bias[c], 0.f));
      }
}

// ---------------------------------------------------------------------------
// MLP layer 2 (row-major A): out = relu(A @ W2^T + b2).
// ---------------------------------------------------------------------------
__global__ __launch_bounds__(256) void mlp_gemm(
    const unsigned short* __restrict__ A, int lda,
    const unsigned short* __restrict__ W, int ldw,
    const float* __restrict__ bias, unsigned short* __restrict__ out,
    int ldo, int nk, int relu) {
  const int tid = threadIdx.x;
  const int w = tid >> 6, l = tid & 63;
  const int l16 = l & 15, lk8 = (l >> 4) * 8;
  const int row0 = blockIdx.y * 128 + w * 32;
  const int col0 = blockIdx.x * 64;
  f32x4 acc[2][4] = {};
  for (int kk = 0; kk < nk; ++kk) {
    const int k = kk * 32 + lk8;
    bf16x8 a0 = ld8(A + (size_t)(row0 + l16) * lda + k);
    bf16x8 a1 = ld8(A + (size_t)(row0 + 16 + l16) * lda + k);
    const unsigned short* wp = W + (size_t)(col0 + l16) * ldw + k;
    bf16x8 bb[4];
#pragma unroll
    for (int nn = 0; nn < 4; ++nn) bb[nn] = ld8(wp + nn * 16 * ldw);
#pragma unroll
    for (int nn = 0; nn < 4; ++nn) {
      acc[0][nn] = MFMA(a0, bb[nn], acc[0][nn]);
      acc[1][nn] = MFMA(a1, bb[nn], acc[1][nn]);
    }
  }
  const int cr = (l >> 4) * 4;
#pragma unroll
  for (int m = 0; m < 2; ++m)
#pragma unroll
    for (int nn = 0; nn < 4; ++nn)
#pragma unroll
      for (int e = 0; e < 4; ++e) {
        const int r = row0 + m * 16 + cr + e;
        const int c = col0 + nn * 16 + l16;
        float v = acc[m][nn][e] + bias[c];
        if (relu) v = fmaxf(v, 0.f);
        out[(size_t)r * ldo + c] = f2bu(v);
      }
}

// ---------------------------------------------------------------------------
// Logits (MFMA, N=64 padded) + log_softmax over 50, fused. 128 rows/block.
// ---------------------------------------------------------------------------
__global__ __launch_bounds__(256) void logits_fused(
    const unsigned short* __restrict__ h2, const unsigned short* __restrict__ W3p,
    const float* __restrict__ b3, float* __restrict__ out) {
  __shared__ float gt[128][68];
  __shared__ float lseb[128];
  const int tid = threadIdx.x;
  const int w = tid >> 6, l = tid & 63;
  const int l16 = l & 15, lk8 = (l >> 4) * 8;
  const int r0 = blockIdx.x * 128;
  const int rr0 = w * 32 + l16, rr1 = rr0 + 16;
  f32x4 acc[2][4] = {};
#pragma unroll
  for (int kk = 0; kk < 8; ++kk) {
    const int k = kk * 32 + lk8;
    bf16x8 a0 = ld8(h2 + (size_t)(r0 + rr0) * 256 + k);
    bf16x8 a1 = ld8(h2 + (size_t)(r0 + rr1) * 256 + k);
#pragma unroll
    for (int nn = 0; nn < 4; ++nn) {
      bf16x8 bv = ld8(W3p + (size_t)(nn * 16 + l16) * 256 + k);
      acc[0][nn] = MFMA(a0, bv, acc[0][nn]);
      acc[1][nn] = MFMA(a1, bv, acc[1][nn]);
    }
  }
  const int cr = (l >> 4) * 4;
#pragma unroll
  for (int m = 0; m < 2; ++m)
#pragma unroll
    for (int nn = 0; nn < 4; ++nn)
#pragma unroll
      for (int e = 0; e < 4; ++e) {
        const int col = nn * 16 + l16;
        gt[w * 32 + m * 16 + cr + e][col] =
            acc[m][nn][e] + (col < NOUT ? b3[col] : 0.f);
      }
  __syncthreads();
  if (tid < 128) {
    float mx = -INFINITY;
#pragma unroll
    for (int j = 0; j < NOUT; ++j) mx = fmaxf(mx, gt[tid][j]);
    float s = 0.f;
#pragma unroll
    for (int j = 0; j < NOUT; ++j) s += fex2(LOG2E * (gt[tid][j] - mx));
    lseb[tid] = flog2(s) * 0.6931471805599453f + mx;
  }
  __syncthreads();
  for (int idx = tid; idx < 128 * NOUT; idx += 256) {
    const int r = idx / NOUT, j = idx - r * NOUT;
    out[(size_t)(r0 + r) * NOUT + j] = gt[r][j] - lseb[r];
  }
}

// ---------------------------------------------------------------------------
// Prep kernels
// ---------------------------------------------------------------------------
__global__ void prep_w(const float* __restrict__ ih, const float* __restrict__ hh,
                       unsigned short* __restrict__ dst, int HU, int KI, int KH) {
  const int K = KI + KH;
  const long tot = (long)HU * 4 * K;
  for (long idx = (long)blockIdx.x * blockDim.x + threadIdx.x; idx < tot;
       idx += (long)gridDim.x * blockDim.x) {
    const int row = (int)(idx / K), k = (int)(idx % K);
    const int chunk = row >> 6, c = row & 63;
    const int g = c >> 4, u = chunk * 16 + (c & 15);
    const float v = (k < KI) ? ih[(size_t)(g * HU + u) * KI + k]
                             : hh[(size_t)(g * HU + u) * KH + (k - KI)];
    dst[idx] = f2bu(v);
  }
}

// fp8 h-part weights: dst[row][k] e4m3, row gate-major, k in [0,KH)
__global__ void prep_w8(const float* __restrict__ hh, unsigned char* __restrict__ dst,
                        int HU, int KH) {
  const long tot = (long)HU * 4 * (KH / 2);
  for (long p = (long)blockIdx.x * blockDim.x + threadIdx.x; p < tot;
       p += (long)gridDim.x * blockDim.x) {
    const int row = (int)(p / (KH / 2)), kp = (int)(p % (KH / 2)) * 2;
    const int chunk = row >> 6, c = row & 63;
    const int g = c >> 4, u = chunk * 16 + (c & 15);
    const float a = hh[(size_t)(g * HU + u) * KH + kp];
    const float b = hh[(size_t)(g * HU + u) * KH + kp + 1];
    const int d = __builtin_amdgcn_cvt_pk_fp8_f32(a, b, 0, false);
    *reinterpret_cast<unsigned short*>(dst + (size_t)row * KH + kp) =
        (unsigned short)(d & 0xFFFF);
  }
}

__global__ void prep_bias(const float* bih, const float* bhh, float* dst, int HU) {
  const int idx = blockIdx.x * blockDim.x + threadIdx.x;   // gate-major flat
  if (idx < 4 * HU) {
    const int chunk = idx >> 6, c = idx & 63;
    const int g = c >> 4, u = chunk * 16 + (c & 15);
    dst[idx] = bih[g * HU + u] + bhh[g * HU + u];
  }
}

// char bias: bcT[u*4 + g]
__global__ void prep_biasT(const float* bih, const float* bhh, float* dst, int HU) {
  const int idx = blockIdx.x * blockDim.x + threadIdx.x;
  if (idx < 4 * HU) {
    const int u = idx >> 2, g = idx & 3;
    dst[idx] = bih[g * HU + u] + bhh[g * HU + u];
  }
}

__global__ void conv_bf(const float* __restrict__ src, unsigned short* __restrict__ dst,
                        long n) {
  for (long i = (long)blockIdx.x * blockDim.x + threadIdx.x; i < n;
       i += (long)gridDim.x * blockDim.x)
    dst[i] = f2bu(src[i]);
}

__global__ void prep_w3(const float* __restrict__ W3, unsigned short* __restrict__ dst) {
  const int i = blockIdx.x * blockDim.x + threadIdx.x;   // 64*256
  if (i < 64 * 256) {
    const int r = i >> 8;
    dst[i] = (r < NOUT) ? f2bu(W3[i]) : 0;
  }
}

__global__ void lengths_k(const int* x, int* len) {
  const int n = blockIdx.x * blockDim.x + threadIdx.x;
  if (n < NW) {
    int c = 0;
#pragma unroll
    for (int l = 0; l < LC; ++l) c += (x[(size_t)n * LC + l] != 0) ? 1 : 0;
    len[n] = c;
  }
}

__global__ void zero_k(int* p, int n) {
  const int i = blockIdx.x * blockDim.x + threadIdx.x;
  if (i < n) p[i] = 0;
}

__global__ void sentinel_k(float* out, int n) {
  const int i = blockIdx.x * blockDim.x + threadIdx.x;
  if (i < n) out[i] = 1000.0f;
}

// ---------------------------------------------------------------------------
extern "C" void kernel_launch(void* const* d_in, const int* in_sizes, int n_in,
                              void* d_out, int out_size, void* d_ws, size_t ws_size,
                              hipStream_t stream) {
  const int*   x     = (const int*)d_in[0];
  const float* emb   = (const float*)d_in[1];
  const float* cW_ih = (const float*)d_in[2];
  const float* cW_hh = (const float*)d_in[3];
  const float* cb_ih = (const float*)d_in[4];
  const float* cb_hh = (const float*)d_in[5];
  const float* fW_ih = (const float*)d_in[6];
  const float* fW_hh = (const float*)d_in[7];
  const float* fb_ih = (const float*)d_in[8];
  const float* fb_hh = (const float*)d_in[9];
  const float* bW_ih = (const float*)d_in[10];
  const float* bW_hh = (const float*)d_in[11];
  const float* bb_ih = (const float*)d_in[12];
  const float* bb_hh = (const float*)d_in[13];
  const float* W1 = (const float*)d_in[14];
  const float* b1 = (const float*)d_in[15];
  const float* W2 = (const float*)d_in[16];
  const float* b2 = (const float*)d_in[17];
  const float* W3 = (const float*)d_in[18];
  const float* b3 = (const float*)d_in[19];
  float* out = (float*)d_out;
  (void)in_sizes; (void)n_in;

  char* ws = (char*)d_ws;
  size_t off = 0;
  auto alloc = [&](size_t bytes) -> char* {
    char* p = ws + off;
    off += (bytes + 255) & ~(size_t)255;
    return p;
  };
  int*            len_  = (int*)alloc((size_t)NW * 4);
  int*            aflag = (int*)alloc((size_t)SEQ * 32 * FPAD * 4);   // 256KB
  unsigned short* embb  = (unsigned short*)alloc((size_t)100 * EDIM * 2);
  unsigned short* Wc_i  = (unsigned short*)alloc((size_t)1024 * 320 * 2);
  unsigned short* Wf_i  = (unsigned short*)alloc((size_t)2048 * 768 * 2);
  unsigned short* Wb_i  = (unsigned short*)alloc((size_t)2048 * 768 * 2);
  unsigned char*  Wf8   = (unsigned char*)alloc((size_t)2048 * 512);
  unsigned char*  Wb8   = (unsigned char*)alloc((size_t)2048 * 512);
  unsigned short* W1b   = (unsigned short*)alloc((size_t)256 * 1024 * 2);
  unsigned short* W2b   = (unsigned short*)alloc((size_t)256 * 256 * 2);
  unsigned short* W3p   = (unsigned short*)alloc((size_t)64 * 256 * 2);
  float*          bcT   = (float*)alloc(1024 * 4);
  float*          bf_i  = (float*)alloc(2048 * 4);
  float*          bb_i  = (float*)alloc(2048 * 4);
  unsigned short* lastT = (unsigned short*)alloc((size_t)NW * HC * 2);       // 8MB
  unsigned char*  hbL8  = (unsigned char*)alloc((size_t)2 * 2 * 32 * 128 * 16);
  unsigned short* hsW   = (unsigned short*)alloc((size_t)2 * 32 * 128 * 128 * 16 * 2);
  unsigned short* h1    = (unsigned short*)alloc((size_t)NW * HC * 2);       // 8MB
  unsigned short* h2    = (unsigned short*)alloc((size_t)NW * HC * 2);       // 8MB

  if (off > ws_size) {
    sentinel_k<<<(out_size + 255) / 256, 256, 0, stream>>>(out, out_size);
    return;
  }

  auto cdiv = [](long a, long b) { return (int)((a + b - 1) / b); };

  // ---- prep ----
  prep_w<<<1280, 256, 0, stream>>>(cW_ih, cW_hh, Wc_i, HC, EDIM, HC);
  prep_w<<<3072, 256, 0, stream>>>(fW_ih, fW_hh, Wf_i, HW, HC, HW);
  prep_w<<<3072, 256, 0, stream>>>(bW_ih, bW_hh, Wb_i, HW, HC, HW);
  prep_w8<<<2048, 256, 0, stream>>>(fW_hh, Wf8, HW, HW);
  prep_w8<<<2048, 256, 0, stream>>>(bW_hh, Wb8, HW, HW);
  prep_biasT<<<cdiv(1024, 256), 256, 0, stream>>>(cb_ih, cb_hh, bcT, HC);
  prep_bias<<<cdiv(2048, 256), 256, 0, stream>>>(fb_ih, fb_hh, bf_i, HW);
  prep_bias<<<cdiv(2048, 256), 256, 0, stream>>>(bb_ih, bb_hh, bb_i, HW);
  conv_bf<<<25, 256, 0, stream>>>(emb, embb, 100L * EDIM);
  conv_bf<<<1024, 256, 0, stream>>>(W1, W1b, 256L * 1024);
  conv_bf<<<256, 256, 0, stream>>>(W2, W2b, 256L * 256);
  prep_w3<<<64, 256, 0, stream>>>(W3, W3p);
  lengths_k<<<cdiv(NW, 256), 256, 0, stream>>>(x, len_);
  zero_k<<<cdiv(SEQ * 32 * FPAD, 256), 256, 0, stream>>>(aflag, SEQ * 32 * FPAD);

  // ---- persistent char LSTM (1 launch, 512 threads, 2 waves/SIMD) ----
  char_lstm<<<NW / 64, 512, 0, stream>>>(x, embb, Wc_i, bcT, lastT, len_);

  // ---- persistent word BiLSTM (1 launch, both dirs/block, 32 blocks) ----
  word_lstm<<<NWB, 256, 0, stream>>>(lastT, Wf_i, Wb_i, Wf8, Wb8, bf_i, bb_i,
                                     hbL8, hsW, aflag);

  // ---- MLP + fused logits/log_softmax ----
  mlp1_gemm<<<dim3(4, 128), 256, 0, stream>>>(hsW, W1b, b1, h1);
  mlp_gemm<<<dim3(4, 128), 256, 0, stream>>>(h1, 256, W2b, 256, b2, h2, 256, 8, 1);
  logits_fused<<<NW / 128, 256, 0, stream>>>(h2, W3p, b3, out);
}

// Round 18
// 2106.022 us; speedup vs baseline: 1.0639x; 1.0639x over previous
//
#include <hip/hip_runtime.h>
#include <hip/hip_bf16.h>
#include <math.h>

typedef __hip_bfloat16 bf16;
typedef __attribute__((ext_vector_type(8))) short bf16x8;   // 8 bf16 = 4 VGPR
typedef __attribute__((ext_vector_type(4))) float f32x4;
typedef long i64t;                                          // 8 fp8 = 2 VGPR

#define NW   16384
#define LC   20
#define EDIM 64
#define HC   256
#define HW   512
#define SEQ  128
#define NOUT 50
#define NWB  64      // word-kernel blocks (2 dirs x 32), must be co-resident
#define FPAD 16      // ints per flag (64B line)

// ---- fast transcendentals ----
#define LOG2E 1.4426950408889634f
__device__ __forceinline__ float fex2(float x) {
  float r; asm("v_exp_f32 %0, %1" : "=v"(r) : "v"(x)); return r;
}
__device__ __forceinline__ float frcp(float x) {
  float r; asm("v_rcp_f32 %0, %1" : "=v"(r) : "v"(x)); return r;
}
__device__ __forceinline__ float flog2(float x) {
  float r; asm("v_log_f32 %0, %1" : "=v"(r) : "v"(x)); return r;
}
__device__ __forceinline__ float fsig(float x) { return frcp(1.f + fex2(-LOG2E * x)); }
__device__ __forceinline__ float ftanh(float x) {
  return 1.f - 2.f * frcp(1.f + fex2(2.f * LOG2E * x));
}

__device__ __forceinline__ unsigned short f2bu(float f) {
  bf16 h = __float2bfloat16(f);
  return *reinterpret_cast<unsigned short*>(&h);
}
__device__ __forceinline__ bf16x8 ld8(const unsigned short* p) {
  return *reinterpret_cast<const bf16x8*>(p);
}
// Coherent (cross-XCD) plain ops: sc0 sc1 -> bypass L1+L2, hit LLC.
__device__ __forceinline__ i64t ld8sc8(const unsigned char* p) {   // 8B load
  i64t r;
  asm volatile("global_load_dwordx2 %0, %1, off sc0 sc1" : "=v"(r) : "v"(p));
  return r;
}
__device__ __forceinline__ void st8sc8(unsigned char* p, i64t v) { // 8B store
  asm volatile("global_store_dwordx2 %0, %1, off sc0 sc1" :: "v"(p), "v"(v) : "memory");
}
#define MFMA(a, b, c)  __builtin_amdgcn_mfma_f32_16x16x32_bf16(a, b, c, 0, 0, 0)
#define MFMA8(a, b, c) __builtin_amdgcn_mfma_f32_16x16x32_fp8_fp8(a, b, c, 0, 0, 0)

// ---------------------------------------------------------------------------
// Persistent char LSTM, TRANSPOSED compute, 32 WORDS/BLOCK, 512 threads
// (8 waves x 2 chunks). LDS 68.6 KB -> 2 blocks/CU = 4 waves/SIMD for
// latency hiding. c-state in LDS; in-register gate update; uint2 h-writes.
// ---------------------------------------------------------------------------
__global__ __launch_bounds__(512, 4) void char_lstm(
    const int* __restrict__ x, const unsigned short* __restrict__ embb,
    const unsigned short* __restrict__ Wc, const float* __restrict__ bcT,
    unsigned short* __restrict__ lastT, const int* __restrict__ len) {
  __shared__ unsigned short Hs[2][32][264];   // 33.8 KB
  __shared__ float Cs[256][34];               // 34.8 KB c-state
  const int tid = threadIdx.x;
  const int w = tid >> 6, l = tid & 63;       // w 0..7
  const int l16 = l & 15, lk8 = (l >> 4) * 8, q = l >> 4;
  const int w0 = blockIdx.x * 32;
  int lenw[2], lroww[2];
#pragma unroll
  for (int wh = 0; wh < 2; ++wh) {
    const int n = w0 + wh * 16 + l16;
    lenw[wh] = len[n];
    lroww[wh] = ((n & 127) * 128 + (n >> 7)) * HC;   // time-major row base
  }
  float cst[2][8];                      // [chunk][wh*4 + e]
#pragma unroll
  for (int c = 0; c < 2; ++c)
#pragma unroll
    for (int j = 0; j < 8; ++j) cst[c][j] = 0.f;

  for (int t = 0; t < LC; ++t) {
    const int cur = t & 1, nxt = cur ^ 1;
    int xi[2];
#pragma unroll
    for (int wh = 0; wh < 2; ++wh) xi[wh] = x[(w0 + wh * 16 + l16) * LC + t];
#pragma unroll
    for (int c = 0; c < 2; ++c) {
      const int chg = w * 2 + c;                // chunk 0..15
      const int cc0 = chg * 64;                 // gate-col base
      f32x4 acc[2][4] = {};                     // [wh][gate]
#pragma unroll
      for (int kk = 0; kk < 2; ++kk) {          // K 0..63: embedding
        const int k = kk * 32 + lk8;
        const unsigned short* wp = Wc + (size_t)(cc0 + l16) * 320 + k;
        bf16x8 bv[4];
#pragma unroll
        for (int g = 0; g < 4; ++g) bv[g] = ld8(wp + g * 16 * 320);
        bf16x8 a0 = ld8(embb + (size_t)xi[0] * EDIM + k);
        bf16x8 a1 = ld8(embb + (size_t)xi[1] * EDIM + k);
#pragma unroll
        for (int g = 0; g < 4; ++g) {
          acc[0][g] = MFMA(bv[g], a0, acc[0][g]);
          acc[1][g] = MFMA(bv[g], a1, acc[1][g]);
        }
      }
      if (t > 0) {
#pragma unroll
        for (int kk = 2; kk < 10; ++kk) {       // K 64..319: h(t-1) from LDS
          const int k = kk * 32 + lk8;
          const unsigned short* wp = Wc + (size_t)(cc0 + l16) * 320 + k;
          bf16x8 bv[4];
#pragma unroll
          for (int g = 0; g < 4; ++g) bv[g] = ld8(wp + g * 16 * 320);
          bf16x8 a0 = ld8(&Hs[cur][l16][k - 64]);
          bf16x8 a1 = ld8(&Hs[cur][16 + l16][k - 64]);
#pragma unroll
          for (int g = 0; g < 4; ++g) {
            acc[0][g] = MFMA(bv[g], a0, acc[0][g]);
            acc[1][g] = MFMA(bv[g], a1, acc[1][g]);
          }
        }
      }
      // ---- update: lane owns units chg*16+q*4+e, words wh*16+l16 ----
      union { unsigned short s[4]; uint2 v; } hp[2];
#pragma unroll
      for (int e = 0; e < 4; ++e) {
        const int ug = chg * 16 + q * 4 + e;    // global unit
        const float4 bb = *reinterpret_cast<const float4*>(bcT + ug * 4);
#pragma unroll
        for (int wh = 0; wh < 2; ++wh) {
          const int wd = wh * 16 + l16;
          const float gi = acc[wh][0][e] + bb.x;
          const float gf = acc[wh][1][e] + bb.y;
          const float gg = acc[wh][2][e] + bb.z;
          const float go = acc[wh][3][e] + bb.w;
          const float cprev = t ? Cs[ug][wd] : 0.f;
          const float ccv = fsig(gf) * cprev + fsig(gi) * ftanh(gg);
          Cs[ug][wd] = ccv;
          hp[wh].s[e] = f2bu(fsig(go) * ftanh(ccv));
        }
      }
      const int uoff = chg * 16 + q * 4;        // 4-short aligned
#pragma unroll
      for (int wh = 0; wh < 2; ++wh) {
        *reinterpret_cast<uint2*>(&Hs[nxt][wh * 16 + l16][uoff]) = hp[wh].v;
        if (t == lenw[wh] - 1)
          *reinterpret_cast<uint2*>(lastT + lroww[wh] + uoff) = hp[wh].v;
        else if (lenw[wh] == 0 && t == 0)
          *reinterpret_cast<uint2*>(lastT + lroww[wh] + uoff) = make_uint2(0, 0);
      }
    }
    __syncthreads();   // Hs[nxt] complete before next step reads it
  }
}

// ---------------------------------------------------------------------------
// Persistent word BiLSTM (r16-proven): 64 blocks (dir = bx>>5, 16 units).
// x-weights bf16 (32KB) + h-weights fp8 (32KB) in LDS; h exchanged fp8 via
// sc0sc1 at LLC (half traffic), consumed by mfma fp8_fp8. In-register
// update -> bf16 (hsW) + fp8 (hbL8). Padded flag barrier.
// ---------------------------------------------------------------------------
__global__ __launch_bounds__(256, 1) void word_lstm(
    const unsigned short* __restrict__ lastT,   // [pos][128][HC] bf16
    const unsigned short* __restrict__ W16,     // bf16 gate-major (fwd)
    const unsigned short* __restrict__ W16b,    // (bwd)
    const unsigned char* __restrict__ W8f,      // fp8 gate-major (fwd)
    const unsigned char* __restrict__ W8b,      // (bwd)
    const float* __restrict__ bfi, const float* __restrict__ bbi,
    unsigned char* __restrict__ hbL8,   // [2][2][32][128][16] fp8
    unsigned short* __restrict__ hsW,   // [2][32][128 pos][128 b][16] bf16
    int* __restrict__ aflag) {          // [2][SEQ][32][FPAD]
  __shared__ unsigned short Wlds16[64 * 256];   // 32 KB x-part bf16
  __shared__ unsigned char  Wlds8[64 * 512];    // 32 KB h-part fp8
  __shared__ unsigned short ht[128][24];        // 6 KB bf16 transpose
  __shared__ unsigned char  ht8[128][24];       // 3 KB fp8 transpose
  const int tid = threadIdx.x;
  const int w = tid >> 6, l = tid & 63;
  const int l16 = l & 15, lk8 = (l >> 4) * 8, q = l >> 4;
  const int dir = blockIdx.x >> 5;
  const int nb = blockIdx.x & 31;
  const int c0 = nb * 64;
  const unsigned short* Wx = dir ? W16b : W16;
  const unsigned char*  Wh = dir ? W8b : W8f;
  const float* bias = dir ? bbi : bfi;
  for (int ci = tid; ci < 64 * 32; ci += 256) {
    const int col = ci >> 5, kc = (ci & 31) * 8;
    const int kcs = kc ^ ((col & 15) * 8);
    *reinterpret_cast<bf16x8*>(&Wlds16[col * 256 + kcs]) =
        ld8(Wx + (size_t)(c0 + col) * 768 + kc);
  }
  for (int ci = tid; ci < 64 * 64; ci += 256) {
    const int col = ci >> 6, kb = (ci & 63) * 8;
    const int kbs = kb ^ ((col & 15) * 8);
    *reinterpret_cast<i64t*>(&Wlds8[col * 512 + kbs]) =
        *reinterpret_cast<const i64t*>(Wh + (size_t)(c0 + col) * 512 + kb);
  }
  const float b0 = bias[c0 + 0 * 16 + l16];
  const float b1 = bias[c0 + 1 * 16 + l16];
  const float b2 = bias[c0 + 2 * 16 + l16];
  const float b3 = bias[c0 + 3 * 16 + l16];
  const int ksw = l16 * 8;
  float cst[8];
#pragma unroll
  for (int i = 0; i < 8; ++i) cst[i] = 0.f;
  __syncthreads();                      // LDS weights ready

  for (int t = 0; t < SEQ; ++t) {
    const int cur = t & 1;
    const int pos = dir ? (SEQ - 1 - t) : t;
    // ---- x-part: plain cached lastT loads, bf16 MFMA ----
    f32x4 acc[2][4] = {};
#pragma unroll
    for (int kk = 0; kk < 8; ++kk) {
      const int k = kk * 32 + lk8;
      bf16x8 a0 = ld8(lastT + ((size_t)pos * 128 + w * 32 + l16) * HC + k);
      bf16x8 a1 = ld8(lastT + ((size_t)pos * 128 + w * 32 + l16 + 16) * HC + k);
      const int ks = k ^ ksw;
#pragma unroll
      for (int nn = 0; nn < 4; ++nn) {
        bf16x8 bv = ld8(&Wlds16[(l16 + nn * 16) * 256 + ks]);
        acc[0][nn] = MFMA(a0, bv, acc[0][nn]);
        acc[1][nn] = MFMA(a1, bv, acc[1][nn]);
      }
    }
    if (t > 0) {
      if (w == 0) {                      // flag-barrier wait for step t-1
        const int* fp = aflag + (size_t)(dir * SEQ + (t - 1)) * 32 * FPAD;
        for (;;) {
          int v = 1;
          if (l < 32)
            v = __hip_atomic_load(fp + l * FPAD, __ATOMIC_RELAXED,
                                  __HIP_MEMORY_SCOPE_AGENT);
          if (__ballot(v != 0) == ~0ull) break;
          __builtin_amdgcn_s_sleep(1);
        }
      }
      __syncthreads();
      // ---- h loads (fp8, coherent 8B) + fp8 MFMA ----
      i64t af8[16][2];
      const unsigned char* hp =
          hbL8 + (size_t)(((cur ^ 1) * 2 + dir) * 32) * 128 * 16;
#pragma unroll
      for (int kk = 0; kk < 16; ++kk) {
        const int u = kk * 32 + lk8;
        const int nbs = u >> 4, ul = u & 15;
#pragma unroll
        for (int r = 0; r < 2; ++r) {
          const int bt = w * 32 + l16 + r * 16;
          af8[kk][r] = ld8sc8(hp + ((size_t)nbs * 128 + bt) * 16 + ul);
        }
      }
      asm volatile("s_waitcnt vmcnt(0)" ::: "memory");
      __builtin_amdgcn_sched_barrier(0);   // rule #18
#pragma unroll
      for (int kk = 0; kk < 16; ++kk) {
        const int ks8 = (kk * 32 + lk8) ^ ksw;
#pragma unroll
        for (int nn = 0; nn < 4; ++nn) {
          i64t w8 = *reinterpret_cast<const i64t*>(
              &Wlds8[(l16 + nn * 16) * 512 + ks8]);
          acc[0][nn] = MFMA8(af8[kk][0], w8, acc[0][nn]);
          acc[1][nn] = MFMA8(af8[kk][1], w8, acc[1][nn]);
        }
      }
    }
    // ---- in-register LSTM update (lane owns unit nb*16+l16, 8 batches) ----
    float hvf[8];
    int bats[8];
#pragma unroll
    for (int m = 0; m < 2; ++m)
#pragma unroll
      for (int e = 0; e < 4; ++e) {
        const int j = m * 4 + e;
        const float gi = acc[m][0][e] + b0;
        const float gf = acc[m][1][e] + b1;
        const float gg = acc[m][2][e] + b2;
        const float go = acc[m][3][e] + b3;
        const float ccv = fsig(gf) * cst[j] + fsig(gi) * ftanh(gg);
        cst[j] = ccv;
        const float hv = fsig(go) * ftanh(ccv);
        const int bat = w * 32 + q * 4 + e + m * 16;    // 0..127
        ht[bat][l16] = f2bu(hv);
        hvf[j] = hv; bats[j] = bat;
      }
    {
      const int d0 = __builtin_amdgcn_cvt_pk_fp8_f32(hvf[0], hvf[1], 0, false);
      const int d1 = __builtin_amdgcn_cvt_pk_fp8_f32(hvf[2], hvf[3], 0, false);
      const int d2 = __builtin_amdgcn_cvt_pk_fp8_f32(hvf[4], hvf[5], 0, false);
      const int d3 = __builtin_amdgcn_cvt_pk_fp8_f32(hvf[6], hvf[7], 0, false);
      ht8[bats[0]][l16] = (unsigned char)(d0 & 255);
      ht8[bats[1]][l16] = (unsigned char)((d0 >> 8) & 255);
      ht8[bats[2]][l16] = (unsigned char)(d1 & 255);
      ht8[bats[3]][l16] = (unsigned char)((d1 >> 8) & 255);
      ht8[bats[4]][l16] = (unsigned char)(d2 & 255);
      ht8[bats[5]][l16] = (unsigned char)((d2 >> 8) & 255);
      ht8[bats[6]][l16] = (unsigned char)(d3 & 255);
      ht8[bats[7]][l16] = (unsigned char)((d3 >> 8) & 255);
    }
    __syncthreads();
    // ---- coalesced write-back; flag chain: hbL8 store -> drain -> flag ----
    const int ub = tid >> 1, uh = tid & 1;
    i64t hv8 = *reinterpret_cast<const i64t*>(&ht8[ub][uh * 8]);
    st8sc8(hbL8 + (size_t)((cur * 2 + dir) * 32 + nb) * 128 * 16
               + ub * 16 + uh * 8, hv8);
    if (t < SEQ - 1) {
      asm volatile("s_waitcnt vmcnt(0)" ::: "memory");
      __syncthreads();
      if (tid == 0)
        __hip_atomic_store(aflag + ((size_t)(dir * SEQ + t) * 32 + nb) * FPAD, 1,
                           __ATOMIC_RELAXED, __HIP_MEMORY_SCOPE_AGENT);
    }
    // hsW store AFTER the flag: off the cross-block critical chain
    bf16x8 hv = ld8(&ht[ub][uh * 8]);
    *reinterpret_cast<bf16x8*>(
        hsW + (((size_t)(dir * 32 + nb) * 128 + pos) * 128 + ub) * 16 + uh * 8) = hv;
  }
}

// ---------------------------------------------------------------------------
// MLP layer 1: A gathered from hsW layout. out = relu(A @ W1^T + b1).
// ---------------------------------------------------------------------------
__global__ __launch_bounds__(256) void mlp1_gemm(
    const unsigned short* __restrict__ hsW, const unsigned short* __restrict__ W1b,
    const float* __restrict__ bias, unsigned short* __restrict__ out) {
  const int tid = threadIdx.x;
  const int w = tid >> 6, l = tid & 63;
  const int l16 = l & 15, lk8 = (l >> 4) * 8;
  const int by = blockIdx.y;                   // batch
  const int row0 = by * 128 + w * 32;
  const int col0 = blockIdx.x * 64;
  f32x4 acc[2][4] = {};
  for (int kk = 0; kk < 32; ++kk) {
    const int k = kk * 32 + lk8;               // 0..1023
    const int dirk = k >> 9, u = k & 511, nbs = u >> 4, ul = u & 15;
    const int p0 = w * 32 + l16, p1 = p0 + 16; // pos within batch
    bf16x8 a0 = ld8(hsW + (((size_t)(dirk * 32 + nbs) * 128 + p0) * 128 + by) * 16 + ul);
    bf16x8 a1 = ld8(hsW + (((size_t)(dirk * 32 + nbs) * 128 + p1) * 128 + by) * 16 + ul);
    const unsigned short* wp = W1b + (size_t)(col0 + l16) * 1024 + k;
#pragma unroll
    for (int nn = 0; nn < 4; ++nn) {
      bf16x8 bv = ld8(wp + nn * 16 * 1024);
      acc[0][nn] = MFMA(a0, bv, acc[0][nn]);
      acc[1][nn] = MFMA(a1, bv, acc[1][nn]);
    }
  }
  const int cr = (l >> 4) * 4;
#pragma unroll
  for (int m = 0; m < 2; ++m)
#pragma unroll
    for (int nn = 0; nn < 4; ++nn)
#pragma unroll
      for (int e = 0; e < 4; ++e) {
        const int r = row0 + m * 16 + cr + e;
        const int c = col0 + nn * 16 + l16;
        out[(size_t)r * 256 + c] = f2bu(fmaxf(acc[m][nn][e] + bias[c], 0.f));
      }
}

// ---------------------------------------------------------------------------
// MLP layer 2 (row-major A): out = relu(A @ W2^T + b2).
// ---------------------------------------------------------------------------
__global__ __launch_bounds__(256) void mlp_gemm(
    const unsigned short* __restrict__ A, int lda,
    const unsigned short* __restrict__ W, int ldw,
    const float* __restrict__ bias, unsigned short* __restrict__ out,
    int ldo, int nk, int relu) {
  const int tid = threadIdx.x;
  const int w = tid >> 6, l = tid & 63;
  const int l16 = l & 15, lk8 = (l >> 4) * 8;
  const int row0 = blockIdx.y * 128 + w * 32;
  const int col0 = blockIdx.x * 64;
  f32x4 acc[2][4] = {};
  for (int kk = 0; kk < nk; ++kk) {
    const int k = kk * 32 + lk8;
    bf16x8 a0 = ld8(A + (size_t)(row0 + l16) * lda + k);
    bf16x8 a1 = ld8(A + (size_t)(row0 + 16 + l16) * lda + k);
    const unsigned short* wp = W + (size_t)(col0 + l16) * ldw + k;
    bf16x8 bb[4];
#pragma unroll
    for (int nn = 0; nn < 4; ++nn) bb[nn] = ld8(wp + nn * 16 * ldw);
#pragma unroll
    for (int nn = 0; nn < 4; ++nn) {
      acc[0][nn] = MFMA(a0, bb[nn], acc[0][nn]);
      acc[1][nn] = MFMA(a1, bb[nn], acc[1][nn]);
    }
  }
  const int cr = (l >> 4) * 4;
#pragma unroll
  for (int m = 0; m < 2; ++m)
#pragma unroll
    for (int nn = 0; nn < 4; ++nn)
#pragma unroll
      for (int e = 0; e < 4; ++e) {
        const int r = row0 + m * 16 + cr + e;
        const int c = col0 + nn * 16 + l16;
        float v = acc[m][nn][e] + bias[c];
        if (relu) v = fmaxf(v, 0.f);
        out[(size_t)r * ldo + c] = f2bu(v);
      }
}

// ---------------------------------------------------------------------------
// Logits (MFMA, N=64 padded) + log_softmax over 50, fused. 128 rows/block.
// ---------------------------------------------------------------------------
__global__ __launch_bounds__(256) void logits_fused(
    const unsigned short* __restrict__ h2, const unsigned short* __restrict__ W3p,
    const float* __restrict__ b3, float* __restrict__ out) {
  __shared__ float gt[128][68];
  __shared__ float lseb[128];
  const int tid = threadIdx.x;
  const int w = tid >> 6, l = tid & 63;
  const int l16 = l & 15, lk8 = (l >> 4) * 8;
  const int r0 = blockIdx.x * 128;
  const int rr0 = w * 32 + l16, rr1 = rr0 + 16;
  f32x4 acc[2][4] = {};
#pragma unroll
  for (int kk = 0; kk < 8; ++kk) {
    const int k = kk * 32 + lk8;
    bf16x8 a0 = ld8(h2 + (size_t)(r0 + rr0) * 256 + k);
    bf16x8 a1 = ld8(h2 + (size_t)(r0 + rr1) * 256 + k);
#pragma unroll
    for (int nn = 0; nn < 4; ++nn) {
      bf16x8 bv = ld8(W3p + (size_t)(nn * 16 + l16) * 256 + k);
      acc[0][nn] = MFMA(a0, bv, acc[0][nn]);
      acc[1][nn] = MFMA(a1, bv, acc[1][nn]);
    }
  }
  const int cr = (l >> 4) * 4;
#pragma unroll
  for (int m = 0; m < 2; ++m)
#pragma unroll
    for (int nn = 0; nn < 4; ++nn)
#pragma unroll
      for (int e = 0; e < 4; ++e) {
        const int col = nn * 16 + l16;
        gt[w * 32 + m * 16 + cr + e][col] =
            acc[m][nn][e] + (col < NOUT ? b3[col] : 0.f);
      }
  __syncthreads();
  if (tid < 128) {
    float mx = -INFINITY;
#pragma unroll
    for (int j = 0; j < NOUT; ++j) mx = fmaxf(mx, gt[tid][j]);
    float s = 0.f;
#pragma unroll
    for (int j = 0; j < NOUT; ++j) s += fex2(LOG2E * (gt[tid][j] - mx));
    lseb[tid] = flog2(s) * 0.6931471805599453f + mx;
  }
  __syncthreads();
  for (int idx = tid; idx < 128 * NOUT; idx += 256) {
    const int r = idx / NOUT, j = idx - r * NOUT;
    out[(size_t)(r0 + r) * NOUT + j] = gt[r][j] - lseb[r];
  }
}

// ---------------------------------------------------------------------------
// Prep kernels
// ---------------------------------------------------------------------------
__global__ void prep_w(const float* __restrict__ ih, const float* __restrict__ hh,
                       unsigned short* __restrict__ dst, int HU, int KI, int KH) {
  const int K = KI + KH;
  const long tot = (long)HU * 4 * K;
  for (long idx = (long)blockIdx.x * blockDim.x + threadIdx.x; idx < tot;
       idx += (long)gridDim.x * blockDim.x) {
    const int row = (int)(idx / K), k = (int)(idx % K);
    const int chunk = row >> 6, c = row & 63;
    const int g = c >> 4, u = chunk * 16 + (c & 15);
    const float v = (k < KI) ? ih[(size_t)(g * HU + u) * KI + k]
                             : hh[(size_t)(g * HU + u) * KH + (k - KI)];
    dst[idx] = f2bu(v);
  }
}

// fp8 h-part weights: dst[row][k] e4m3, row gate-major, k in [0,KH)
__global__ void prep_w8(const float* __restrict__ hh, unsigned char* __restrict__ dst,
                        int HU, int KH) {
  const long tot = (long)HU * 4 * (KH / 2);
  for (long p = (long)blockIdx.x * blockDim.x + threadIdx.x; p < tot;
       p += (long)gridDim.x * blockDim.x) {
    const int row = (int)(p / (KH / 2)), kp = (int)(p % (KH / 2)) * 2;
    const int chunk = row >> 6, c = row & 63;
    const int g = c >> 4, u = chunk * 16 + (c & 15);
    const float a = hh[(size_t)(g * HU + u) * KH + kp];
    const float b = hh[(size_t)(g * HU + u) * KH + kp + 1];
    const int d = __builtin_amdgcn_cvt_pk_fp8_f32(a, b, 0, false);
    *reinterpret_cast<unsigned short*>(dst + (size_t)row * KH + kp) =
        (unsigned short)(d & 0xFFFF);
  }
}

__global__ void prep_bias(const float* bih, const float* bhh, float* dst, int HU) {
  const int idx = blockIdx.x * blockDim.x + threadIdx.x;   // gate-major flat
  if (idx < 4 * HU) {
    const int chunk = idx >> 6, c = idx & 63;
    const int g = c >> 4, u = chunk * 16 + (c & 15);
    dst[idx] = bih[g * HU + u] + bhh[g * HU + u];
  }
}

// char bias: bcT[u*4 + g]
__global__ void prep_biasT(const float* bih, const float* bhh, float* dst, int HU) {
  const int idx = blockIdx.x * blockDim.x + threadIdx.x;
  if (idx < 4 * HU) {
    const int u = idx >> 2, g = idx & 3;
    dst[idx] = bih[g * HU + u] + bhh[g * HU + u];
  }
}

__global__ void conv_bf(const float* __restrict__ src, unsigned short* __restrict__ dst,
                        long n) {
  for (long i = (long)blockIdx.x * blockDim.x + threadIdx.x; i < n;
       i += (long)gridDim.x * blockDim.x)
    dst[i] = f2bu(src[i]);
}

__global__ void prep_w3(const float* __restrict__ W3, unsigned short* __restrict__ dst) {
  const int i = blockIdx.x * blockDim.x + threadIdx.x;   // 64*256
  if (i < 64 * 256) {
    const int r = i >> 8;
    dst[i] = (r < NOUT) ? f2bu(W3[i]) : 0;
  }
}

__global__ void lengths_k(const int* x, int* len) {
  const int n = blockIdx.x * blockDim.x + threadIdx.x;
  if (n < NW) {
    int c = 0;
#pragma unroll
    for (int l = 0; l < LC; ++l) c += (x[(size_t)n * LC + l] != 0) ? 1 : 0;
    len[n] = c;
  }
}

__global__ void zero_k(int* p, int n) {
  const int i = blockIdx.x * blockDim.x + threadIdx.x;
  if (i < n) p[i] = 0;
}

__global__ void sentinel_k(float* out, int n) {
  const int i = blockIdx.x * blockDim.x + threadIdx.x;
  if (i < n) out[i] = 1000.0f;
}

// ---------------------------------------------------------------------------
extern "C" void kernel_launch(void* const* d_in, const int* in_sizes, int n_in,
                              void* d_out, int out_size, void* d_ws, size_t ws_size,
                              hipStream_t stream) {
  const int*   x     = (const int*)d_in[0];
  const float* emb   = (const float*)d_in[1];
  const float* cW_ih = (const float*)d_in[2];
  const float* cW_hh = (const float*)d_in[3];
  const float* cb_ih = (const float*)d_in[4];
  const float* cb_hh = (const float*)d_in[5];
  const float* fW_ih = (const float*)d_in[6];
  const float* fW_hh = (const float*)d_in[7];
  const float* fb_ih = (const float*)d_in[8];
  const float* fb_hh = (const float*)d_in[9];
  const float* bW_ih = (const float*)d_in[10];
  const float* bW_hh = (const float*)d_in[11];
  const float* bb_ih = (const float*)d_in[12];
  const float* bb_hh = (const float*)d_in[13];
  const float* W1 = (const float*)d_in[14];
  const float* b1 = (const float*)d_in[15];
  const float* W2 = (const float*)d_in[16];
  const float* b2 = (const float*)d_in[17];
  const float* W3 = (const float*)d_in[18];
  const float* b3 = (const float*)d_in[19];
  float* out = (float*)d_out;
  (void)in_sizes; (void)n_in;

  char* ws = (char*)d_ws;
  size_t off = 0;
  auto alloc = [&](size_t bytes) -> char* {
    char* p = ws + off;
    off += (bytes + 255) & ~(size_t)255;
    return p;
  };
  int*            len_  = (int*)alloc((size_t)NW * 4);
  int*            aflag = (int*)alloc((size_t)2 * SEQ * 32 * FPAD * 4);   // 512KB
  unsigned short* embb  = (unsigned short*)alloc((size_t)100 * EDIM * 2);
  unsigned short* Wc_i  = (unsigned short*)alloc((size_t)1024 * 320 * 2);
  unsigned short* Wf_i  = (unsigned short*)alloc((size_t)2048 * 768 * 2);
  unsigned short* Wb_i  = (unsigned short*)alloc((size_t)2048 * 768 * 2);
  unsigned char*  Wf8   = (unsigned char*)alloc((size_t)2048 * 512);
  unsigned char*  Wb8   = (unsigned char*)alloc((size_t)2048 * 512);
  unsigned short* W1b   = (unsigned short*)alloc((size_t)256 * 1024 * 2);
  unsigned short* W2b   = (unsigned short*)alloc((size_t)256 * 256 * 2);
  unsigned short* W3p   = (unsigned short*)alloc((size_t)64 * 256 * 2);
  float*          bcT   = (float*)alloc(1024 * 4);
  float*          bf_i  = (float*)alloc(2048 * 4);
  float*          bb_i  = (float*)alloc(2048 * 4);
  unsigned short* lastT = (unsigned short*)alloc((size_t)NW * HC * 2);       // 8MB
  unsigned char*  hbL8  = (unsigned char*)alloc((size_t)2 * 2 * 32 * 128 * 16);
  unsigned short* hsW   = (unsigned short*)alloc((size_t)2 * 32 * 128 * 128 * 16 * 2);
  unsigned short* h1    = (unsigned short*)alloc((size_t)NW * HC * 2);       // 8MB
  unsigned short* h2    = (unsigned short*)alloc((size_t)NW * HC * 2);       // 8MB

  if (off > ws_size) {
    sentinel_k<<<(out_size + 255) / 256, 256, 0, stream>>>(out, out_size);
    return;
  }

  auto cdiv = [](long a, long b) { return (int)((a + b - 1) / b); };

  // ---- prep ----
  prep_w<<<1280, 256, 0, stream>>>(cW_ih, cW_hh, Wc_i, HC, EDIM, HC);
  prep_w<<<3072, 256, 0, stream>>>(fW_ih, fW_hh, Wf_i, HW, HC, HW);
  prep_w<<<3072, 256, 0, stream>>>(bW_ih, bW_hh, Wb_i, HW, HC, HW);
  prep_w8<<<2048, 256, 0, stream>>>(fW_hh, Wf8, HW, HW);
  prep_w8<<<2048, 256, 0, stream>>>(bW_hh, Wb8, HW, HW);
  prep_biasT<<<cdiv(1024, 256), 256, 0, stream>>>(cb_ih, cb_hh, bcT, HC);
  prep_bias<<<cdiv(2048, 256), 256, 0, stream>>>(fb_ih, fb_hh, bf_i, HW);
  prep_bias<<<cdiv(2048, 256), 256, 0, stream>>>(bb_ih, bb_hh, bb_i, HW);
  conv_bf<<<25, 256, 0, stream>>>(emb, embb, 100L * EDIM);
  conv_bf<<<1024, 256, 0, stream>>>(W1, W1b, 256L * 1024);
  conv_bf<<<256, 256, 0, stream>>>(W2, W2b, 256L * 256);
  prep_w3<<<64, 256, 0, stream>>>(W3, W3p);
  lengths_k<<<cdiv(NW, 256), 256, 0, stream>>>(x, len_);
  zero_k<<<cdiv(2 * SEQ * 32 * FPAD, 256), 256, 0, stream>>>(aflag, 2 * SEQ * 32 * FPAD);

  // ---- persistent char LSTM (1 launch, 32 words/block, 2 blocks/CU) ----
  char_lstm<<<NW / 32, 512, 0, stream>>>(x, embb, Wc_i, bcT, lastT, len_);

  // ---- persistent word BiLSTM (1 launch, r16 config, fp8 exchange) ----
  word_lstm<<<NWB, 256, 0, stream>>>(lastT, Wf_i, Wb_i, Wf8, Wb8, bf_i, bb_i,
                                     hbL8, hsW, aflag);

  // ---- MLP + fused logits/log_softmax ----
  mlp1_gemm<<<dim3(4, 128), 256, 0, stream>>>(hsW, W1b, b1, h1);
  mlp_gemm<<<dim3(4, 128), 256, 0, stream>>>(h1, 256, W2b, 256, b2, h2, 256, 8, 1);
  logits_fused<<<NW / 128, 256, 0, stream>>>(h2, W3p, b3, out);
}

// Round 19
// 1771.476 us; speedup vs baseline: 1.2648x; 1.1889x over previous
//
#include <hip/hip_runtime.h>
#include <hip/hip_bf16.h>
#include <math.h>

typedef __hip_bfloat16 bf16;
typedef __attribute__((ext_vector_type(8))) short bf16x8;   // 8 bf16 = 4 VGPR
typedef __attribute__((ext_vector_type(4))) float f32x4;
typedef long i64t;                                          // 8 fp8 = 2 VGPR

#define NW   16384
#define LC   20
#define EDIM 64
#define HC   256
#define HW   512
#define SEQ  128
#define NOUT 50
#define NWB  64      // word-kernel blocks (2 dirs x 32), must be co-resident
#define FPAD 16      // ints per flag (64B line)

// ---- fast transcendentals ----
#define LOG2E 1.4426950408889634f
__device__ __forceinline__ float fex2(float x) {
  float r; asm("v_exp_f32 %0, %1" : "=v"(r) : "v"(x)); return r;
}
__device__ __forceinline__ float frcp(float x) {
  float r; asm("v_rcp_f32 %0, %1" : "=v"(r) : "v"(x)); return r;
}
__device__ __forceinline__ float flog2(float x) {
  float r; asm("v_log_f32 %0, %1" : "=v"(r) : "v"(x)); return r;
}
__device__ __forceinline__ float fsig(float x) { return frcp(1.f + fex2(-LOG2E * x)); }
__device__ __forceinline__ float ftanh(float x) {
  return 1.f - 2.f * frcp(1.f + fex2(2.f * LOG2E * x));
}

__device__ __forceinline__ unsigned short f2bu(float f) {
  bf16 h = __float2bfloat16(f);
  return *reinterpret_cast<unsigned short*>(&h);
}
__device__ __forceinline__ bf16x8 ld8(const unsigned short* p) {
  return *reinterpret_cast<const bf16x8*>(p);
}
// Coherent (cross-XCD) plain ops: sc0 sc1 -> bypass L1+L2, hit LLC.
__device__ __forceinline__ i64t ld8sc8(const unsigned char* p) {   // 8B load
  i64t r;
  asm volatile("global_load_dwordx2 %0, %1, off sc0 sc1" : "=v"(r) : "v"(p));
  return r;
}
__device__ __forceinline__ void st8sc8(unsigned char* p, i64t v) { // 8B store
  asm volatile("global_store_dwordx2 %0, %1, off sc0 sc1" :: "v"(p), "v"(v) : "memory");
}
#define MFMA(a, b, c)  __builtin_amdgcn_mfma_f32_16x16x32_bf16(a, b, c, 0, 0, 0)
#define MFMA8(a, b, c) __builtin_amdgcn_mfma_f32_16x16x32_fp8_fp8(a, b, c, 0, 0, 0)

// ---------------------------------------------------------------------------
// Persistent char LSTM, TRANSPOSED compute, 32 WORDS/BLOCK, 512 threads
// (8 waves x 2 chunks). LDS 68.6 KB -> 2 blocks/CU (LDS-capped) = 4
// waves/SIMD for latency hiding. NO VGPR cap (r18's (512,4) forced 64 VGPR
// -> 1.8GB spill traffic). c-state in LDS; in-register gate update.
// ---------------------------------------------------------------------------
__global__ __launch_bounds__(512, 1) void char_lstm(
    const int* __restrict__ x, const unsigned short* __restrict__ embb,
    const unsigned short* __restrict__ Wc, const float* __restrict__ bcT,
    unsigned short* __restrict__ lastT, const int* __restrict__ len) {
  __shared__ unsigned short Hs[2][32][264];   // 33.8 KB
  __shared__ float Cs[256][34];               // 34.8 KB c-state
  const int tid = threadIdx.x;
  const int w = tid >> 6, l = tid & 63;       // w 0..7
  const int l16 = l & 15, lk8 = (l >> 4) * 8, q = l >> 4;
  const int w0 = blockIdx.x * 32;
  int lenw[2], lroww[2];
#pragma unroll
  for (int wh = 0; wh < 2; ++wh) {
    const int n = w0 + wh * 16 + l16;
    lenw[wh] = len[n];
    lroww[wh] = ((n & 127) * 128 + (n >> 7)) * HC;   // time-major row base
  }

  for (int t = 0; t < LC; ++t) {
    const int cur = t & 1, nxt = cur ^ 1;
    int xi[2];
#pragma unroll
    for (int wh = 0; wh < 2; ++wh) xi[wh] = x[(w0 + wh * 16 + l16) * LC + t];
#pragma unroll
    for (int c = 0; c < 2; ++c) {
      const int chg = w * 2 + c;                // chunk 0..15
      const int cc0 = chg * 64;                 // gate-col base
      f32x4 acc[2][4] = {};                     // [wh][gate]
#pragma unroll
      for (int kk = 0; kk < 2; ++kk) {          // K 0..63: embedding
        const int k = kk * 32 + lk8;
        const unsigned short* wp = Wc + (size_t)(cc0 + l16) * 320 + k;
        bf16x8 bv[4];
#pragma unroll
        for (int g = 0; g < 4; ++g) bv[g] = ld8(wp + g * 16 * 320);
        bf16x8 a0 = ld8(embb + (size_t)xi[0] * EDIM + k);
        bf16x8 a1 = ld8(embb + (size_t)xi[1] * EDIM + k);
#pragma unroll
        for (int g = 0; g < 4; ++g) {
          acc[0][g] = MFMA(bv[g], a0, acc[0][g]);
          acc[1][g] = MFMA(bv[g], a1, acc[1][g]);
        }
      }
      if (t > 0) {
#pragma unroll
        for (int kk = 2; kk < 10; ++kk) {       // K 64..319: h(t-1) from LDS
          const int k = kk * 32 + lk8;
          const unsigned short* wp = Wc + (size_t)(cc0 + l16) * 320 + k;
          bf16x8 bv[4];
#pragma unroll
          for (int g = 0; g < 4; ++g) bv[g] = ld8(wp + g * 16 * 320);
          bf16x8 a0 = ld8(&Hs[cur][l16][k - 64]);
          bf16x8 a1 = ld8(&Hs[cur][16 + l16][k - 64]);
#pragma unroll
          for (int g = 0; g < 4; ++g) {
            acc[0][g] = MFMA(bv[g], a0, acc[0][g]);
            acc[1][g] = MFMA(bv[g], a1, acc[1][g]);
          }
        }
      }
      // ---- update: lane owns units chg*16+q*4+e, words wh*16+l16 ----
      union { unsigned short s[4]; uint2 v; } hp[2];
#pragma unroll
      for (int e = 0; e < 4; ++e) {
        const int ug = chg * 16 + q * 4 + e;    // global unit
        const float4 bb = *reinterpret_cast<const float4*>(bcT + ug * 4);
#pragma unroll
        for (int wh = 0; wh < 2; ++wh) {
          const int wd = wh * 16 + l16;
          const float gi = acc[wh][0][e] + bb.x;
          const float gf = acc[wh][1][e] + bb.y;
          const float gg = acc[wh][2][e] + bb.z;
          const float go = acc[wh][3][e] + bb.w;
          const float cprev = t ? Cs[ug][wd] : 0.f;
          const float ccv = fsig(gf) * cprev + fsig(gi) * ftanh(gg);
          Cs[ug][wd] = ccv;
          hp[wh].s[e] = f2bu(fsig(go) * ftanh(ccv));
        }
      }
      const int uoff = chg * 16 + q * 4;        // 4-short aligned
#pragma unroll
      for (int wh = 0; wh < 2; ++wh) {
        *reinterpret_cast<uint2*>(&Hs[nxt][wh * 16 + l16][uoff]) = hp[wh].v;
        if (t == lenw[wh] - 1)
          *reinterpret_cast<uint2*>(lastT + lroww[wh] + uoff) = hp[wh].v;
        else if (lenw[wh] == 0 && t == 0)
          *reinterpret_cast<uint2*>(lastT + lroww[wh] + uoff) = make_uint2(0, 0);
      }
    }
    __syncthreads();   // Hs[nxt] complete before next step reads it
  }
}

// ---------------------------------------------------------------------------
// Persistent word BiLSTM (r16-proven): 64 blocks (dir = bx>>5, 16 units).
// x-weights bf16 (32KB) + h-weights fp8 (32KB) in LDS; h exchanged fp8 via
// sc0sc1 at LLC (half traffic), consumed by mfma fp8_fp8. In-register
// update -> bf16 (hsW) + fp8 (hbL8). Padded flag barrier.
// ---------------------------------------------------------------------------
__global__ __launch_bounds__(256, 1) void word_lstm(
    const unsigned short* __restrict__ lastT,   // [pos][128][HC] bf16
    const unsigned short* __restrict__ W16,     // bf16 gate-major (fwd)
    const unsigned short* __restrict__ W16b,    // (bwd)
    const unsigned char* __restrict__ W8f,      // fp8 gate-major (fwd)
    const unsigned char* __restrict__ W8b,      // (bwd)
    const float* __restrict__ bfi, const float* __restrict__ bbi,
    unsigned char* __restrict__ hbL8,   // [2][2][32][128][16] fp8
    unsigned short* __restrict__ hsW,   // [2][32][128 pos][128 b][16] bf16
    int* __restrict__ aflag) {          // [2][SEQ][32][FPAD]
  __shared__ unsigned short Wlds16[64 * 256];   // 32 KB x-part bf16
  __shared__ unsigned char  Wlds8[64 * 512];    // 32 KB h-part fp8
  __shared__ unsigned short ht[128][24];        // 6 KB bf16 transpose
  __shared__ unsigned char  ht8[128][24];       // 3 KB fp8 transpose
  const int tid = threadIdx.x;
  const int w = tid >> 6, l = tid & 63;
  const int l16 = l & 15, lk8 = (l >> 4) * 8, q = l >> 4;
  const int dir = blockIdx.x >> 5;
  const int nb = blockIdx.x & 31;
  const int c0 = nb * 64;
  const unsigned short* Wx = dir ? W16b : W16;
  const unsigned char*  Wh = dir ? W8b : W8f;
  const float* bias = dir ? bbi : bfi;
  for (int ci = tid; ci < 64 * 32; ci += 256) {
    const int col = ci >> 5, kc = (ci & 31) * 8;
    const int kcs = kc ^ ((col & 15) * 8);
    *reinterpret_cast<bf16x8*>(&Wlds16[col * 256 + kcs]) =
        ld8(Wx + (size_t)(c0 + col) * 768 + kc);
  }
  for (int ci = tid; ci < 64 * 64; ci += 256) {
    const int col = ci >> 6, kb = (ci & 63) * 8;
    const int kbs = kb ^ ((col & 15) * 8);
    *reinterpret_cast<i64t*>(&Wlds8[col * 512 + kbs]) =
        *reinterpret_cast<const i64t*>(Wh + (size_t)(c0 + col) * 512 + kb);
  }
  const float b0 = bias[c0 + 0 * 16 + l16];
  const float b1 = bias[c0 + 1 * 16 + l16];
  const float b2 = bias[c0 + 2 * 16 + l16];
  const float b3 = bias[c0 + 3 * 16 + l16];
  const int ksw = l16 * 8;
  float cst[8];
#pragma unroll
  for (int i = 0; i < 8; ++i) cst[i] = 0.f;
  __syncthreads();                      // LDS weights ready

  for (int t = 0; t < SEQ; ++t) {
    const int cur = t & 1;
    const int pos = dir ? (SEQ - 1 - t) : t;
    // ---- x-part: plain cached lastT loads, bf16 MFMA ----
    f32x4 acc[2][4] = {};
#pragma unroll
    for (int kk = 0; kk < 8; ++kk) {
      const int k = kk * 32 + lk8;
      bf16x8 a0 = ld8(lastT + ((size_t)pos * 128 + w * 32 + l16) * HC + k);
      bf16x8 a1 = ld8(lastT + ((size_t)pos * 128 + w * 32 + l16 + 16) * HC + k);
      const int ks = k ^ ksw;
#pragma unroll
      for (int nn = 0; nn < 4; ++nn) {
        bf16x8 bv = ld8(&Wlds16[(l16 + nn * 16) * 256 + ks]);
        acc[0][nn] = MFMA(a0, bv, acc[0][nn]);
        acc[1][nn] = MFMA(a1, bv, acc[1][nn]);
      }
    }
    if (t > 0) {
      if (w == 0) {                      // flag-barrier wait for step t-1
        const int* fp = aflag + (size_t)(dir * SEQ + (t - 1)) * 32 * FPAD;
        for (;;) {
          int v = 1;
          if (l < 32)
            v = __hip_atomic_load(fp + l * FPAD, __ATOMIC_RELAXED,
                                  __HIP_MEMORY_SCOPE_AGENT);
          if (__ballot(v != 0) == ~0ull) break;
          __builtin_amdgcn_s_sleep(1);
        }
      }
      __syncthreads();
      // ---- h loads (fp8, coherent 8B) + fp8 MFMA ----
      i64t af8[16][2];
      const unsigned char* hp =
          hbL8 + (size_t)(((cur ^ 1) * 2 + dir) * 32) * 128 * 16;
#pragma unroll
      for (int kk = 0; kk < 16; ++kk) {
        const int u = kk * 32 + lk8;
        const int nbs = u >> 4, ul = u & 15;
#pragma unroll
        for (int r = 0; r < 2; ++r) {
          const int bt = w * 32 + l16 + r * 16;
          af8[kk][r] = ld8sc8(hp + ((size_t)nbs * 128 + bt) * 16 + ul);
        }
      }
      asm volatile("s_waitcnt vmcnt(0)" ::: "memory");
      __builtin_amdgcn_sched_barrier(0);   // rule #18
#pragma unroll
      for (int kk = 0; kk < 16; ++kk) {
        const int ks8 = (kk * 32 + lk8) ^ ksw;
#pragma unroll
        for (int nn = 0; nn < 4; ++nn) {
          i64t w8 = *reinterpret_cast<const i64t*>(
              &Wlds8[(l16 + nn * 16) * 512 + ks8]);
          acc[0][nn] = MFMA8(af8[kk][0], w8, acc[0][nn]);
          acc[1][nn] = MFMA8(af8[kk][1], w8, acc[1][nn]);
        }
      }
    }
    // ---- in-register LSTM update (lane owns unit nb*16+l16, 8 batches) ----
    float hvf[8];
    int bats[8];
#pragma unroll
    for (int m = 0; m < 2; ++m)
#pragma unroll
      for (int e = 0; e < 4; ++e) {
        const int j = m * 4 + e;
        const float gi = acc[m][0][e] + b0;
        const float gf = acc[m][1][e] + b1;
        const float gg = acc[m][2][e] + b2;
        const float go = acc[m][3][e] + b3;
        const float ccv = fsig(gf) * cst[j] + fsig(gi) * ftanh(gg);
        cst[j] = ccv;
        const float hv = fsig(go) * ftanh(ccv);
        const int bat = w * 32 + q * 4 + e + m * 16;    // 0..127
        ht[bat][l16] = f2bu(hv);
        hvf[j] = hv; bats[j] = bat;
      }
    {
      const int d0 = __builtin_amdgcn_cvt_pk_fp8_f32(hvf[0], hvf[1], 0, false);
      const int d1 = __builtin_amdgcn_cvt_pk_fp8_f32(hvf[2], hvf[3], 0, false);
      const int d2 = __builtin_amdgcn_cvt_pk_fp8_f32(hvf[4], hvf[5], 0, false);
      const int d3 = __builtin_amdgcn_cvt_pk_fp8_f32(hvf[6], hvf[7], 0, false);
      ht8[bats[0]][l16] = (unsigned char)(d0 & 255);
      ht8[bats[1]][l16] = (unsigned char)((d0 >> 8) & 255);
      ht8[bats[2]][l16] = (unsigned char)(d1 & 255);
      ht8[bats[3]][l16] = (unsigned char)((d1 >> 8) & 255);
      ht8[bats[4]][l16] = (unsigned char)(d2 & 255);
      ht8[bats[5]][l16] = (unsigned char)((d2 >> 8) & 255);
      ht8[bats[6]][l16] = (unsigned char)(d3 & 255);
      ht8[bats[7]][l16] = (unsigned char)((d3 >> 8) & 255);
    }
    __syncthreads();
    // ---- coalesced write-back; flag chain: hbL8 store -> drain -> flag ----
    const int ub = tid >> 1, uh = tid & 1;
    i64t hv8 = *reinterpret_cast<const i64t*>(&ht8[ub][uh * 8]);
    st8sc8(hbL8 + (size_t)((cur * 2 + dir) * 32 + nb) * 128 * 16
               + ub * 16 + uh * 8, hv8);
    if (t < SEQ - 1) {
      asm volatile("s_waitcnt vmcnt(0)" ::: "memory");
      __syncthreads();
      if (tid == 0)
        __hip_atomic_store(aflag + ((size_t)(dir * SEQ + t) * 32 + nb) * FPAD, 1,
                           __ATOMIC_RELAXED, __HIP_MEMORY_SCOPE_AGENT);
    }
    // hsW store AFTER the flag: off the cross-block critical chain
    bf16x8 hv = ld8(&ht[ub][uh * 8]);
    *reinterpret_cast<bf16x8*>(
        hsW + (((size_t)(dir * 32 + nb) * 128 + pos) * 128 + ub) * 16 + uh * 8) = hv;
  }
}

// ---------------------------------------------------------------------------
// MLP layer 1: A gathered from hsW layout. out = relu(A @ W1^T + b1).
// ---------------------------------------------------------------------------
__global__ __launch_bounds__(256) void mlp1_gemm(
    const unsigned short* __restrict__ hsW, const unsigned short* __restrict__ W1b,
    const float* __restrict__ bias, unsigned short* __restrict__ out) {
  const int tid = threadIdx.x;
  const int w = tid >> 6, l = tid & 63;
  const int l16 = l & 15, lk8 = (l >> 4) * 8;
  const int by = blockIdx.y;                   // batch
  const int row0 = by * 128 + w * 32;
  const int col0 = blockIdx.x * 64;
  f32x4 acc[2][4] = {};
  for (int kk = 0; kk < 32; ++kk) {
    const int k = kk * 32 + lk8;               // 0..1023
    const int dirk = k >> 9, u = k & 511, nbs = u >> 4, ul = u & 15;
    const int p0 = w * 32 + l16, p1 = p0 + 16; // pos within batch
    bf16x8 a0 = ld8(hsW + (((size_t)(dirk * 32 + nbs) * 128 + p0) * 128 + by) * 16 + ul);
    bf16x8 a1 = ld8(hsW + (((size_t)(dirk * 32 + nbs) * 128 + p1) * 128 + by) * 16 + ul);
    const unsigned short* wp = W1b + (size_t)(col0 + l16) * 1024 + k;
#pragma unroll
    for (int nn = 0; nn < 4; ++nn) {
      bf16x8 bv = ld8(wp + nn * 16 * 1024);
      acc[0][nn] = MFMA(a0, bv, acc[0][nn]);
      acc[1][nn] = MFMA(a1, bv, acc[1][nn]);
    }
  }
  const int cr = (l >> 4) * 4;
#pragma unroll
  for (int m = 0; m < 2; ++m)
#pragma unroll
    for (int nn = 0; nn < 4; ++nn)
#pragma unroll
      for (int e = 0; e < 4; ++e) {
        const int r = row0 + m * 16 + cr + e;
        const int c = col0 + nn * 16 + l16;
        out[(size_t)r * 256 + c] = f2bu(fmaxf(acc[m][nn][e] + bias[c], 0.f));
      }
}

// ---------------------------------------------------------------------------
// MLP layer 2 (row-major A): out = relu(A @ W2^T + b2).
// ---------------------------------------------------------------------------
__global__ __launch_bounds__(256) void mlp_gemm(
    const unsigned short* __restrict__ A, int lda,
    const unsigned short* __restrict__ W, int ldw,
    const float* __restrict__ bias, unsigned short* __restrict__ out,
    int ldo, int nk, int relu) {
  const int tid = threadIdx.x;
  const int w = tid >> 6, l = tid & 63;
  const int l16 = l & 15, lk8 = (l >> 4) * 8;
  const int row0 = blockIdx.y * 128 + w * 32;
  const int col0 = blockIdx.x * 64;
  f32x4 acc[2][4] = {};
  for (int kk = 0; kk < nk; ++kk) {
    const int k = kk * 32 + lk8;
    bf16x8 a0 = ld8(A + (size_t)(row0 + l16) * lda + k);
    bf16x8 a1 = ld8(A + (size_t)(row0 + 16 + l16) * lda + k);
    const unsigned short* wp = W + (size_t)(col0 + l16) * ldw + k;
    bf16x8 bb[4];
#pragma unroll
    for (int nn = 0; nn < 4; ++nn) bb[nn] = ld8(wp + nn * 16 * ldw);
#pragma unroll
    for (int nn = 0; nn < 4; ++nn) {
      acc[0][nn] = MFMA(a0, bb[nn], acc[0][nn]);
      acc[1][nn] = MFMA(a1, bb[nn], acc[1][nn]);
    }
  }
  const int cr = (l >> 4) * 4;
#pragma unroll
  for (int m = 0; m < 2; ++m)
#pragma unroll
    for (int nn = 0; nn < 4; ++nn)
#pragma unroll
      for (int e = 0; e < 4; ++e) {
        const int r = row0 + m * 16 + cr + e;
        const int c = col0 + nn * 16 + l16;
        float v = acc[m][nn][e] + bias[c];
        if (relu) v = fmaxf(v, 0.f);
        out[(size_t)r * ldo + c] = f2bu(v);
      }
}

// ---------------------------------------------------------------------------
// Logits (MFMA, N=64 padded) + log_softmax over 50, fused. 128 rows/block.
// ---------------------------------------------------------------------------
__global__ __launch_bounds__(256) void logits_fused(
    const unsigned short* __restrict__ h2, const unsigned short* __restrict__ W3p,
    const float* __restrict__ b3, float* __restrict__ out) {
  __shared__ float gt[128][68];
  __shared__ float lseb[128];
  const int tid = threadIdx.x;
  const int w = tid >> 6, l = tid & 63;
  const int l16 = l & 15, lk8 = (l >> 4) * 8;
  const int r0 = blockIdx.x * 128;
  const int rr0 = w * 32 + l16, rr1 = rr0 + 16;
  f32x4 acc[2][4] = {};
#pragma unroll
  for (int kk = 0; kk < 8; ++kk) {
    const int k = kk * 32 + lk8;
    bf16x8 a0 = ld8(h2 + (size_t)(r0 + rr0) * 256 + k);
    bf16x8 a1 = ld8(h2 + (size_t)(r0 + rr1) * 256 + k);
#pragma unroll
    for (int nn = 0; nn < 4; ++nn) {
      bf16x8 bv = ld8(W3p + (size_t)(nn * 16 + l16) * 256 + k);
      acc[0][nn] = MFMA(a0, bv, acc[0][nn]);
      acc[1][nn] = MFMA(a1, bv, acc[1][nn]);
    }
  }
  const int cr = (l >> 4) * 4;
#pragma unroll
  for (int m = 0; m < 2; ++m)
#pragma unroll
    for (int nn = 0; nn < 4; ++nn)
#pragma unroll
      for (int e = 0; e < 4; ++e) {
        const int col = nn * 16 + l16;
        gt[w * 32 + m * 16 + cr + e][col] =
            acc[m][nn][e] + (col < NOUT ? b3[col] : 0.f);
      }
  __syncthreads();
  if (tid < 128) {
    float mx = -INFINITY;
#pragma unroll
    for (int j = 0; j < NOUT; ++j) mx = fmaxf(mx, gt[tid][j]);
    float s = 0.f;
#pragma unroll
    for (int j = 0; j < NOUT; ++j) s += fex2(LOG2E * (gt[tid][j] - mx));
    lseb[tid] = flog2(s) * 0.6931471805599453f + mx;
  }
  __syncthreads();
  for (int idx = tid; idx < 128 * NOUT; idx += 256) {
    const int r = idx / NOUT, j = idx - r * NOUT;
    out[(size_t)(r0 + r) * NOUT + j] = gt[r][j] - lseb[r];
  }
}

// ---------------------------------------------------------------------------
// Prep kernels
// ---------------------------------------------------------------------------
__global__ void prep_w(const float* __restrict__ ih, const float* __restrict__ hh,
                       unsigned short* __restrict__ dst, int HU, int KI, int KH) {
  const int K = KI + KH;
  const long tot = (long)HU * 4 * K;
  for (long idx = (long)blockIdx.x * blockDim.x + threadIdx.x; idx < tot;
       idx += (long)gridDim.x * blockDim.x) {
    const int row = (int)(idx / K), k = (int)(idx % K);
    const int chunk = row >> 6, c = row & 63;
    const int g = c >> 4, u = chunk * 16 + (c & 15);
    const float v = (k < KI) ? ih[(size_t)(g * HU + u) * KI + k]
                             : hh[(size_t)(g * HU + u) * KH + (k - KI)];
    dst[idx] = f2bu(v);
  }
}

// fp8 h-part weights: dst[row][k] e4m3, row gate-major, k in [0,KH)
__global__ void prep_w8(const float* __restrict__ hh, unsigned char* __restrict__ dst,
                        int HU, int KH) {
  const long tot = (long)HU * 4 * (KH / 2);
  for (long p = (long)blockIdx.x * blockDim.x + threadIdx.x; p < tot;
       p += (long)gridDim.x * blockDim.x) {
    const int row = (int)(p / (KH / 2)), kp = (int)(p % (KH / 2)) * 2;
    const int chunk = row >> 6, c = row & 63;
    const int g = c >> 4, u = chunk * 16 + (c & 15);
    const float a = hh[(size_t)(g * HU + u) * KH + kp];
    const float b = hh[(size_t)(g * HU + u) * KH + kp + 1];
    const int d = __builtin_amdgcn_cvt_pk_fp8_f32(a, b, 0, false);
    *reinterpret_cast<unsigned short*>(dst + (size_t)row * KH + kp) =
        (unsigned short)(d & 0xFFFF);
  }
}

__global__ void prep_bias(const float* bih, const float* bhh, float* dst, int HU) {
  const int idx = blockIdx.x * blockDim.x + threadIdx.x;   // gate-major flat
  if (idx < 4 * HU) {
    const int chunk = idx >> 6, c = idx & 63;
    const int g = c >> 4, u = chunk * 16 + (c & 15);
    dst[idx] = bih[g * HU + u] + bhh[g * HU + u];
  }
}

// char bias: bcT[u*4 + g]
__global__ void prep_biasT(const float* bih, const float* bhh, float* dst, int HU) {
  const int idx = blockIdx.x * blockDim.x + threadIdx.x;
  if (idx < 4 * HU) {
    const int u = idx >> 2, g = idx & 3;
    dst[idx] = bih[g * HU + u] + bhh[g * HU + u];
  }
}

__global__ void conv_bf(const float* __restrict__ src, unsigned short* __restrict__ dst,
                        long n) {
  for (long i = (long)blockIdx.x * blockDim.x + threadIdx.x; i < n;
       i += (long)gridDim.x * blockDim.x)
    dst[i] = f2bu(src[i]);
}

__global__ void prep_w3(const float* __restrict__ W3, unsigned short* __restrict__ dst) {
  const int i = blockIdx.x * blockDim.x + threadIdx.x;   // 64*256
  if (i < 64 * 256) {
    const int r = i >> 8;
    dst[i] = (r < NOUT) ? f2bu(W3[i]) : 0;
  }
}

__global__ void lengths_k(const int* x, int* len) {
  const int n = blockIdx.x * blockDim.x + threadIdx.x;
  if (n < NW) {
    int c = 0;
#pragma unroll
    for (int l = 0; l < LC; ++l) c += (x[(size_t)n * LC + l] != 0) ? 1 : 0;
    len[n] = c;
  }
}

__global__ void zero_k(int* p, int n) {
  const int i = blockIdx.x * blockDim.x + threadIdx.x;
  if (i < n) p[i] = 0;
}

__global__ void sentinel_k(float* out, int n) {
  const int i = blockIdx.x * blockDim.x + threadIdx.x;
  if (i < n) out[i] = 1000.0f;
}

// ---------------------------------------------------------------------------
extern "C" void kernel_launch(void* const* d_in, const int* in_sizes, int n_in,
                              void* d_out, int out_size, void* d_ws, size_t ws_size,
                              hipStream_t stream) {
  const int*   x     = (const int*)d_in[0];
  const float* emb   = (const float*)d_in[1];
  const float* cW_ih = (const float*)d_in[2];
  const float* cW_hh = (const float*)d_in[3];
  const float* cb_ih = (const float*)d_in[4];
  const float* cb_hh = (const float*)d_in[5];
  const float* fW_ih = (const float*)d_in[6];
  const float* fW_hh = (const float*)d_in[7];
  const float* fb_ih = (const float*)d_in[8];
  const float* fb_hh = (const float*)d_in[9];
  const float* bW_ih = (const float*)d_in[10];
  const float* bW_hh = (const float*)d_in[11];
  const float* bb_ih = (const float*)d_in[12];
  const float* bb_hh = (const float*)d_in[13];
  const float* W1 = (const float*)d_in[14];
  const float* b1 = (const float*)d_in[15];
  const float* W2 = (const float*)d_in[16];
  const float* b2 = (const float*)d_in[17];
  const float* W3 = (const float*)d_in[18];
  const float* b3 = (const float*)d_in[19];
  float* out = (float*)d_out;
  (void)in_sizes; (void)n_in;

  char* ws = (char*)d_ws;
  size_t off = 0;
  auto alloc = [&](size_t bytes) -> char* {
    char* p = ws + off;
    off += (bytes + 255) & ~(size_t)255;
    return p;
  };
  int*            len_  = (int*)alloc((size_t)NW * 4);
  int*            aflag = (int*)alloc((size_t)2 * SEQ * 32 * FPAD * 4);   // 512KB
  unsigned short* embb  = (unsigned short*)alloc((size_t)100 * EDIM * 2);
  unsigned short* Wc_i  = (unsigned short*)alloc((size_t)1024 * 320 * 2);
  unsigned short* Wf_i  = (unsigned short*)alloc((size_t)2048 * 768 * 2);
  unsigned short* Wb_i  = (unsigned short*)alloc((size_t)2048 * 768 * 2);
  unsigned char*  Wf8   = (unsigned char*)alloc((size_t)2048 * 512);
  unsigned char*  Wb8   = (unsigned char*)alloc((size_t)2048 * 512);
  unsigned short* W1b   = (unsigned short*)alloc((size_t)256 * 1024 * 2);
  unsigned short* W2b   = (unsigned short*)alloc((size_t)256 * 256 * 2);
  unsigned short* W3p   = (unsigned short*)alloc((size_t)64 * 256 * 2);
  float*          bcT   = (float*)alloc(1024 * 4);
  float*          bf_i  = (float*)alloc(2048 * 4);
  float*          bb_i  = (float*)alloc(2048 * 4);
  unsigned short* lastT = (unsigned short*)alloc((size_t)NW * HC * 2);       // 8MB
  unsigned char*  hbL8  = (unsigned char*)alloc((size_t)2 * 2 * 32 * 128 * 16);
  unsigned short* hsW   = (unsigned short*)alloc((size_t)2 * 32 * 128 * 128 * 16 * 2);
  unsigned short* h1    = (unsigned short*)alloc((size_t)NW * HC * 2);       // 8MB
  unsigned short* h2    = (unsigned short*)alloc((size_t)NW * HC * 2);       // 8MB

  if (off > ws_size) {
    sentinel_k<<<(out_size + 255) / 256, 256, 0, stream>>>(out, out_size);
    return;
  }

  auto cdiv = [](long a, long b) { return (int)((a + b - 1) / b); };

  // ---- prep ----
  prep_w<<<1280, 256, 0, stream>>>(cW_ih, cW_hh, Wc_i, HC, EDIM, HC);
  prep_w<<<3072, 256, 0, stream>>>(fW_ih, fW_hh, Wf_i, HW, HC, HW);
  prep_w<<<3072, 256, 0, stream>>>(bW_ih, bW_hh, Wb_i, HW, HC, HW);
  prep_w8<<<2048, 256, 0, stream>>>(fW_hh, Wf8, HW, HW);
  prep_w8<<<2048, 256, 0, stream>>>(bW_hh, Wb8, HW, HW);
  prep_biasT<<<cdiv(1024, 256), 256, 0, stream>>>(cb_ih, cb_hh, bcT, HC);
  prep_bias<<<cdiv(2048, 256), 256, 0, stream>>>(fb_ih, fb_hh, bf_i, HW);
  prep_bias<<<cdiv(2048, 256), 256, 0, stream>>>(bb_ih, bb_hh, bb_i, HW);
  conv_bf<<<25, 256, 0, stream>>>(emb, embb, 100L * EDIM);
  conv_bf<<<1024, 256, 0, stream>>>(W1, W1b, 256L * 1024);
  conv_bf<<<256, 256, 0, stream>>>(W2, W2b, 256L * 256);
  prep_w3<<<64, 256, 0, stream>>>(W3, W3p);
  lengths_k<<<cdiv(NW, 256), 256, 0, stream>>>(x, len_);
  zero_k<<<cdiv(2 * SEQ * 32 * FPAD, 256), 256, 0, stream>>>(aflag, 2 * SEQ * 32 * FPAD);

  // ---- persistent char LSTM (1 launch, 32 words/block, no VGPR cap) ----
  char_lstm<<<NW / 32, 512, 0, stream>>>(x, embb, Wc_i, bcT, lastT, len_);

  // ---- persistent word BiLSTM (1 launch, r16 config, fp8 exchange) ----
  word_lstm<<<NWB, 256, 0, stream>>>(lastT, Wf_i, Wb_i, Wf8, Wb8, bf_i, bb_i,
                                     hbL8, hsW, aflag);

  // ---- MLP + fused logits/log_softmax ----
  mlp1_gemm<<<dim3(4, 128), 256, 0, stream>>>(hsW, W1b, b1, h1);
  mlp_gemm<<<dim3(4, 128), 256, 0, stream>>>(h1, 256, W2b, 256, b2, h2, 256, 8, 1);
  logits_fused<<<NW / 128, 256, 0, stream>>>(h2, W3p, b3, out);
}

// Round 20
// 1565.283 us; speedup vs baseline: 1.4314x; 1.1317x over previous
//
#include <hip/hip_runtime.h>
#include <hip/hip_bf16.h>
#include <math.h>

typedef __hip_bfloat16 bf16;
typedef __attribute__((ext_vector_type(8))) short bf16x8;   // 8 bf16 = 4 VGPR
typedef __attribute__((ext_vector_type(4))) float f32x4;
typedef long i64t;                                          // 8 fp8 = 2 VGPR

#define NW   16384
#define LC   20
#define EDIM 64
#define HC   256
#define HW   512
#define SEQ  128
#define NOUT 50
#define NWB  64      // word-kernel blocks (2 dirs x 32), must be co-resident
#define FPAD 16      // ints per flag (64B line)

// ---- fast transcendentals ----
#define LOG2E 1.4426950408889634f
__device__ __forceinline__ float fex2(float x) {
  float r; asm("v_exp_f32 %0, %1" : "=v"(r) : "v"(x)); return r;
}
__device__ __forceinline__ float frcp(float x) {
  float r; asm("v_rcp_f32 %0, %1" : "=v"(r) : "v"(x)); return r;
}
__device__ __forceinline__ float flog2(float x) {
  float r; asm("v_log_f32 %0, %1" : "=v"(r) : "v"(x)); return r;
}
__device__ __forceinline__ float fsig(float x) { return frcp(1.f + fex2(-LOG2E * x)); }
__device__ __forceinline__ float ftanh(float x) {
  return 1.f - 2.f * frcp(1.f + fex2(2.f * LOG2E * x));
}

__device__ __forceinline__ unsigned short f2bu(float f) {
  bf16 h = __float2bfloat16(f);
  return *reinterpret_cast<unsigned short*>(&h);
}
__device__ __forceinline__ bf16x8 ld8(const unsigned short* p) {
  return *reinterpret_cast<const bf16x8*>(p);
}
// Coherent (cross-XCD) plain ops: sc0 sc1 -> bypass L1+L2, hit LLC.
__device__ __forceinline__ i64t ld8sc8(const unsigned char* p) {   // 8B load
  i64t r;
  asm volatile("global_load_dwordx2 %0, %1, off sc0 sc1" : "=v"(r) : "v"(p));
  return r;
}
__device__ __forceinline__ void st8sc8(unsigned char* p, i64t v) { // 8B store
  asm volatile("global_store_dwordx2 %0, %1, off sc0 sc1" :: "v"(p), "v"(v) : "memory");
}
#define MFMA(a, b, c)  __builtin_amdgcn_mfma_f32_16x16x32_bf16(a, b, c, 0, 0, 0)
#define MFMA8(a, b, c) __builtin_amdgcn_mfma_f32_16x16x32_fp8_fp8(a, b, c, 0, 0, 0)

// ---------------------------------------------------------------------------
// Persistent char LSTM (r16 geometry): 64 words/block, 512 threads (8 waves
// x 2 chunks). c-state in LDS. lastT written DEFERRED at step end as full
// 512B rows (8 thr x 64B per finishing word) -> no partial-line RMW
// (r16 had 205MB WRITE / 25x amplification from scattered 8B stores).
// ---------------------------------------------------------------------------
__global__ __launch_bounds__(512, 1) void char_lstm(
    const int* __restrict__ x, const unsigned short* __restrict__ embb,
    const unsigned short* __restrict__ Wc, const float* __restrict__ bcT,
    unsigned short* __restrict__ lastT, const int* __restrict__ len) {
  __shared__ unsigned short Hs[2][64][264];   // 67.6 KB
  __shared__ float Cs[256][66];               // 67.6 KB c-state
  __shared__ int lenS[64];
  const int tid = threadIdx.x;
  const int w = tid >> 6, l = tid & 63;       // w 0..7
  const int l16 = l & 15, lk8 = (l >> 4) * 8, q = l >> 4;
  const int w0 = blockIdx.x * 64;
  if (tid < 64) lenS[tid] = len[w0 + tid];
  // (first use of lenS is after the first in-loop __syncthreads)

  for (int t = 0; t < LC; ++t) {
    const int cur = t & 1, nxt = cur ^ 1;
    int xi[4];
#pragma unroll
    for (int wh = 0; wh < 4; ++wh) xi[wh] = x[(w0 + wh * 16 + l16) * LC + t];
#pragma unroll
    for (int c = 0; c < 2; ++c) {
      const int chg = w * 2 + c;                // chunk 0..15
      const int cc0 = chg * 64;                 // gate-col base
      f32x4 acc[4][4] = {};                     // [wh][gate]
#pragma unroll
      for (int kk = 0; kk < 2; ++kk) {          // K 0..63: embedding
        const int k = kk * 32 + lk8;
        const unsigned short* wp = Wc + (size_t)(cc0 + l16) * 320 + k;
        bf16x8 bv[4];
#pragma unroll
        for (int g = 0; g < 4; ++g) bv[g] = ld8(wp + g * 16 * 320);
#pragma unroll
        for (int wh = 0; wh < 4; ++wh) {
          bf16x8 a = ld8(embb + (size_t)xi[wh] * EDIM + k);
#pragma unroll
          for (int g = 0; g < 4; ++g) acc[wh][g] = MFMA(bv[g], a, acc[wh][g]);
        }
      }
      if (t > 0) {
#pragma unroll
        for (int kk = 2; kk < 10; ++kk) {       // K 64..319: h(t-1) from LDS
          const int k = kk * 32 + lk8;
          const unsigned short* wp = Wc + (size_t)(cc0 + l16) * 320 + k;
          bf16x8 bv[4];
#pragma unroll
          for (int g = 0; g < 4; ++g) bv[g] = ld8(wp + g * 16 * 320);
#pragma unroll
          for (int wh = 0; wh < 4; ++wh) {
            bf16x8 a = ld8(&Hs[cur][wh * 16 + l16][k - 64]);
#pragma unroll
            for (int g = 0; g < 4; ++g) acc[wh][g] = MFMA(bv[g], a, acc[wh][g]);
          }
        }
      }
      // ---- update: lane owns units chg*16+q*4+e, words wh*16+l16 ----
      union { unsigned short s[4]; uint2 v; } hp[4];
#pragma unroll
      for (int e = 0; e < 4; ++e) {
        const int ug = chg * 16 + q * 4 + e;    // global unit
        const float4 bb = *reinterpret_cast<const float4*>(bcT + ug * 4);
#pragma unroll
        for (int wh = 0; wh < 4; ++wh) {
          const int wd = wh * 16 + l16;
          const float gi = acc[wh][0][e] + bb.x;
          const float gf = acc[wh][1][e] + bb.y;
          const float gg = acc[wh][2][e] + bb.z;
          const float go = acc[wh][3][e] + bb.w;
          const float cprev = t ? Cs[ug][wd] : 0.f;
          const float ccv = fsig(gf) * cprev + fsig(gi) * ftanh(gg);
          Cs[ug][wd] = ccv;
          hp[wh].s[e] = f2bu(fsig(go) * ftanh(ccv));
        }
      }
      const int uoff = chg * 16 + q * 4;        // 4-short aligned
#pragma unroll
      for (int wh = 0; wh < 4; ++wh)
        *reinterpret_cast<uint2*>(&Hs[nxt][wh * 16 + l16][uoff]) = hp[wh].v;
    }
    __syncthreads();   // Hs[nxt] complete (and lenS ready after t=0)
    // ---- deferred, coalesced lastT write for words finishing at step t ----
    {
      const int wd = tid >> 3, sub = tid & 7;   // 64 words x 8 threads
      const int myl = lenS[wd];
      if (myl == t + 1 || (myl == 0 && t == 0)) {
        const int n = w0 + wd;
        const int lrow = ((n & 127) * 128 + (n >> 7)) * HC;  // time-major row
        if (myl == 0) {
          bf16x8 z = {};
#pragma unroll
          for (int j = 0; j < 4; ++j)
            *reinterpret_cast<bf16x8*>(lastT + lrow + sub * 32 + j * 8) = z;
        } else {
#pragma unroll
          for (int j = 0; j < 4; ++j)
            *reinterpret_cast<bf16x8*>(lastT + lrow + sub * 32 + j * 8) =
                ld8(&Hs[nxt][wd][sub * 32 + j * 8]);
        }
      }
    }
  }
}

// ---------------------------------------------------------------------------
// Persistent word BiLSTM (r16-proven): 64 blocks (dir = bx>>5, 16 units).
// x-weights bf16 (32KB) + h-weights fp8 (32KB) in LDS; h exchanged fp8 via
// sc0sc1 at LLC (half traffic), consumed by mfma fp8_fp8. In-register
// update -> bf16 (hsW) + fp8 (hbL8). Padded flag barrier.
// ---------------------------------------------------------------------------
__global__ __launch_bounds__(256, 1) void word_lstm(
    const unsigned short* __restrict__ lastT,   // [pos][128][HC] bf16
    const unsigned short* __restrict__ W16,     // bf16 gate-major (fwd)
    const unsigned short* __restrict__ W16b,    // (bwd)
    const unsigned char* __restrict__ W8f,      // fp8 gate-major (fwd)
    const unsigned char* __restrict__ W8b,      // (bwd)
    const float* __restrict__ bfi, const float* __restrict__ bbi,
    unsigned char* __restrict__ hbL8,   // [2][2][32][128][16] fp8
    unsigned short* __restrict__ hsW,   // [2][32][128 pos][128 b][16] bf16
    int* __restrict__ aflag) {          // [2][SEQ][32][FPAD]
  __shared__ unsigned short Wlds16[64 * 256];   // 32 KB x-part bf16
  __shared__ unsigned char  Wlds8[64 * 512];    // 32 KB h-part fp8
  __shared__ unsigned short ht[128][24];        // 6 KB bf16 transpose
  __shared__ unsigned char  ht8[128][24];       // 3 KB fp8 transpose
  const int tid = threadIdx.x;
  const int w = tid >> 6, l = tid & 63;
  const int l16 = l & 15, lk8 = (l >> 4) * 8, q = l >> 4;
  const int dir = blockIdx.x >> 5;
  const int nb = blockIdx.x & 31;
  const int c0 = nb * 64;
  const unsigned short* Wx = dir ? W16b : W16;
  const unsigned char*  Wh = dir ? W8b : W8f;
  const float* bias = dir ? bbi : bfi;
  for (int ci = tid; ci < 64 * 32; ci += 256) {
    const int col = ci >> 5, kc = (ci & 31) * 8;
    const int kcs = kc ^ ((col & 15) * 8);
    *reinterpret_cast<bf16x8*>(&Wlds16[col * 256 + kcs]) =
        ld8(Wx + (size_t)(c0 + col) * 768 + kc);
  }
  for (int ci = tid; ci < 64 * 64; ci += 256) {
    const int col = ci >> 6, kb = (ci & 63) * 8;
    const int kbs = kb ^ ((col & 15) * 8);
    *reinterpret_cast<i64t*>(&Wlds8[col * 512 + kbs]) =
        *reinterpret_cast<const i64t*>(Wh + (size_t)(c0 + col) * 512 + kb);
  }
  const float b0 = bias[c0 + 0 * 16 + l16];
  const float b1 = bias[c0 + 1 * 16 + l16];
  const float b2 = bias[c0 + 2 * 16 + l16];
  const float b3 = bias[c0 + 3 * 16 + l16];
  const int ksw = l16 * 8;
  float cst[8];
#pragma unroll
  for (int i = 0; i < 8; ++i) cst[i] = 0.f;
  __syncthreads();                      // LDS weights ready

  for (int t = 0; t < SEQ; ++t) {
    const int cur = t & 1;
    const int pos = dir ? (SEQ - 1 - t) : t;
    // ---- x-part: plain cached lastT loads, bf16 MFMA ----
    f32x4 acc[2][4] = {};
#pragma unroll
    for (int kk = 0; kk < 8; ++kk) {
      const int k = kk * 32 + lk8;
      bf16x8 a0 = ld8(lastT + ((size_t)pos * 128 + w * 32 + l16) * HC + k);
      bf16x8 a1 = ld8(lastT + ((size_t)pos * 128 + w * 32 + l16 + 16) * HC + k);
      const int ks = k ^ ksw;
#pragma unroll
      for (int nn = 0; nn < 4; ++nn) {
        bf16x8 bv = ld8(&Wlds16[(l16 + nn * 16) * 256 + ks]);
        acc[0][nn] = MFMA(a0, bv, acc[0][nn]);
        acc[1][nn] = MFMA(a1, bv, acc[1][nn]);
      }
    }
    if (t > 0) {
      if (w == 0) {                      // flag-barrier wait for step t-1
        const int* fp = aflag + (size_t)(dir * SEQ + (t - 1)) * 32 * FPAD;
        for (;;) {
          int v = 1;
          if (l < 32)
            v = __hip_atomic_load(fp + l * FPAD, __ATOMIC_RELAXED,
                                  __HIP_MEMORY_SCOPE_AGENT);
          if (__ballot(v != 0) == ~0ull) break;
          __builtin_amdgcn_s_sleep(1);
        }
      }
      __syncthreads();
      // ---- h loads (fp8, coherent 8B) + fp8 MFMA ----
      i64t af8[16][2];
      const unsigned char* hp =
          hbL8 + (size_t)(((cur ^ 1) * 2 + dir) * 32) * 128 * 16;
#pragma unroll
      for (int kk = 0; kk < 16; ++kk) {
        const int u = kk * 32 + lk8;
        const int nbs = u >> 4, ul = u & 15;
#pragma unroll
        for (int r = 0; r < 2; ++r) {
          const int bt = w * 32 + l16 + r * 16;
          af8[kk][r] = ld8sc8(hp + ((size_t)nbs * 128 + bt) * 16 + ul);
        }
      }
      asm volatile("s_waitcnt vmcnt(0)" ::: "memory");
      __builtin_amdgcn_sched_barrier(0);   // rule #18
#pragma unroll
      for (int kk = 0; kk < 16; ++kk) {
        const int ks8 = (kk * 32 + lk8) ^ ksw;
#pragma unroll
        for (int nn = 0; nn < 4; ++nn) {
          i64t w8 = *reinterpret_cast<const i64t*>(
              &Wlds8[(l16 + nn * 16) * 512 + ks8]);
          acc[0][nn] = MFMA8(af8[kk][0], w8, acc[0][nn]);
          acc[1][nn] = MFMA8(af8[kk][1], w8, acc[1][nn]);
        }
      }
    }
    // ---- in-register LSTM update (lane owns unit nb*16+l16, 8 batches) ----
    float hvf[8];
    int bats[8];
#pragma unroll
    for (int m = 0; m < 2; ++m)
#pragma unroll
      for (int e = 0; e < 4; ++e) {
        const int j = m * 4 + e;
        const float gi = acc[m][0][e] + b0;
        const float gf = acc[m][1][e] + b1;
        const float gg = acc[m][2][e] + b2;
        const float go = acc[m][3][e] + b3;
        const float ccv = fsig(gf) * cst[j] + fsig(gi) * ftanh(gg);
        cst[j] = ccv;
        const float hv = fsig(go) * ftanh(ccv);
        const int bat = w * 32 + q * 4 + e + m * 16;    // 0..127
        ht[bat][l16] = f2bu(hv);
        hvf[j] = hv; bats[j] = bat;
      }
    {
      const int d0 = __builtin_amdgcn_cvt_pk_fp8_f32(hvf[0], hvf[1], 0, false);
      const int d1 = __builtin_amdgcn_cvt_pk_fp8_f32(hvf[2], hvf[3], 0, false);
      const int d2 = __builtin_amdgcn_cvt_pk_fp8_f32(hvf[4], hvf[5], 0, false);
      const int d3 = __builtin_amdgcn_cvt_pk_fp8_f32(hvf[6], hvf[7], 0, false);
      ht8[bats[0]][l16] = (unsigned char)(d0 & 255);
      ht8[bats[1]][l16] = (unsigned char)((d0 >> 8) & 255);
      ht8[bats[2]][l16] = (unsigned char)(d1 & 255);
      ht8[bats[3]][l16] = (unsigned char)((d1 >> 8) & 255);
      ht8[bats[4]][l16] = (unsigned char)(d2 & 255);
      ht8[bats[5]][l16] = (unsigned char)((d2 >> 8) & 255);
      ht8[bats[6]][l16] = (unsigned char)(d3 & 255);
      ht8[bats[7]][l16] = (unsigned char)((d3 >> 8) & 255);
    }
    __syncthreads();
    // ---- coalesced write-back; flag chain: hbL8 store -> drain -> flag ----
    const int ub = tid >> 1, uh = tid & 1;
    i64t hv8 = *reinterpret_cast<const i64t*>(&ht8[ub][uh * 8]);
    st8sc8(hbL8 + (size_t)((cur * 2 + dir) * 32 + nb) * 128 * 16
               + ub * 16 + uh * 8, hv8);
    if (t < SEQ - 1) {
      asm volatile("s_waitcnt vmcnt(0)" ::: "memory");
      __syncthreads();
      if (tid == 0)
        __hip_atomic_store(aflag + ((size_t)(dir * SEQ + t) * 32 + nb) * FPAD, 1,
                           __ATOMIC_RELAXED, __HIP_MEMORY_SCOPE_AGENT);
    }
    // hsW store AFTER the flag: off the cross-block critical chain
    bf16x8 hv = ld8(&ht[ub][uh * 8]);
    *reinterpret_cast<bf16x8*>(
        hsW + (((size_t)(dir * 32 + nb) * 128 + pos) * 128 + ub) * 16 + uh * 8) = hv;
  }
}

// ---------------------------------------------------------------------------
// MLP layer 1: A gathered from hsW layout. out = relu(A @ W1^T + b1).
// ---------------------------------------------------------------------------
__global__ __launch_bounds__(256) void mlp1_gemm(
    const unsigned short* __restrict__ hsW, const unsigned short* __restrict__ W1b,
    const float* __restrict__ bias, unsigned short* __restrict__ out) {
  const int tid = threadIdx.x;
  const int w = tid >> 6, l = tid & 63;
  const int l16 = l & 15, lk8 = (l >> 4) * 8;
  const int by = blockIdx.y;                   // batch
  const int row0 = by * 128 + w * 32;
  const int col0 = blockIdx.x * 64;
  f32x4 acc[2][4] = {};
  for (int kk = 0; kk < 32; ++kk) {
    const int k = kk * 32 + lk8;               // 0..1023
    const int dirk = k >> 9, u = k & 511, nbs = u >> 4, ul = u & 15;
    const int p0 = w * 32 + l16, p1 = p0 + 16; // pos within batch
    bf16x8 a0 = ld8(hsW + (((size_t)(dirk * 32 + nbs) * 128 + p0) * 128 + by) * 16 + ul);
    bf16x8 a1 = ld8(hsW + (((size_t)(dirk * 32 + nbs) * 128 + p1) * 128 + by) * 16 + ul);
    const unsigned short* wp = W1b + (size_t)(col0 + l16) * 1024 + k;
#pragma unroll
    for (int nn = 0; nn < 4; ++nn) {
      bf16x8 bv = ld8(wp + nn * 16 * 1024);
      acc[0][nn] = MFMA(a0, bv, acc[0][nn]);
      acc[1][nn] = MFMA(a1, bv, acc[1][nn]);
    }
  }
  const int cr = (l >> 4) * 4;
#pragma unroll
  for (int m = 0; m < 2; ++m)
#pragma unroll
    for (int nn = 0; nn < 4; ++nn)
#pragma unroll
      for (int e = 0; e < 4; ++e) {
        const int r = row0 + m * 16 + cr + e;
        const int c = col0 + nn * 16 + l16;
        out[(size_t)r * 256 + c] = f2bu(fmaxf(acc[m][nn][e] + bias[c], 0.f));
      }
}

// ---------------------------------------------------------------------------
// MLP layer 2 (row-major A): out = relu(A @ W2^T + b2).
// ---------------------------------------------------------------------------
__global__ __launch_bounds__(256) void mlp_gemm(
    const unsigned short* __restrict__ A, int lda,
    const unsigned short* __restrict__ W, int ldw,
    const float* __restrict__ bias, unsigned short* __restrict__ out,
    int ldo, int nk, int relu) {
  const int tid = threadIdx.x;
  const int w = tid >> 6, l = tid & 63;
  const int l16 = l & 15, lk8 = (l >> 4) * 8;
  const int row0 = blockIdx.y * 128 + w * 32;
  const int col0 = blockIdx.x * 64;
  f32x4 acc[2][4] = {};
  for (int kk = 0; kk < nk; ++kk) {
    const int k = kk * 32 + lk8;
    bf16x8 a0 = ld8(A + (size_t)(row0 + l16) * lda + k);
    bf16x8 a1 = ld8(A + (size_t)(row0 + 16 + l16) * lda + k);
    const unsigned short* wp = W + (size_t)(col0 + l16) * ldw + k;
    bf16x8 bb[4];
#pragma unroll
    for (int nn = 0; nn < 4; ++nn) bb[nn] = ld8(wp + nn * 16 * ldw);
#pragma unroll
    for (int nn = 0; nn < 4; ++nn) {
      acc[0][nn] = MFMA(a0, bb[nn], acc[0][nn]);
      acc[1][nn] = MFMA(a1, bb[nn], acc[1][nn]);
    }
  }
  const int cr = (l >> 4) * 4;
#pragma unroll
  for (int m = 0; m < 2; ++m)
#pragma unroll
    for (int nn = 0; nn < 4; ++nn)
#pragma unroll
      for (int e = 0; e < 4; ++e) {
        const int r = row0 + m * 16 + cr + e;
        const int c = col0 + nn * 16 + l16;
        float v = acc[m][nn][e] + bias[c];
        if (relu) v = fmaxf(v, 0.f);
        out[(size_t)r * ldo + c] = f2bu(v);
      }
}

// ---------------------------------------------------------------------------
// Logits (MFMA, N=64 padded) + log_softmax over 50, fused. 128 rows/block.
// ---------------------------------------------------------------------------
__global__ __launch_bounds__(256) void logits_fused(
    const unsigned short* __restrict__ h2, const unsigned short* __restrict__ W3p,
    const float* __restrict__ b3, float* __restrict__ out) {
  __shared__ float gt[128][68];
  __shared__ float lseb[128];
  const int tid = threadIdx.x;
  const int w = tid >> 6, l = tid & 63;
  const int l16 = l & 15, lk8 = (l >> 4) * 8;
  const int r0 = blockIdx.x * 128;
  const int rr0 = w * 32 + l16, rr1 = rr0 + 16;
  f32x4 acc[2][4] = {};
#pragma unroll
  for (int kk = 0; kk < 8; ++kk) {
    const int k = kk * 32 + lk8;
    bf16x8 a0 = ld8(h2 + (size_t)(r0 + rr0) * 256 + k);
    bf16x8 a1 = ld8(h2 + (size_t)(r0 + rr1) * 256 + k);
#pragma unroll
    for (int nn = 0; nn < 4; ++nn) {
      bf16x8 bv = ld8(W3p + (size_t)(nn * 16 + l16) * 256 + k);
      acc[0][nn] = MFMA(a0, bv, acc[0][nn]);
      acc[1][nn] = MFMA(a1, bv, acc[1][nn]);
    }
  }
  const int cr = (l >> 4) * 4;
#pragma unroll
  for (int m = 0; m < 2; ++m)
#pragma unroll
    for (int nn = 0; nn < 4; ++nn)
#pragma unroll
      for (int e = 0; e < 4; ++e) {
        const int col = nn * 16 + l16;
        gt[w * 32 + m * 16 + cr + e][col] =
            acc[m][nn][e] + (col < NOUT ? b3[col] : 0.f);
      }
  __syncthreads();
  if (tid < 128) {
    float mx = -INFINITY;
#pragma unroll
    for (int j = 0; j < NOUT; ++j) mx = fmaxf(mx, gt[tid][j]);
    float s = 0.f;
#pragma unroll
    for (int j = 0; j < NOUT; ++j) s += fex2(LOG2E * (gt[tid][j] - mx));
    lseb[tid] = flog2(s) * 0.6931471805599453f + mx;
  }
  __syncthreads();
  for (int idx = tid; idx < 128 * NOUT; idx += 256) {
    const int r = idx / NOUT, j = idx - r * NOUT;
    out[(size_t)(r0 + r) * NOUT + j] = gt[r][j] - lseb[r];
  }
}

// ---------------------------------------------------------------------------
// Prep kernels
// ---------------------------------------------------------------------------
__global__ void prep_w(const float* __restrict__ ih, const float* __restrict__ hh,
                       unsigned short* __restrict__ dst, int HU, int KI, int KH) {
  const int K = KI + KH;
  const long tot = (long)HU * 4 * K;
  for (long idx = (long)blockIdx.x * blockDim.x + threadIdx.x; idx < tot;
       idx += (long)gridDim.x * blockDim.x) {
    const int row = (int)(idx / K), k = (int)(idx % K);
    const int chunk = row >> 6, c = row & 63;
    const int g = c >> 4, u = chunk * 16 + (c & 15);
    const float v = (k < KI) ? ih[(size_t)(g * HU + u) * KI + k]
                             : hh[(size_t)(g * HU + u) * KH + (k - KI)];
    dst[idx] = f2bu(v);
  }
}

// fp8 h-part weights: dst[row][k] e4m3, row gate-major, k in [0,KH)
__global__ void prep_w8(const float* __restrict__ hh, unsigned char* __restrict__ dst,
                        int HU, int KH) {
  const long tot = (long)HU * 4 * (KH / 2);
  for (long p = (long)blockIdx.x * blockDim.x + threadIdx.x; p < tot;
       p += (long)gridDim.x * blockDim.x) {
    const int row = (int)(p / (KH / 2)), kp = (int)(p % (KH / 2)) * 2;
    const int chunk = row >> 6, c = row & 63;
    const int g = c >> 4, u = chunk * 16 + (c & 15);
    const float a = hh[(size_t)(g * HU + u) * KH + kp];
    const float b = hh[(size_t)(g * HU + u) * KH + kp + 1];
    const int d = __builtin_amdgcn_cvt_pk_fp8_f32(a, b, 0, false);
    *reinterpret_cast<unsigned short*>(dst + (size_t)row * KH + kp) =
        (unsigned short)(d & 0xFFFF);
  }
}

__global__ void prep_bias(const float* bih, const float* bhh, float* dst, int HU) {
  const int idx = blockIdx.x * blockDim.x + threadIdx.x;   // gate-major flat
  if (idx < 4 * HU) {
    const int chunk = idx >> 6, c = idx & 63;
    const int g = c >> 4, u = chunk * 16 + (c & 15);
    dst[idx] = bih[g * HU + u] + bhh[g * HU + u];
  }
}

// char bias: bcT[u*4 + g]
__global__ void prep_biasT(const float* bih, const float* bhh, float* dst, int HU) {
  const int idx = blockIdx.x * blockDim.x + threadIdx.x;
  if (idx < 4 * HU) {
    const int u = idx >> 2, g = idx & 3;
    dst[idx] = bih[g * HU + u] + bhh[g * HU + u];
  }
}

__global__ void conv_bf(const float* __restrict__ src, unsigned short* __restrict__ dst,
                        long n) {
  for (long i = (long)blockIdx.x * blockDim.x + threadIdx.x; i < n;
       i += (long)gridDim.x * blockDim.x)
    dst[i] = f2bu(src[i]);
}

__global__ void prep_w3(const float* __restrict__ W3, unsigned short* __restrict__ dst) {
  const int i = blockIdx.x * blockDim.x + threadIdx.x;   // 64*256
  if (i < 64 * 256) {
    const int r = i >> 8;
    dst[i] = (r < NOUT) ? f2bu(W3[i]) : 0;
  }
}

__global__ void lengths_k(const int* x, int* len) {
  const int n = blockIdx.x * blockDim.x + threadIdx.x;
  if (n < NW) {
    int c = 0;
#pragma unroll
    for (int l = 0; l < LC; ++l) c += (x[(size_t)n * LC + l] != 0) ? 1 : 0;
    len[n] = c;
  }
}

__global__ void zero_k(int* p, int n) {
  const int i = blockIdx.x * blockDim.x + threadIdx.x;
  if (i < n) p[i] = 0;
}

__global__ void sentinel_k(float* out, int n) {
  const int i = blockIdx.x * blockDim.x + threadIdx.x;
  if (i < n) out[i] = 1000.0f;
}

// ---------------------------------------------------------------------------
extern "C" void kernel_launch(void* const* d_in, const int* in_sizes, int n_in,
                              void* d_out, int out_size, void* d_ws, size_t ws_size,
                              hipStream_t stream) {
  const int*   x     = (const int*)d_in[0];
  const float* emb   = (const float*)d_in[1];
  const float* cW_ih = (const float*)d_in[2];
  const float* cW_hh = (const float*)d_in[3];
  const float* cb_ih = (const float*)d_in[4];
  const float* cb_hh = (const float*)d_in[5];
  const float* fW_ih = (const float*)d_in[6];
  const float* fW_hh = (const float*)d_in[7];
  const float* fb_ih = (const float*)d_in[8];
  const float* fb_hh = (const float*)d_in[9];
  const float* bW_ih = (const float*)d_in[10];
  const float* bW_hh = (const float*)d_in[11];
  const float* bb_ih = (const float*)d_in[12];
  const float* bb_hh = (const float*)d_in[13];
  const float* W1 = (const float*)d_in[14];
  const float* b1 = (const float*)d_in[15];
  const float* W2 = (const float*)d_in[16];
  const float* b2 = (const float*)d_in[17];
  const float* W3 = (const float*)d_in[18];
  const float* b3 = (const float*)d_in[19];
  float* out = (float*)d_out;
  (void)in_sizes; (void)n_in;

  char* ws = (char*)d_ws;
  size_t off = 0;
  auto alloc = [&](size_t bytes) -> char* {
    char* p = ws + off;
    off += (bytes + 255) & ~(size_t)255;
    return p;
  };
  int*            len_  = (int*)alloc((size_t)NW * 4);
  int*            aflag = (int*)alloc((size_t)2 * SEQ * 32 * FPAD * 4);   // 512KB
  unsigned short* embb  = (unsigned short*)alloc((size_t)100 * EDIM * 2);
  unsigned short* Wc_i  = (unsigned short*)alloc((size_t)1024 * 320 * 2);
  unsigned short* Wf_i  = (unsigned short*)alloc((size_t)2048 * 768 * 2);
  unsigned short* Wb_i  = (unsigned short*)alloc((size_t)2048 * 768 * 2);
  unsigned char*  Wf8   = (unsigned char*)alloc((size_t)2048 * 512);
  unsigned char*  Wb8   = (unsigned char*)alloc((size_t)2048 * 512);
  unsigned short* W1b   = (unsigned short*)alloc((size_t)256 * 1024 * 2);
  unsigned short* W2b   = (unsigned short*)alloc((size_t)256 * 256 * 2);
  unsigned short* W3p   = (unsigned short*)alloc((size_t)64 * 256 * 2);
  float*          bcT   = (float*)alloc(1024 * 4);
  float*          bf_i  = (float*)alloc(2048 * 4);
  float*          bb_i  = (float*)alloc(2048 * 4);
  unsigned short* lastT = (unsigned short*)alloc((size_t)NW * HC * 2);       // 8MB
  unsigned char*  hbL8  = (unsigned char*)alloc((size_t)2 * 2 * 32 * 128 * 16);
  unsigned short* hsW   = (unsigned short*)alloc((size_t)2 * 32 * 128 * 128 * 16 * 2);
  unsigned short* h1    = (unsigned short*)alloc((size_t)NW * HC * 2);       // 8MB
  unsigned short* h2    = (unsigned short*)alloc((size_t)NW * HC * 2);       // 8MB

  if (off > ws_size) {
    sentinel_k<<<(out_size + 255) / 256, 256, 0, stream>>>(out, out_size);
    return;
  }

  auto cdiv = [](long a, long b) { return (int)((a + b - 1) / b); };

  // ---- prep ----
  prep_w<<<1280, 256, 0, stream>>>(cW_ih, cW_hh, Wc_i, HC, EDIM, HC);
  prep_w<<<3072, 256, 0, stream>>>(fW_ih, fW_hh, Wf_i, HW, HC, HW);
  prep_w<<<3072, 256, 0, stream>>>(bW_ih, bW_hh, Wb_i, HW, HC, HW);
  prep_w8<<<2048, 256, 0, stream>>>(fW_hh, Wf8, HW, HW);
  prep_w8<<<2048, 256, 0, stream>>>(bW_hh, Wb8, HW, HW);
  prep_biasT<<<cdiv(1024, 256), 256, 0, stream>>>(cb_ih, cb_hh, bcT, HC);
  prep_bias<<<cdiv(2048, 256), 256, 0, stream>>>(fb_ih, fb_hh, bf_i, HW);
  prep_bias<<<cdiv(2048, 256), 256, 0, stream>>>(bb_ih, bb_hh, bb_i, HW);
  conv_bf<<<25, 256, 0, stream>>>(emb, embb, 100L * EDIM);
  conv_bf<<<1024, 256, 0, stream>>>(W1, W1b, 256L * 1024);
  conv_bf<<<256, 256, 0, stream>>>(W2, W2b, 256L * 256);
  prep_w3<<<64, 256, 0, stream>>>(W3, W3p);
  lengths_k<<<cdiv(NW, 256), 256, 0, stream>>>(x, len_);
  zero_k<<<cdiv(2 * SEQ * 32 * FPAD, 256), 256, 0, stream>>>(aflag, 2 * SEQ * 32 * FPAD);

  // ---- persistent char LSTM (1 launch, r16 geometry + deferred lastT) ----
  char_lstm<<<NW / 64, 512, 0, stream>>>(x, embb, Wc_i, bcT, lastT, len_);

  // ---- persistent word BiLSTM (1 launch, r16 config, fp8 exchange) ----
  word_lstm<<<NWB, 256, 0, stream>>>(lastT, Wf_i, Wb_i, Wf8, Wb8, bf_i, bb_i,
                                     hbL8, hsW, aflag);

  // ---- MLP + fused logits/log_softmax ----
  mlp1_gemm<<<dim3(4, 128), 256, 0, stream>>>(hsW, W1b, b1, h1);
  mlp_gemm<<<dim3(4, 128), 256, 0, stream>>>(h1, 256, W2b, 256, b2, h2, 256, 8, 1);
  logits_fused<<<NW / 128, 256, 0, stream>>>(h2, W3p, b3, out);
}

// Round 21
// 1372.174 us; speedup vs baseline: 1.6328x; 1.1407x over previous
//
#include <hip/hip_runtime.h>
#include <hip/hip_bf16.h>
#include <math.h>

typedef __hip_bfloat16 bf16;
typedef __attribute__((ext_vector_type(8))) short bf16x8;   // 8 bf16 = 4 VGPR
typedef __attribute__((ext_vector_type(4))) float f32x4;
typedef long i64t;                                          // 8 fp8 = 2 VGPR

#define NW   16384
#define LC   20
#define EDIM 64
#define HC   256
#define HW   512
#define SEQ  128
#define NOUT 50
#define NWB  64      // word-kernel blocks (2 dirs x 32), must be co-resident
#define FPAD 16      // ints per flag (64B line)

// ---- fast transcendentals ----
#define LOG2E 1.4426950408889634f
__device__ __forceinline__ float fex2(float x) {
  float r; asm("v_exp_f32 %0, %1" : "=v"(r) : "v"(x)); return r;
}
__device__ __forceinline__ float frcp(float x) {
  float r; asm("v_rcp_f32 %0, %1" : "=v"(r) : "v"(x)); return r;
}
__device__ __forceinline__ float flog2(float x) {
  float r; asm("v_log_f32 %0, %1" : "=v"(r) : "v"(x)); return r;
}
__device__ __forceinline__ float fsig(float x) { return frcp(1.f + fex2(-LOG2E * x)); }
__device__ __forceinline__ float ftanh(float x) {
  return 1.f - 2.f * frcp(1.f + fex2(2.f * LOG2E * x));
}

__device__ __forceinline__ unsigned short f2bu(float f) {
  bf16 h = __float2bfloat16(f);
  return *reinterpret_cast<unsigned short*>(&h);
}
__device__ __forceinline__ bf16x8 ld8(const unsigned short* p) {
  return *reinterpret_cast<const bf16x8*>(p);
}
__device__ __forceinline__ float fp8_to_f32(unsigned int b) {  // byte 0 of b
  float r; asm("v_cvt_f32_fp8 %0, %1" : "=v"(r) : "v"(b)); return r;
}
// Coherent (cross-XCD) plain ops: sc0 sc1 -> bypass L1+L2, hit LLC.
__device__ __forceinline__ i64t ld8sc8(const unsigned char* p) {   // 8B load
  i64t r;
  asm volatile("global_load_dwordx2 %0, %1, off sc0 sc1" : "=v"(r) : "v"(p));
  return r;
}
__device__ __forceinline__ void st8sc8(unsigned char* p, i64t v) { // 8B store
  asm volatile("global_store_dwordx2 %0, %1, off sc0 sc1" :: "v"(p), "v"(v) : "memory");
}
#define MFMA(a, b, c)  __builtin_amdgcn_mfma_f32_16x16x32_bf16(a, b, c, 0, 0, 0)
#define MFMA8(a, b, c) __builtin_amdgcn_mfma_f32_16x16x32_fp8_fp8(a, b, c, 0, 0, 0)

// ---------------------------------------------------------------------------
// Persistent char LSTM, FULL FP8: weights + emb + h-state fp8 (mfma fp8_fp8),
// c-state f16. LDS 68KB -> 2 blocks/CU (4 waves/SIMD) AND halved weight
// bytes from L2. 64 words/block, 512 threads (8 waves x 2 chunks).
// Deferred coalesced lastT write (fp8 -> bf16) at step end.
// ---------------------------------------------------------------------------
__global__ __launch_bounds__(512, 1) void char_lstm(
    const int* __restrict__ x, const unsigned char* __restrict__ emb8,
    const unsigned char* __restrict__ Wc8, const float* __restrict__ bcT,
    unsigned short* __restrict__ lastT, const int* __restrict__ len) {
  __shared__ unsigned char Hs8[2][64][264];   // 33.8 KB fp8 h (stride 264 = 8*33)
  __shared__ _Float16 Cs[256][66];            // 33.8 KB f16 c-state
  __shared__ int lenS[64];
  const int tid = threadIdx.x;
  const int w = tid >> 6, l = tid & 63;       // w 0..7
  const int l16 = l & 15, lk8 = (l >> 4) * 8, q = l >> 4;
  const int w0 = blockIdx.x * 64;
  if (tid < 64) lenS[tid] = len[w0 + tid];
  // (first use of lenS is after the first in-loop __syncthreads)

  for (int t = 0; t < LC; ++t) {
    const int cur = t & 1, nxt = cur ^ 1;
    int xi[4];
#pragma unroll
    for (int wh = 0; wh < 4; ++wh) xi[wh] = x[(w0 + wh * 16 + l16) * LC + t];
#pragma unroll
    for (int c = 0; c < 2; ++c) {
      const int chg = w * 2 + c;                // chunk 0..15
      const int cc0 = chg * 64;                 // gate-col base
      f32x4 acc[4][4] = {};                     // [wh][gate]
#pragma unroll
      for (int kk = 0; kk < 2; ++kk) {          // K 0..63: embedding (fp8)
        const int k = kk * 32 + lk8;
        const unsigned char* wp = Wc8 + (size_t)(cc0 + l16) * 320 + k;
        i64t bv8[4];
#pragma unroll
        for (int g = 0; g < 4; ++g)
          bv8[g] = *reinterpret_cast<const i64t*>(wp + g * 16 * 320);
#pragma unroll
        for (int wh = 0; wh < 4; ++wh) {
          i64t a8 = *reinterpret_cast<const i64t*>(emb8 + (size_t)xi[wh] * 64 + k);
#pragma unroll
          for (int g = 0; g < 4; ++g) acc[wh][g] = MFMA8(bv8[g], a8, acc[wh][g]);
        }
      }
      if (t > 0) {
#pragma unroll
        for (int kk = 2; kk < 10; ++kk) {       // K 64..319: h(t-1) fp8 from LDS
          const int k = kk * 32 + lk8;
          const unsigned char* wp = Wc8 + (size_t)(cc0 + l16) * 320 + k;
          i64t bv8[4];
#pragma unroll
          for (int g = 0; g < 4; ++g)
            bv8[g] = *reinterpret_cast<const i64t*>(wp + g * 16 * 320);
#pragma unroll
          for (int wh = 0; wh < 4; ++wh) {
            i64t a8 = *reinterpret_cast<const i64t*>(&Hs8[cur][wh * 16 + l16][k - 64]);
#pragma unroll
            for (int g = 0; g < 4; ++g) acc[wh][g] = MFMA8(bv8[g], a8, acc[wh][g]);
          }
        }
      }
      // ---- update: lane owns units chg*16+q*4+e, words wh*16+l16 ----
      float4 bb4[4];
#pragma unroll
      for (int e = 0; e < 4; ++e)
        bb4[e] = *reinterpret_cast<const float4*>(bcT + (chg * 16 + q * 4 + e) * 4);
      const int uoff = chg * 16 + q * 4;        // 4-byte aligned fp8 offset
#pragma unroll
      for (int wh = 0; wh < 4; ++wh) {
        const int wd = wh * 16 + l16;
        float hv[4];
#pragma unroll
        for (int e = 0; e < 4; ++e) {
          const int ug = chg * 16 + q * 4 + e;
          const float gi = acc[wh][0][e] + bb4[e].x;
          const float gf = acc[wh][1][e] + bb4[e].y;
          const float gg = acc[wh][2][e] + bb4[e].z;
          const float go = acc[wh][3][e] + bb4[e].w;
          const float cprev = t ? (float)Cs[ug][wd] : 0.f;
          const float ccv = fsig(gf) * cprev + fsig(gi) * ftanh(gg);
          Cs[ug][wd] = (_Float16)ccv;
          hv[e] = fsig(go) * ftanh(ccv);
        }
        const int d0 = __builtin_amdgcn_cvt_pk_fp8_f32(hv[0], hv[1], 0, false);
        const int d1 = __builtin_amdgcn_cvt_pk_fp8_f32(hv[2], hv[3], 0, false);
        const unsigned int pk = (unsigned int)(d0 & 0xFFFF) |
                                ((unsigned int)(d1 & 0xFFFF) << 16);
        *reinterpret_cast<unsigned int*>(&Hs8[nxt][wd][uoff]) = pk;
      }
    }
    __syncthreads();   // Hs8[nxt] complete (and lenS ready after t=0)
    // ---- deferred, coalesced lastT write for words finishing at step t ----
    {
      const int wd = tid >> 3, sub = tid & 7;   // 64 words x 8 threads
      const int myl = lenS[wd];
      if (myl == t + 1 || (myl == 0 && t == 0)) {
        const int n = w0 + wd;
        const int lrow = ((n & 127) * 128 + (n >> 7)) * HC;  // time-major row
        if (myl == 0) {
          bf16x8 z = {};
#pragma unroll
          for (int j = 0; j < 4; ++j)
            *reinterpret_cast<bf16x8*>(lastT + lrow + sub * 32 + j * 8) = z;
        } else {
#pragma unroll
          for (int j = 0; j < 4; ++j) {
            unsigned int v0 = *reinterpret_cast<unsigned int*>(
                &Hs8[nxt][wd][sub * 32 + j * 8]);
            unsigned int v1 = *reinterpret_cast<unsigned int*>(
                &Hs8[nxt][wd][sub * 32 + j * 8 + 4]);
            union { unsigned short s[8]; bf16x8 v; } o;
#pragma unroll
            for (int b = 0; b < 4; ++b) {
              o.s[b]     = f2bu(fp8_to_f32((v0 >> (8 * b)) & 0xFF));
              o.s[4 + b] = f2bu(fp8_to_f32((v1 >> (8 * b)) & 0xFF));
            }
            *reinterpret_cast<bf16x8*>(lastT + lrow + sub * 32 + j * 8) = o.v;
          }
        }
      }
    }
  }
}

// ---------------------------------------------------------------------------
// Persistent word BiLSTM (r16-proven, FROZEN): 64 blocks (dir = bx>>5, 16
// units). x-weights bf16 (32KB) + h-weights fp8 (32KB) in LDS; h exchanged
// fp8 via sc0sc1 at LLC, consumed by mfma fp8_fp8. Padded flag barrier.
// ---------------------------------------------------------------------------
__global__ __launch_bounds__(256, 1) void word_lstm(
    const unsigned short* __restrict__ lastT,   // [pos][128][HC] bf16
    const unsigned short* __restrict__ W16,     // bf16 gate-major (fwd)
    const unsigned short* __restrict__ W16b,    // (bwd)
    const unsigned char* __restrict__ W8f,      // fp8 gate-major (fwd)
    const unsigned char* __restrict__ W8b,      // (bwd)
    const float* __restrict__ bfi, const float* __restrict__ bbi,
    unsigned char* __restrict__ hbL8,   // [2][2][32][128][16] fp8
    unsigned short* __restrict__ hsW,   // [2][32][128 pos][128 b][16] bf16
    int* __restrict__ aflag) {          // [2][SEQ][32][FPAD]
  __shared__ unsigned short Wlds16[64 * 256];   // 32 KB x-part bf16
  __shared__ unsigned char  Wlds8[64 * 512];    // 32 KB h-part fp8
  __shared__ unsigned short ht[128][24];        // 6 KB bf16 transpose
  __shared__ unsigned char  ht8[128][24];       // 3 KB fp8 transpose
  const int tid = threadIdx.x;
  const int w = tid >> 6, l = tid & 63;
  const int l16 = l & 15, lk8 = (l >> 4) * 8, q = l >> 4;
  const int dir = blockIdx.x >> 5;
  const int nb = blockIdx.x & 31;
  const int c0 = nb * 64;
  const unsigned short* Wx = dir ? W16b : W16;
  const unsigned char*  Wh = dir ? W8b : W8f;
  const float* bias = dir ? bbi : bfi;
  for (int ci = tid; ci < 64 * 32; ci += 256) {
    const int col = ci >> 5, kc = (ci & 31) * 8;
    const int kcs = kc ^ ((col & 15) * 8);
    *reinterpret_cast<bf16x8*>(&Wlds16[col * 256 + kcs]) =
        ld8(Wx + (size_t)(c0 + col) * 768 + kc);
  }
  for (int ci = tid; ci < 64 * 64; ci += 256) {
    const int col = ci >> 6, kb = (ci & 63) * 8;
    const int kbs = kb ^ ((col & 15) * 8);
    *reinterpret_cast<i64t*>(&Wlds8[col * 512 + kbs]) =
        *reinterpret_cast<const i64t*>(Wh + (size_t)(c0 + col) * 512 + kb);
  }
  const float b0 = bias[c0 + 0 * 16 + l16];
  const float b1 = bias[c0 + 1 * 16 + l16];
  const float b2 = bias[c0 + 2 * 16 + l16];
  const float b3 = bias[c0 + 3 * 16 + l16];
  const int ksw = l16 * 8;
  float cst[8];
#pragma unroll
  for (int i = 0; i < 8; ++i) cst[i] = 0.f;
  __syncthreads();                      // LDS weights ready

  for (int t = 0; t < SEQ; ++t) {
    const int cur = t & 1;
    const int pos = dir ? (SEQ - 1 - t) : t;
    // ---- x-part: plain cached lastT loads, bf16 MFMA ----
    f32x4 acc[2][4] = {};
#pragma unroll
    for (int kk = 0; kk < 8; ++kk) {
      const int k = kk * 32 + lk8;
      bf16x8 a0 = ld8(lastT + ((size_t)pos * 128 + w * 32 + l16) * HC + k);
      bf16x8 a1 = ld8(lastT + ((size_t)pos * 128 + w * 32 + l16 + 16) * HC + k);
      const int ks = k ^ ksw;
#pragma unroll
      for (int nn = 0; nn < 4; ++nn) {
        bf16x8 bv = ld8(&Wlds16[(l16 + nn * 16) * 256 + ks]);
        acc[0][nn] = MFMA(a0, bv, acc[0][nn]);
        acc[1][nn] = MFMA(a1, bv, acc[1][nn]);
      }
    }
    if (t > 0) {
      if (w == 0) {                      // flag-barrier wait for step t-1
        const int* fp = aflag + (size_t)(dir * SEQ + (t - 1)) * 32 * FPAD;
        for (;;) {
          int v = 1;
          if (l < 32)
            v = __hip_atomic_load(fp + l * FPAD, __ATOMIC_RELAXED,
                                  __HIP_MEMORY_SCOPE_AGENT);
          if (__ballot(v != 0) == ~0ull) break;
          __builtin_amdgcn_s_sleep(1);
        }
      }
      __syncthreads();
      // ---- h loads (fp8, coherent 8B) + fp8 MFMA ----
      i64t af8[16][2];
      const unsigned char* hp =
          hbL8 + (size_t)(((cur ^ 1) * 2 + dir) * 32) * 128 * 16;
#pragma unroll
      for (int kk = 0; kk < 16; ++kk) {
        const int u = kk * 32 + lk8;
        const int nbs = u >> 4, ul = u & 15;
#pragma unroll
        for (int r = 0; r < 2; ++r) {
          const int bt = w * 32 + l16 + r * 16;
          af8[kk][r] = ld8sc8(hp + ((size_t)nbs * 128 + bt) * 16 + ul);
        }
      }
      asm volatile("s_waitcnt vmcnt(0)" ::: "memory");
      __builtin_amdgcn_sched_barrier(0);   // rule #18
#pragma unroll
      for (int kk = 0; kk < 16; ++kk) {
        const int ks8 = (kk * 32 + lk8) ^ ksw;
#pragma unroll
        for (int nn = 0; nn < 4; ++nn) {
          i64t w8 = *reinterpret_cast<const i64t*>(
              &Wlds8[(l16 + nn * 16) * 512 + ks8]);
          acc[0][nn] = MFMA8(af8[kk][0], w8, acc[0][nn]);
          acc[1][nn] = MFMA8(af8[kk][1], w8, acc[1][nn]);
        }
      }
    }
    // ---- in-register LSTM update (lane owns unit nb*16+l16, 8 batches) ----
    float hvf[8];
    int bats[8];
#pragma unroll
    for (int m = 0; m < 2; ++m)
#pragma unroll
      for (int e = 0; e < 4; ++e) {
        const int j = m * 4 + e;
        const float gi = acc[m][0][e] + b0;
        const float gf = acc[m][1][e] + b1;
        const float gg = acc[m][2][e] + b2;
        const float go = acc[m][3][e] + b3;
        const float ccv = fsig(gf) * cst[j] + fsig(gi) * ftanh(gg);
        cst[j] = ccv;
        const float hv = fsig(go) * ftanh(ccv);
        const int bat = w * 32 + q * 4 + e + m * 16;    // 0..127
        ht[bat][l16] = f2bu(hv);
        hvf[j] = hv; bats[j] = bat;
      }
    {
      const int d0 = __builtin_amdgcn_cvt_pk_fp8_f32(hvf[0], hvf[1], 0, false);
      const int d1 = __builtin_amdgcn_cvt_pk_fp8_f32(hvf[2], hvf[3], 0, false);
      const int d2 = __builtin_amdgcn_cvt_pk_fp8_f32(hvf[4], hvf[5], 0, false);
      const int d3 = __builtin_amdgcn_cvt_pk_fp8_f32(hvf[6], hvf[7], 0, false);
      ht8[bats[0]][l16] = (unsigned char)(d0 & 255);
      ht8[bats[1]][l16] = (unsigned char)((d0 >> 8) & 255);
      ht8[bats[2]][l16] = (unsigned char)(d1 & 255);
      ht8[bats[3]][l16] = (unsigned char)((d1 >> 8) & 255);
      ht8[bats[4]][l16] = (unsigned char)(d2 & 255);
      ht8[bats[5]][l16] = (unsigned char)((d2 >> 8) & 255);
      ht8[bats[6]][l16] = (unsigned char)(d3 & 255);
      ht8[bats[7]][l16] = (unsigned char)((d3 >> 8) & 255);
    }
    __syncthreads();
    // ---- coalesced write-back; flag chain: hbL8 store -> drain -> flag ----
    const int ub = tid >> 1, uh = tid & 1;
    i64t hv8 = *reinterpret_cast<const i64t*>(&ht8[ub][uh * 8]);
    st8sc8(hbL8 + (size_t)((cur * 2 + dir) * 32 + nb) * 128 * 16
               + ub * 16 + uh * 8, hv8);
    if (t < SEQ - 1) {
      asm volatile("s_waitcnt vmcnt(0)" ::: "memory");
      __syncthreads();
      if (tid == 0)
        __hip_atomic_store(aflag + ((size_t)(dir * SEQ + t) * 32 + nb) * FPAD, 1,
                           __ATOMIC_RELAXED, __HIP_MEMORY_SCOPE_AGENT);
    }
    // hsW store AFTER the flag: off the cross-block critical chain
    bf16x8 hv = ld8(&ht[ub][uh * 8]);
    *reinterpret_cast<bf16x8*>(
        hsW + (((size_t)(dir * 32 + nb) * 128 + pos) * 128 + ub) * 16 + uh * 8) = hv;
  }
}

// ---------------------------------------------------------------------------
// MLP layer 1: A gathered from hsW layout. out = relu(A @ W1^T + b1).
// ---------------------------------------------------------------------------
__global__ __launch_bounds__(256) void mlp1_gemm(
    const unsigned short* __restrict__ hsW, const unsigned short* __restrict__ W1b,
    const float* __restrict__ bias, unsigned short* __restrict__ out) {
  const int tid = threadIdx.x;
  const int w = tid >> 6, l = tid & 63;
  const int l16 = l & 15, lk8 = (l >> 4) * 8;
  const int by = blockIdx.y;                   // batch
  const int row0 = by * 128 + w * 32;
  const int col0 = blockIdx.x * 64;
  f32x4 acc[2][4] = {};
  for (int kk = 0; kk < 32; ++kk) {
    const int k = kk * 32 + lk8;               // 0..1023
    const int dirk = k >> 9, u = k & 511, nbs = u >> 4, ul = u & 15;
    const int p0 = w * 32 + l16, p1 = p0 + 16; // pos within batch
    bf16x8 a0 = ld8(hsW + (((size_t)(dirk * 32 + nbs) * 128 + p0) * 128 + by) * 16 + ul);
    bf16x8 a1 = ld8(hsW + (((size_t)(dirk * 32 + nbs) * 128 + p1) * 128 + by) * 16 + ul);
    const unsigned short* wp = W1b + (size_t)(col0 + l16) * 1024 + k;
#pragma unroll
    for (int nn = 0; nn < 4; ++nn) {
      bf16x8 bv = ld8(wp + nn * 16 * 1024);
      acc[0][nn] = MFMA(a0, bv, acc[0][nn]);
      acc[1][nn] = MFMA(a1, bv, acc[1][nn]);
    }
  }
  const int cr = (l >> 4) * 4;
#pragma unroll
  for (int m = 0; m < 2; ++m)
#pragma unroll
    for (int nn = 0; nn < 4; ++nn)
#pragma unroll
      for (int e = 0; e < 4; ++e) {
        const int r = row0 + m * 16 + cr + e;
        const int c = col0 + nn * 16 + l16;
        out[(size_t)r * 256 + c] = f2bu(fmaxf(acc[m][nn][e] + bias[c], 0.f));
      }
}

// ---------------------------------------------------------------------------
// MLP layer 2 (row-major A): out = relu(A @ W2^T + b2).
// ---------------------------------------------------------------------------
__global__ __launch_bounds__(256) void mlp_gemm(
    const unsigned short* __restrict__ A, int lda,
    const unsigned short* __restrict__ W, int ldw,
    const float* __restrict__ bias, unsigned short* __restrict__ out,
    int ldo, int nk, int relu) {
  const int tid = threadIdx.x;
  const int w = tid >> 6, l = tid & 63;
  const int l16 = l & 15, lk8 = (l >> 4) * 8;
  const int row0 = blockIdx.y * 128 + w * 32;
  const int col0 = blockIdx.x * 64;
  f32x4 acc[2][4] = {};
  for (int kk = 0; kk < nk; ++kk) {
    const int k = kk * 32 + lk8;
    bf16x8 a0 = ld8(A + (size_t)(row0 + l16) * lda + k);
    bf16x8 a1 = ld8(A + (size_t)(row0 + 16 + l16) * lda + k);
    const unsigned short* wp = W + (size_t)(col0 + l16) * ldw + k;
    bf16x8 bb[4];
#pragma unroll
    for (int nn = 0; nn < 4; ++nn) bb[nn] = ld8(wp + nn * 16 * ldw);
#pragma unroll
    for (int nn = 0; nn < 4; ++nn) {
      acc[0][nn] = MFMA(a0, bb[nn], acc[0][nn]);
      acc[1][nn] = MFMA(a1, bb[nn], acc[1][nn]);
    }
  }
  const int cr = (l >> 4) * 4;
#pragma unroll
  for (int m = 0; m < 2; ++m)
#pragma unroll
    for (int nn = 0; nn < 4; ++nn)
#pragma unroll
      for (int e = 0; e < 4; ++e) {
        const int r = row0 + m * 16 + cr + e;
        const int c = col0 + nn * 16 + l16;
        float v = acc[m][nn][e] + bias[c];
        if (relu) v = fmaxf(v, 0.f);
        out[(size_t)r * ldo + c] = f2bu(v);
      }
}

// ---------------------------------------------------------------------------
// Logits (MFMA, N=64 padded) + log_softmax over 50, fused. 128 rows/block.
// ---------------------------------------------------------------------------
__global__ __launch_bounds__(256) void logits_fused(
    const unsigned short* __restrict__ h2, const unsigned short* __restrict__ W3p,
    const float* __restrict__ b3, float* __restrict__ out) {
  __shared__ float gt[128][68];
  __shared__ float lseb[128];
  const int tid = threadIdx.x;
  const int w = tid >> 6, l = tid & 63;
  const int l16 = l & 15, lk8 = (l >> 4) * 8;
  const int r0 = blockIdx.x * 128;
  const int rr0 = w * 32 + l16, rr1 = rr0 + 16;
  f32x4 acc[2][4] = {};
#pragma unroll
  for (int kk = 0; kk < 8; ++kk) {
    const int k = kk * 32 + lk8;
    bf16x8 a0 = ld8(h2 + (size_t)(r0 + rr0) * 256 + k);
    bf16x8 a1 = ld8(h2 + (size_t)(r0 + rr1) * 256 + k);
#pragma unroll
    for (int nn = 0; nn < 4; ++nn) {
      bf16x8 bv = ld8(W3p + (size_t)(nn * 16 + l16) * 256 + k);
      acc[0][nn] = MFMA(a0, bv, acc[0][nn]);
      acc[1][nn] = MFMA(a1, bv, acc[1][nn]);
    }
  }
  const int cr = (l >> 4) * 4;
#pragma unroll
  for (int m = 0; m < 2; ++m)
#pragma unroll
    for (int nn = 0; nn < 4; ++nn)
#pragma unroll
      for (int e = 0; e < 4; ++e) {
        const int col = nn * 16 + l16;
        gt[w * 32 + m * 16 + cr + e][col] =
            acc[m][nn][e] + (col < NOUT ? b3[col] : 0.f);
      }
  __syncthreads();
  if (tid < 128) {
    float mx = -INFINITY;
#pragma unroll
    for (int j = 0; j < NOUT; ++j) mx = fmaxf(mx, gt[tid][j]);
    float s = 0.f;
#pragma unroll
    for (int j = 0; j < NOUT; ++j) s += fex2(LOG2E * (gt[tid][j] - mx));
    lseb[tid] = flog2(s) * 0.6931471805599453f + mx;
  }
  __syncthreads();
  for (int idx = tid; idx < 128 * NOUT; idx += 256) {
    const int r = idx / NOUT, j = idx - r * NOUT;
    out[(size_t)(r0 + r) * NOUT + j] = gt[r][j] - lseb[r];
  }
}

// ---------------------------------------------------------------------------
// Prep kernels
// ---------------------------------------------------------------------------
__global__ void prep_w(const float* __restrict__ ih, const float* __restrict__ hh,
                       unsigned short* __restrict__ dst, int HU, int KI, int KH) {
  const int K = KI + KH;
  const long tot = (long)HU * 4 * K;
  for (long idx = (long)blockIdx.x * blockDim.x + threadIdx.x; idx < tot;
       idx += (long)gridDim.x * blockDim.x) {
    const int row = (int)(idx / K), k = (int)(idx % K);
    const int chunk = row >> 6, c = row & 63;
    const int g = c >> 4, u = chunk * 16 + (c & 15);
    const float v = (k < KI) ? ih[(size_t)(g * HU + u) * KI + k]
                             : hh[(size_t)(g * HU + u) * KH + (k - KI)];
    dst[idx] = f2bu(v);
  }
}

// gate-major fp8 weights, combined [ih|hh] (K = KI+KH, KI even)
__global__ void prep_wc8(const float* __restrict__ ih, const float* __restrict__ hh,
                         unsigned char* __restrict__ dst, int HU, int KI, int KH) {
  const int K = KI + KH;
  const long tot = (long)HU * 4 * (K / 2);
  for (long p = (long)blockIdx.x * blockDim.x + threadIdx.x; p < tot;
       p += (long)gridDim.x * blockDim.x) {
    const int row = (int)(p / (K / 2)), kp = (int)(p % (K / 2)) * 2;
    const int chunk = row >> 6, c = row & 63;
    const int g = c >> 4, u = chunk * 16 + (c & 15);
    const float a = (kp < KI) ? ih[(size_t)(g * HU + u) * KI + kp]
                              : hh[(size_t)(g * HU + u) * KH + (kp - KI)];
    const float b = (kp + 1 < KI) ? ih[(size_t)(g * HU + u) * KI + kp + 1]
                                  : hh[(size_t)(g * HU + u) * KH + (kp + 1 - KI)];
    const int d = __builtin_amdgcn_cvt_pk_fp8_f32(a, b, 0, false);
    *reinterpret_cast<unsigned short*>(dst + (size_t)row * K + kp) =
        (unsigned short)(d & 0xFFFF);
  }
}

// fp8 h-part weights: dst[row][k] e4m3, row gate-major, k in [0,KH)
__global__ void prep_w8(const float* __restrict__ hh, unsigned char* __restrict__ dst,
                        int HU, int KH) {
  const long tot = (long)HU * 4 * (KH / 2);
  for (long p = (long)blockIdx.x * blockDim.x + threadIdx.x; p < tot;
       p += (long)gridDim.x * blockDim.x) {
    const int row = (int)(p / (KH / 2)), kp = (int)(p % (KH / 2)) * 2;
    const int chunk = row >> 6, c = row & 63;
    const int g = c >> 4, u = chunk * 16 + (c & 15);
    const float a = hh[(size_t)(g * HU + u) * KH + kp];
    const float b = hh[(size_t)(g * HU + u) * KH + kp + 1];
    const int d = __builtin_amdgcn_cvt_pk_fp8_f32(a, b, 0, false);
    *reinterpret_cast<unsigned short*>(dst + (size_t)row * KH + kp) =
        (unsigned short)(d & 0xFFFF);
  }
}

__global__ void prep_bias(const float* bih, const float* bhh, float* dst, int HU) {
  const int idx = blockIdx.x * blockDim.x + threadIdx.x;   // gate-major flat
  if (idx < 4 * HU) {
    const int chunk = idx >> 6, c = idx & 63;
    const int g = c >> 4, u = chunk * 16 + (c & 15);
    dst[idx] = bih[g * HU + u] + bhh[g * HU + u];
  }
}

// char bias: bcT[u*4 + g]
__global__ void prep_biasT(const float* bih, const float* bhh, float* dst, int HU) {
  const int idx = blockIdx.x * blockDim.x + threadIdx.x;
  if (idx < 4 * HU) {
    const int u = idx >> 2, g = idx & 3;
    dst[idx] = bih[g * HU + u] + bhh[g * HU + u];
  }
}

__global__ void conv_bf(const float* __restrict__ src, unsigned short* __restrict__ dst,
                        long n) {
  for (long i = (long)blockIdx.x * blockDim.x + threadIdx.x; i < n;
       i += (long)gridDim.x * blockDim.x)
    dst[i] = f2bu(src[i]);
}

__global__ void conv_fp8(const float* __restrict__ src, unsigned char* __restrict__ dst,
                         long n2) {                    // n2 = n/2 pairs
  for (long i = (long)blockIdx.x * blockDim.x + threadIdx.x; i < n2;
       i += (long)gridDim.x * blockDim.x) {
    const int d = __builtin_amdgcn_cvt_pk_fp8_f32(src[i * 2], src[i * 2 + 1], 0, false);
    *reinterpret_cast<unsigned short*>(dst + i * 2) = (unsigned short)(d & 0xFFFF);
  }
}

__global__ void prep_w3(const float* __restrict__ W3, unsigned short* __restrict__ dst) {
  const int i = blockIdx.x * blockDim.x + threadIdx.x;   // 64*256
  if (i < 64 * 256) {
    const int r = i >> 8;
    dst[i] = (r < NOUT) ? f2bu(W3[i]) : 0;
  }
}

__global__ void lengths_k(const int* x, int* len) {
  const int n = blockIdx.x * blockDim.x + threadIdx.x;
  if (n < NW) {
    int c = 0;
#pragma unroll
    for (int l = 0; l < LC; ++l) c += (x[(size_t)n * LC + l] != 0) ? 1 : 0;
    len[n] = c;
  }
}

__global__ void zero_k(int* p, int n) {
  const int i = blockIdx.x * blockDim.x + threadIdx.x;
  if (i < n) p[i] = 0;
}

__global__ void sentinel_k(float* out, int n) {
  const int i = blockIdx.x * blockDim.x + threadIdx.x;
  if (i < n) out[i] = 1000.0f;
}

// ---------------------------------------------------------------------------
extern "C" void kernel_launch(void* const* d_in, const int* in_sizes, int n_in,
                              void* d_out, int out_size, void* d_ws, size_t ws_size,
                              hipStream_t stream) {
  const int*   x     = (const int*)d_in[0];
  const float* emb   = (const float*)d_in[1];
  const float* cW_ih = (const float*)d_in[2];
  const float* cW_hh = (const float*)d_in[3];
  const float* cb_ih = (const float*)d_in[4];
  const float* cb_hh = (const float*)d_in[5];
  const float* fW_ih = (const float*)d_in[6];
  const float* fW_hh = (const float*)d_in[7];
  const float* fb_ih = (const float*)d_in[8];
  const float* fb_hh = (const float*)d_in[9];
  const float* bW_ih = (const float*)d_in[10];
  const float* bW_hh = (const float*)d_in[11];
  const float* bb_ih = (const float*)d_in[12];
  const float* bb_hh = (const float*)d_in[13];
  const float* W1 = (const float*)d_in[14];
  const float* b1 = (const float*)d_in[15];
  const float* W2 = (const float*)d_in[16];
  const float* b2 = (const float*)d_in[17];
  const float* W3 = (const float*)d_in[18];
  const float* b3 = (const float*)d_in[19];
  float* out = (float*)d_out;
  (void)in_sizes; (void)n_in;

  char* ws = (char*)d_ws;
  size_t off = 0;
  auto alloc = [&](size_t bytes) -> char* {
    char* p = ws + off;
    off += (bytes + 255) & ~(size_t)255;
    return p;
  };
  int*            len_  = (int*)alloc((size_t)NW * 4);
  int*            aflag = (int*)alloc((size_t)2 * SEQ * 32 * FPAD * 4);   // 512KB
  unsigned char*  emb8  = (unsigned char*)alloc((size_t)100 * EDIM);
  unsigned char*  Wc8   = (unsigned char*)alloc((size_t)1024 * 320);
  unsigned short* Wf_i  = (unsigned short*)alloc((size_t)2048 * 768 * 2);
  unsigned short* Wb_i  = (unsigned short*)alloc((size_t)2048 * 768 * 2);
  unsigned char*  Wf8   = (unsigned char*)alloc((size_t)2048 * 512);
  unsigned char*  Wb8   = (unsigned char*)alloc((size_t)2048 * 512);
  unsigned short* W1b   = (unsigned short*)alloc((size_t)256 * 1024 * 2);
  unsigned short* W2b   = (unsigned short*)alloc((size_t)256 * 256 * 2);
  unsigned short* W3p   = (unsigned short*)alloc((size_t)64 * 256 * 2);
  float*          bcT   = (float*)alloc(1024 * 4);
  float*          bf_i  = (float*)alloc(2048 * 4);
  float*          bb_i  = (float*)alloc(2048 * 4);
  unsigned short* lastT = (unsigned short*)alloc((size_t)NW * HC * 2);       // 8MB
  unsigned char*  hbL8  = (unsigned char*)alloc((size_t)2 * 2 * 32 * 128 * 16);
  unsigned short* hsW   = (unsigned short*)alloc((size_t)2 * 32 * 128 * 128 * 16 * 2);
  unsigned short* h1    = (unsigned short*)alloc((size_t)NW * HC * 2);       // 8MB
  unsigned short* h2    = (unsigned short*)alloc((size_t)NW * HC * 2);       // 8MB

  if (off > ws_size) {
    sentinel_k<<<(out_size + 255) / 256, 256, 0, stream>>>(out, out_size);
    return;
  }

  auto cdiv = [](long a, long b) { return (int)((a + b - 1) / b); };

  // ---- prep ----
  prep_wc8<<<640, 256, 0, stream>>>(cW_ih, cW_hh, Wc8, HC, EDIM, HC);
  prep_w<<<3072, 256, 0, stream>>>(fW_ih, fW_hh, Wf_i, HW, HC, HW);
  prep_w<<<3072, 256, 0, stream>>>(bW_ih, bW_hh, Wb_i, HW, HC, HW);
  prep_w8<<<2048, 256, 0, stream>>>(fW_hh, Wf8, HW, HW);
  prep_w8<<<2048, 256, 0, stream>>>(bW_hh, Wb8, HW, HW);
  prep_biasT<<<cdiv(1024, 256), 256, 0, stream>>>(cb_ih, cb_hh, bcT, HC);
  prep_bias<<<cdiv(2048, 256), 256, 0, stream>>>(fb_ih, fb_hh, bf_i, HW);
  prep_bias<<<cdiv(2048, 256), 256, 0, stream>>>(bb_ih, bb_hh, bb_i, HW);
  conv_fp8<<<13, 256, 0, stream>>>(emb, emb8, 100L * EDIM / 2);
  conv_bf<<<1024, 256, 0, stream>>>(W1, W1b, 256L * 1024);
  conv_bf<<<256, 256, 0, stream>>>(W2, W2b, 256L * 256);
  prep_w3<<<64, 256, 0, stream>>>(W3, W3p);
  lengths_k<<<cdiv(NW, 256), 256, 0, stream>>>(x, len_);
  zero_k<<<cdiv(2 * SEQ * 32 * FPAD, 256), 256, 0, stream>>>(aflag, 2 * SEQ * 32 * FPAD);

  // ---- persistent char LSTM (1 launch, full-fp8, 2 blocks/CU) ----
  char_lstm<<<NW / 64, 512, 0, stream>>>(x, emb8, Wc8, bcT, lastT, len_);

  // ---- persistent word BiLSTM (1 launch, r16 config, fp8 exchange) ----
  word_lstm<<<NWB, 256, 0, stream>>>(lastT, Wf_i, Wb_i, Wf8, Wb8, bf_i, bb_i,
                                     hbL8, hsW, aflag);

  // ---- MLP + fused logits/log_softmax ----
  mlp1_gemm<<<dim3(4, 128), 256, 0, stream>>>(hsW, W1b, b1, h1);
  mlp_gemm<<<dim3(4, 128), 256, 0, stream>>>(h1, 256, W2b, 256, b2, h2, 256, 8, 1);
  logits_fused<<<NW / 128, 256, 0, stream>>>(h2, W3p, b3, out);
}

// Round 22
// 1291.616 us; speedup vs baseline: 1.7347x; 1.0624x over previous
//
#include <hip/hip_runtime.h>
#include <hip/hip_bf16.h>
#include <math.h>

typedef __hip_bfloat16 bf16;
typedef __attribute__((ext_vector_type(8))) short bf16x8;   // 8 bf16 = 4 VGPR
typedef __attribute__((ext_vector_type(4))) float f32x4;
typedef long i64t;                                          // 8 fp8 = 2 VGPR

#define NW   16384
#define LC   20
#define EDIM 64
#define HC   256
#define HW   512
#define SEQ  128
#define NOUT 50
#define FPAD 16      // ints per flag (64B line)

// ---- fast transcendentals ----
#define LOG2E 1.4426950408889634f
__device__ __forceinline__ float fex2(float x) {
  float r; asm("v_exp_f32 %0, %1" : "=v"(r) : "v"(x)); return r;
}
__device__ __forceinline__ float frcp(float x) {
  float r; asm("v_rcp_f32 %0, %1" : "=v"(r) : "v"(x)); return r;
}
__device__ __forceinline__ float flog2(float x) {
  float r; asm("v_log_f32 %0, %1" : "=v"(r) : "v"(x)); return r;
}
__device__ __forceinline__ float fsig(float x) { return frcp(1.f + fex2(-LOG2E * x)); }
__device__ __forceinline__ float ftanh(float x) {
  return 1.f - 2.f * frcp(1.f + fex2(2.f * LOG2E * x));
}

__device__ __forceinline__ unsigned short f2bu(float f) {
  bf16 h = __float2bfloat16(f);
  return *reinterpret_cast<unsigned short*>(&h);
}
__device__ __forceinline__ bf16x8 ld8(const unsigned short* p) {
  return *reinterpret_cast<const bf16x8*>(p);
}
__device__ __forceinline__ float fp8_to_f32(unsigned int b) {  // byte 0 of b
  float r; asm("v_cvt_f32_fp8 %0, %1" : "=v"(r) : "v"(b)); return r;
}
// Scope-switchable coherent ops. fast=true: sc0 only (XCD-L2 coherent, ~5x
// lower latency); fast=false: sc0 sc1 (LLC, device-wide correct).
__device__ __forceinline__ i64t ld8x(const unsigned char* p, bool f) {
  i64t r;
  if (f) asm volatile("global_load_dwordx2 %0, %1, off sc0" : "=v"(r) : "v"(p));
  else   asm volatile("global_load_dwordx2 %0, %1, off sc0 sc1" : "=v"(r) : "v"(p));
  return r;
}
__device__ __forceinline__ void st8x(unsigned char* p, i64t v, bool f) {
  if (f) asm volatile("global_store_dwordx2 %0, %1, off sc0" :: "v"(p), "v"(v) : "memory");
  else   asm volatile("global_store_dwordx2 %0, %1, off sc0 sc1" :: "v"(p), "v"(v) : "memory");
}
__device__ __forceinline__ int ldflagx(const int* p, bool f) {
  int r;
  if (f) asm volatile("global_load_dword %0, %1, off sc0" : "=v"(r) : "v"(p));
  else   asm volatile("global_load_dword %0, %1, off sc0 sc1" : "=v"(r) : "v"(p));
  return r;
}
__device__ __forceinline__ void stflagx(int* p, int v, bool f) {
  if (f) asm volatile("global_store_dword %0, %1, off sc0" :: "v"(p), "v"(v) : "memory");
  else   asm volatile("global_store_dword %0, %1, off sc0 sc1" :: "v"(p), "v"(v) : "memory");
}
#define MFMA(a, b, c)  __builtin_amdgcn_mfma_f32_16x16x32_bf16(a, b, c, 0, 0, 0)
#define MFMA8(a, b, c) __builtin_amdgcn_mfma_f32_16x16x32_fp8_fp8(a, b, c, 0, 0, 0)

// ---------------------------------------------------------------------------
// Persistent char LSTM, FULL FP8 (r21-proven, FROZEN).
// ---------------------------------------------------------------------------
__global__ __launch_bounds__(512, 1) void char_lstm(
    const int* __restrict__ x, const unsigned char* __restrict__ emb8,
    const unsigned char* __restrict__ Wc8, const float* __restrict__ bcT,
    unsigned short* __restrict__ lastT, const int* __restrict__ len) {
  __shared__ unsigned char Hs8[2][64][264];
  __shared__ _Float16 Cs[256][66];
  __shared__ int lenS[64];
  const int tid = threadIdx.x;
  const int w = tid >> 6, l = tid & 63;
  const int l16 = l & 15, lk8 = (l >> 4) * 8, q = l >> 4;
  const int w0 = blockIdx.x * 64;
  if (tid < 64) lenS[tid] = len[w0 + tid];

  for (int t = 0; t < LC; ++t) {
    const int cur = t & 1, nxt = cur ^ 1;
    int xi[4];
#pragma unroll
    for (int wh = 0; wh < 4; ++wh) xi[wh] = x[(w0 + wh * 16 + l16) * LC + t];
#pragma unroll
    for (int c = 0; c < 2; ++c) {
      const int chg = w * 2 + c;
      const int cc0 = chg * 64;
      f32x4 acc[4][4] = {};
#pragma unroll
      for (int kk = 0; kk < 2; ++kk) {          // K 0..63: embedding (fp8)
        const int k = kk * 32 + lk8;
        const unsigned char* wp = Wc8 + (size_t)(cc0 + l16) * 320 + k;
        i64t bv8[4];
#pragma unroll
        for (int g = 0; g < 4; ++g)
          bv8[g] = *reinterpret_cast<const i64t*>(wp + g * 16 * 320);
#pragma unroll
        for (int wh = 0; wh < 4; ++wh) {
          i64t a8 = *reinterpret_cast<const i64t*>(emb8 + (size_t)xi[wh] * 64 + k);
#pragma unroll
          for (int g = 0; g < 4; ++g) acc[wh][g] = MFMA8(bv8[g], a8, acc[wh][g]);
        }
      }
      if (t > 0) {
#pragma unroll
        for (int kk = 2; kk < 10; ++kk) {       // K 64..319: h(t-1) fp8
          const int k = kk * 32 + lk8;
          const unsigned char* wp = Wc8 + (size_t)(cc0 + l16) * 320 + k;
          i64t bv8[4];
#pragma unroll
          for (int g = 0; g < 4; ++g)
            bv8[g] = *reinterpret_cast<const i64t*>(wp + g * 16 * 320);
#pragma unroll
          for (int wh = 0; wh < 4; ++wh) {
            i64t a8 = *reinterpret_cast<const i64t*>(&Hs8[cur][wh * 16 + l16][k - 64]);
#pragma unroll
            for (int g = 0; g < 4; ++g) acc[wh][g] = MFMA8(bv8[g], a8, acc[wh][g]);
          }
        }
      }
      float4 bb4[4];
#pragma unroll
      for (int e = 0; e < 4; ++e)
        bb4[e] = *reinterpret_cast<const float4*>(bcT + (chg * 16 + q * 4 + e) * 4);
      const int uoff = chg * 16 + q * 4;
#pragma unroll
      for (int wh = 0; wh < 4; ++wh) {
        const int wd = wh * 16 + l16;
        float hv[4];
#pragma unroll
        for (int e = 0; e < 4; ++e) {
          const int ug = chg * 16 + q * 4 + e;
          const float gi = acc[wh][0][e] + bb4[e].x;
          const float gf = acc[wh][1][e] + bb4[e].y;
          const float gg = acc[wh][2][e] + bb4[e].z;
          const float go = acc[wh][3][e] + bb4[e].w;
          const float cprev = t ? (float)Cs[ug][wd] : 0.f;
          const float ccv = fsig(gf) * cprev + fsig(gi) * ftanh(gg);
          Cs[ug][wd] = (_Float16)ccv;
          hv[e] = fsig(go) * ftanh(ccv);
        }
        const int d0 = __builtin_amdgcn_cvt_pk_fp8_f32(hv[0], hv[1], 0, false);
        const int d1 = __builtin_amdgcn_cvt_pk_fp8_f32(hv[2], hv[3], 0, false);
        const unsigned int pk = (unsigned int)(d0 & 0xFFFF) |
                                ((unsigned int)(d1 & 0xFFFF) << 16);
        *reinterpret_cast<unsigned int*>(&Hs8[nxt][wd][uoff]) = pk;
      }
    }
    __syncthreads();
    {
      const int wd = tid >> 3, sub = tid & 7;
      const int myl = lenS[wd];
      if (myl == t + 1 || (myl == 0 && t == 0)) {
        const int n = w0 + wd;
        const int lrow = ((n & 127) * 128 + (n >> 7)) * HC;
        if (myl == 0) {
          bf16x8 z = {};
#pragma unroll
          for (int j = 0; j < 4; ++j)
            *reinterpret_cast<bf16x8*>(lastT + lrow + sub * 32 + j * 8) = z;
        } else {
#pragma unroll
          for (int j = 0; j < 4; ++j) {
            unsigned int v0 = *reinterpret_cast<unsigned int*>(
                &Hs8[nxt][wd][sub * 32 + j * 8]);
            unsigned int v1 = *reinterpret_cast<unsigned int*>(
                &Hs8[nxt][wd][sub * 32 + j * 8 + 4]);
            union { unsigned short s[8]; bf16x8 v; } o;
#pragma unroll
            for (int b = 0; b < 4; ++b) {
              o.s[b]     = f2bu(fp8_to_f32((v0 >> (8 * b)) & 0xFF));
              o.s[4 + b] = f2bu(fp8_to_f32((v1 >> (8 * b)) & 0xFF));
            }
            *reinterpret_cast<bf16x8*>(lastT + lrow + sub * 32 + j * 8) = o.v;
          }
        }
      }
    }
  }
}

// ---------------------------------------------------------------------------
// Persistent word BiLSTM, XCD-PINNED: launch 256 blocks; only bx%8==0 (fwd)
// and bx%8==1 (bwd) work -> each dir's 32 blocks land on ONE XCD under
// round-robin dispatch. Runtime negotiation via HW_REG_XCC_ID verifies; if
// confirmed, h/flag exchange uses sc0-only (shared XCD-L2, ~5x lower
// latency); else falls back to sc0sc1 (LLC) -- always correct.
// ---------------------------------------------------------------------------
__global__ __launch_bounds__(256, 1) void word_lstm(
    const unsigned short* __restrict__ lastT,   // [pos][128][HC] bf16
    const unsigned short* __restrict__ W16,     // bf16 gate-major x-part [2048][256] (fwd)
    const unsigned short* __restrict__ W16b,    // (bwd)
    const unsigned char* __restrict__ W8f,      // fp8 gate-major h-part (fwd)
    const unsigned char* __restrict__ W8b,      // (bwd)
    const float* __restrict__ bfi, const float* __restrict__ bbi,
    unsigned char* __restrict__ hbL8,   // [2][2][32][128][16] fp8
    unsigned short* __restrict__ hsW,   // [2][32][128 pos][128 b][16] bf16
    int* __restrict__ aflag) {          // [2][SEQ][32][FPAD] + negotiation tail
  const int bx = blockIdx.x;
  if ((bx & 7) > 1) return;             // 192 idle blocks exit
  __shared__ unsigned short Wlds16[64 * 256];   // 32 KB x-part bf16
  __shared__ unsigned char  Wlds8[64 * 512];    // 32 KB h-part fp8
  __shared__ unsigned short ht[128][24];        // 6 KB bf16 transpose
  __shared__ unsigned char  ht8[128][24];       // 3 KB fp8 transpose
  __shared__ int fastS;
  const int tid = threadIdx.x;
  const int w = tid >> 6, l = tid & 63;
  const int l16 = l & 15, lk8 = (l >> 4) * 8, q = l >> 4;
  const int dir = bx & 7;               // 0 fwd, 1 bwd
  const int nb = bx >> 3;               // 0..31
  const int c0 = nb * 64;
  const unsigned short* Wx = dir ? W16b : W16;
  const unsigned char*  Wh = dir ? W8b : W8f;
  const float* bias = dir ? bbi : bfi;
  // ---- XCD negotiation (one-time) ----
  int* negcnt = aflag + (size_t)2 * SEQ * 32 * FPAD;   // [0]; xcnt at +16
  if (tid == 0) {
    const int xcc = __builtin_amdgcn_s_getreg(20 | (31 << 11)) & 7;  // HW_REG_XCC_ID
    int* xc = negcnt + 16 + dir * 8 + xcc;
    __hip_atomic_fetch_add(xc, 1, __ATOMIC_RELAXED, __HIP_MEMORY_SCOPE_AGENT);
    __hip_atomic_fetch_add(negcnt, 1, __ATOMIC_RELAXED, __HIP_MEMORY_SCOPE_AGENT);
    while (__hip_atomic_load(negcnt, __ATOMIC_RELAXED, __HIP_MEMORY_SCOPE_AGENT) < 64)
      __builtin_amdgcn_s_sleep(2);
    fastS = (__hip_atomic_load(xc, __ATOMIC_RELAXED, __HIP_MEMORY_SCOPE_AGENT) == 32);
  }
  // ---- stage weights into LDS ----
  for (int ci = tid; ci < 64 * 32; ci += 256) {
    const int col = ci >> 5, kc = (ci & 31) * 8;
    const int kcs = kc ^ ((col & 15) * 8);
    *reinterpret_cast<bf16x8*>(&Wlds16[col * 256 + kcs]) =
        ld8(Wx + (size_t)(c0 + col) * 256 + kc);
  }
  for (int ci = tid; ci < 64 * 64; ci += 256) {
    const int col = ci >> 6, kb = (ci & 63) * 8;
    const int kbs = kb ^ ((col & 15) * 8);
    *reinterpret_cast<i64t*>(&Wlds8[col * 512 + kbs]) =
        *reinterpret_cast<const i64t*>(Wh + (size_t)(c0 + col) * 512 + kb);
  }
  const float b0 = bias[c0 + 0 * 16 + l16];
  const float b1 = bias[c0 + 1 * 16 + l16];
  const float b2 = bias[c0 + 2 * 16 + l16];
  const float b3 = bias[c0 + 3 * 16 + l16];
  const int ksw = l16 * 8;
  float cst[8];
#pragma unroll
  for (int i = 0; i < 8; ++i) cst[i] = 0.f;
  __syncthreads();                      // Wlds + fastS ready
  const bool fast = (fastS != 0);

  for (int t = 0; t < SEQ; ++t) {
    const int cur = t & 1;
    const int pos = dir ? (SEQ - 1 - t) : t;
    // ---- x-part: plain cached lastT loads, bf16 MFMA ----
    f32x4 acc[2][4] = {};
#pragma unroll
    for (int kk = 0; kk < 8; ++kk) {
      const int k = kk * 32 + lk8;
      bf16x8 a0 = ld8(lastT + ((size_t)pos * 128 + w * 32 + l16) * HC + k);
      bf16x8 a1 = ld8(lastT + ((size_t)pos * 128 + w * 32 + l16 + 16) * HC + k);
      const int ks = k ^ ksw;
#pragma unroll
      for (int nn = 0; nn < 4; ++nn) {
        bf16x8 bv = ld8(&Wlds16[(l16 + nn * 16) * 256 + ks]);
        acc[0][nn] = MFMA(a0, bv, acc[0][nn]);
        acc[1][nn] = MFMA(a1, bv, acc[1][nn]);
      }
    }
    if (t > 0) {
      if (w == 0) {                      // flag-barrier wait for step t-1
        const int* fp = aflag + (size_t)(dir * SEQ + (t - 1)) * 32 * FPAD;
        for (;;) {
          int v = 1;
          if (l < 32) v = ldflagx(fp + l * FPAD, fast);
          if (__ballot(v != 0) == ~0ull) break;
          __builtin_amdgcn_s_sleep(1);
        }
      }
      __syncthreads();
      // ---- h loads (fp8, scope-matched) + fp8 MFMA ----
      i64t af8[16][2];
      const unsigned char* hp =
          hbL8 + (size_t)(((cur ^ 1) * 2 + dir) * 32) * 128 * 16;
#pragma unroll
      for (int kk = 0; kk < 16; ++kk) {
        const int u = kk * 32 + lk8;
        const int nbs = u >> 4, ul = u & 15;
#pragma unroll
        for (int r = 0; r < 2; ++r) {
          const int bt = w * 32 + l16 + r * 16;
          af8[kk][r] = ld8x(hp + ((size_t)nbs * 128 + bt) * 16 + ul, fast);
        }
      }
      asm volatile("s_waitcnt vmcnt(0)" ::: "memory");
      __builtin_amdgcn_sched_barrier(0);   // rule #18
#pragma unroll
      for (int kk = 0; kk < 16; ++kk) {
        const int ks8 = (kk * 32 + lk8) ^ ksw;
#pragma unroll
        for (int nn = 0; nn < 4; ++nn) {
          i64t w8 = *reinterpret_cast<const i64t*>(
              &Wlds8[(l16 + nn * 16) * 512 + ks8]);
          acc[0][nn] = MFMA8(af8[kk][0], w8, acc[0][nn]);
          acc[1][nn] = MFMA8(af8[kk][1], w8, acc[1][nn]);
        }
      }
    }
    // ---- in-register LSTM update (lane owns unit nb*16+l16, 8 batches) ----
    float hvf[8];
    int bats[8];
#pragma unroll
    for (int m = 0; m < 2; ++m)
#pragma unroll
      for (int e = 0; e < 4; ++e) {
        const int j = m * 4 + e;
        const float gi = acc[m][0][e] + b0;
        const float gf = acc[m][1][e] + b1;
        const float gg = acc[m][2][e] + b2;
        const float go = acc[m][3][e] + b3;
        const float ccv = fsig(gf) * cst[j] + fsig(gi) * ftanh(gg);
        cst[j] = ccv;
        const float hv = fsig(go) * ftanh(ccv);
        const int bat = w * 32 + q * 4 + e + m * 16;    // 0..127
        ht[bat][l16] = f2bu(hv);
        hvf[j] = hv; bats[j] = bat;
      }
    {
      const int d0 = __builtin_amdgcn_cvt_pk_fp8_f32(hvf[0], hvf[1], 0, false);
      const int d1 = __builtin_amdgcn_cvt_pk_fp8_f32(hvf[2], hvf[3], 0, false);
      const int d2 = __builtin_amdgcn_cvt_pk_fp8_f32(hvf[4], hvf[5], 0, false);
      const int d3 = __builtin_amdgcn_cvt_pk_fp8_f32(hvf[6], hvf[7], 0, false);
      ht8[bats[0]][l16] = (unsigned char)(d0 & 255);
      ht8[bats[1]][l16] = (unsigned char)((d0 >> 8) & 255);
      ht8[bats[2]][l16] = (unsigned char)(d1 & 255);
      ht8[bats[3]][l16] = (unsigned char)((d1 >> 8) & 255);
      ht8[bats[4]][l16] = (unsigned char)(d2 & 255);
      ht8[bats[5]][l16] = (unsigned char)((d2 >> 8) & 255);
      ht8[bats[6]][l16] = (unsigned char)(d3 & 255);
      ht8[bats[7]][l16] = (unsigned char)((d3 >> 8) & 255);
    }
    __syncthreads();
    // ---- coalesced write-back; flag chain: hbL8 store -> drain -> flag ----
    const int ub = tid >> 1, uh = tid & 1;
    i64t hv8 = *reinterpret_cast<const i64t*>(&ht8[ub][uh * 8]);
    st8x(hbL8 + (size_t)((cur * 2 + dir) * 32 + nb) * 128 * 16
             + ub * 16 + uh * 8, hv8, fast);
    if (t < SEQ - 1) {
      asm volatile("s_waitcnt vmcnt(0)" ::: "memory");
      __syncthreads();
      if (tid == 0)
        stflagx(aflag + ((size_t)(dir * SEQ + t) * 32 + nb) * FPAD, 1, fast);
    }
    // hsW store AFTER the flag: off the cross-block critical chain
    bf16x8 hv = ld8(&ht[ub][uh * 8]);
    *reinterpret_cast<bf16x8*>(
        hsW + (((size_t)(dir * 32 + nb) * 128 + pos) * 128 + ub) * 16 + uh * 8) = hv;
  }
}

// ---------------------------------------------------------------------------
// MLP layer 1 (frozen)
// ---------------------------------------------------------------------------
__global__ __launch_bounds__(256) void mlp1_gemm(
    const unsigned short* __restrict__ hsW, const unsigned short* __restrict__ W1b,
    const float* __restrict__ bias, unsigned short* __restrict__ out) {
  const int tid = threadIdx.x;
  const int w = tid >> 6, l = tid & 63;
  const int l16 = l & 15, lk8 = (l >> 4) * 8;
  const int by = blockIdx.y;
  const int row0 = by * 128 + w * 32;
  const int col0 = blockIdx.x * 64;
  f32x4 acc[2][4] = {};
  for (int kk = 0; kk < 32; ++kk) {
    const int k = kk * 32 + lk8;
    const int dirk = k >> 9, u = k & 511, nbs = u >> 4, ul = u & 15;
    const int p0 = w * 32 + l16, p1 = p0 + 16;
    bf16x8 a0 = ld8(hsW + (((size_t)(dirk * 32 + nbs) * 128 + p0) * 128 + by) * 16 + ul);
    bf16x8 a1 = ld8(hsW + (((size_t)(dirk * 32 + nbs) * 128 + p1) * 128 + by) * 16 + ul);
    const unsigned short* wp = W1b + (size_t)(col0 + l16) * 1024 + k;
#pragma unroll
    for (int nn = 0; nn < 4; ++nn) {
      bf16x8 bv = ld8(wp + nn * 16 * 1024);
      acc[0][nn] = MFMA(a0, bv, acc[0][nn]);
      acc[1][nn] = MFMA(a1, bv, acc[1][nn]);
    }
  }
  const int cr = (l >> 4) * 4;
#pragma unroll
  for (int m = 0; m < 2; ++m)
#pragma unroll
    for (int nn = 0; nn < 4; ++nn)
#pragma unroll
      for (int e = 0; e < 4; ++e) {
        const int r = row0 + m * 16 + cr + e;
        const int c = col0 + nn * 16 + l16;
        out[(size_t)r * 256 + c] = f2bu(fmaxf(acc[m][nn][e] + bias[c], 0.f));
      }
}

// ---------------------------------------------------------------------------
// MLP layer 2 (frozen)
// ---------------------------------------------------------------------------
__global__ __launch_bounds__(256) void mlp_gemm(
    const unsigned short* __restrict__ A, int lda,
    const unsigned short* __restrict__ W, int ldw,
    const float* __restrict__ bias, unsigned short* __restrict__ out,
    int ldo, int nk, int relu) {
  const int tid = threadIdx.x;
  const int w = tid >> 6, l = tid & 63;
  const int l16 = l & 15, lk8 = (l >> 4) * 8;
  const int row0 = blockIdx.y * 128 + w * 32;
  const int col0 = blockIdx.x * 64;
  f32x4 acc[2][4] = {};
  for (int kk = 0; kk < nk; ++kk) {
    const int k = kk * 32 + lk8;
    bf16x8 a0 = ld8(A + (size_t)(row0 + l16) * lda + k);
    bf16x8 a1 = ld8(A + (size_t)(row0 + 16 + l16) * lda + k);
    const unsigned short* wp = W + (size_t)(col0 + l16) * ldw + k;
    bf16x8 bb[4];
#pragma unroll
    for (int nn = 0; nn < 4; ++nn) bb[nn] = ld8(wp + nn * 16 * ldw);
#pragma unroll
    for (int nn = 0; nn < 4; ++nn) {
      acc[0][nn] = MFMA(a0, bb[nn], acc[0][nn]);
      acc[1][nn] = MFMA(a1, bb[nn], acc[1][nn]);
    }
  }
  const int cr = (l >> 4) * 4;
#pragma unroll
  for (int m = 0; m < 2; ++m)
#pragma unroll
    for (int nn = 0; nn < 4; ++nn)
#pragma unroll
      for (int e = 0; e < 4; ++e) {
        const int r = row0 + m * 16 + cr + e;
        const int c = col0 + nn * 16 + l16;
        float v = acc[m][nn][e] + bias[c];
        if (relu) v = fmaxf(v, 0.f);
        out[(size_t)r * ldo + c] = f2bu(v);
      }
}

// ---------------------------------------------------------------------------
// Logits + log_softmax (frozen)
// ---------------------------------------------------------------------------
__global__ __launch_bounds__(256) void logits_fused(
    const unsigned short* __restrict__ h2, const unsigned short* __restrict__ W3p,
    const float* __restrict__ b3, float* __restrict__ out) {
  __shared__ float gt[128][68];
  __shared__ float lseb[128];
  const int tid = threadIdx.x;
  const int w = tid >> 6, l = tid & 63;
  const int l16 = l & 15, lk8 = (l >> 4) * 8;
  const int r0 = blockIdx.x * 128;
  const int rr0 = w * 32 + l16, rr1 = rr0 + 16;
  f32x4 acc[2][4] = {};
#pragma unroll
  for (int kk = 0; kk < 8; ++kk) {
    const int k = kk * 32 + lk8;
    bf16x8 a0 = ld8(h2 + (size_t)(r0 + rr0) * 256 + k);
    bf16x8 a1 = ld8(h2 + (size_t)(r0 + rr1) * 256 + k);
#pragma unroll
    for (int nn = 0; nn < 4; ++nn) {
      bf16x8 bv = ld8(W3p + (size_t)(nn * 16 + l16) * 256 + k);
      acc[0][nn] = MFMA(a0, bv, acc[0][nn]);
      acc[1][nn] = MFMA(a1, bv, acc[1][nn]);
    }
  }
  const int cr = (l >> 4) * 4;
#pragma unroll
  for (int m = 0; m < 2; ++m)
#pragma unroll
    for (int nn = 0; nn < 4; ++nn)
#pragma unroll
      for (int e = 0; e < 4; ++e) {
        const int col = nn * 16 + l16;
        gt[w * 32 + m * 16 + cr + e][col] =
            acc[m][nn][e] + (col < NOUT ? b3[col] : 0.f);
      }
  __syncthreads();
  if (tid < 128) {
    float mx = -INFINITY;
#pragma unroll
    for (int j = 0; j < NOUT; ++j) mx = fmaxf(mx, gt[tid][j]);
    float s = 0.f;
#pragma unroll
    for (int j = 0; j < NOUT; ++j) s += fex2(LOG2E * (gt[tid][j] - mx));
    lseb[tid] = flog2(s) * 0.6931471805599453f + mx;
  }
  __syncthreads();
  for (int idx = tid; idx < 128 * NOUT; idx += 256) {
    const int r = idx / NOUT, j = idx - r * NOUT;
    out[(size_t)(r0 + r) * NOUT + j] = gt[r][j] - lseb[r];
  }
}

// ---------------------------------------------------------------------------
// Prep kernels
// ---------------------------------------------------------------------------
// x-part bf16 weights only (cols 0..KI), gate-major
__global__ void prep_wx(const float* __restrict__ ih, unsigned short* __restrict__ dst,
                        int HU, int KI) {
  const long tot = (long)HU * 4 * KI;
  for (long idx = (long)blockIdx.x * blockDim.x + threadIdx.x; idx < tot;
       idx += (long)gridDim.x * blockDim.x) {
    const int row = (int)(idx / KI), k = (int)(idx % KI);
    const int chunk = row >> 6, c = row & 63;
    const int g = c >> 4, u = chunk * 16 + (c & 15);
    dst[idx] = f2bu(ih[(size_t)(g * HU + u) * KI + k]);
  }
}

// gate-major fp8 weights, combined [ih|hh]
__global__ void prep_wc8(const float* __restrict__ ih, const float* __restrict__ hh,
                         unsigned char* __restrict__ dst, int HU, int KI, int KH) {
  const int K = KI + KH;
  const long tot = (long)HU * 4 * (K / 2);
  for (long p = (long)blockIdx.x * blockDim.x + threadIdx.x; p < tot;
       p += (long)gridDim.x * blockDim.x) {
    const int row = (int)(p / (K / 2)), kp = (int)(p % (K / 2)) * 2;
    const int chunk = row >> 6, c = row & 63;
    const int g = c >> 4, u = chunk * 16 + (c & 15);
    const float a = (kp < KI) ? ih[(size_t)(g * HU + u) * KI + kp]
                              : hh[(size_t)(g * HU + u) * KH + (kp - KI)];
    const float b = (kp + 1 < KI) ? ih[(size_t)(g * HU + u) * KI + kp + 1]
                                  : hh[(size_t)(g * HU + u) * KH + (kp + 1 - KI)];
    const int d = __builtin_amdgcn_cvt_pk_fp8_f32(a, b, 0, false);
    *reinterpret_cast<unsigned short*>(dst + (size_t)row * K + kp) =
        (unsigned short)(d & 0xFFFF);
  }
}

// fp8 h-part weights
__global__ void prep_w8(const float* __restrict__ hh, unsigned char* __restrict__ dst,
                        int HU, int KH) {
  const long tot = (long)HU * 4 * (KH / 2);
  for (long p = (long)blockIdx.x * blockDim.x + threadIdx.x; p < tot;
       p += (long)gridDim.x * blockDim.x) {
    const int row = (int)(p / (KH / 2)), kp = (int)(p % (KH / 2)) * 2;
    const int chunk = row >> 6, c = row & 63;
    const int g = c >> 4, u = chunk * 16 + (c & 15);
    const float a = hh[(size_t)(g * HU + u) * KH + kp];
    const float b = hh[(size_t)(g * HU + u) * KH + kp + 1];
    const int d = __builtin_amdgcn_cvt_pk_fp8_f32(a, b, 0, false);
    *reinterpret_cast<unsigned short*>(dst + (size_t)row * KH + kp) =
        (unsigned short)(d & 0xFFFF);
  }
}

__global__ void prep_bias(const float* bih, const float* bhh, float* dst, int HU) {
  const int idx = blockIdx.x * blockDim.x + threadIdx.x;
  if (idx < 4 * HU) {
    const int chunk = idx >> 6, c = idx & 63;
    const int g = c >> 4, u = chunk * 16 + (c & 15);
    dst[idx] = bih[g * HU + u] + bhh[g * HU + u];
  }
}

__global__ void prep_biasT(const float* bih, const float* bhh, float* dst, int HU) {
  const int idx = blockIdx.x * blockDim.x + threadIdx.x;
  if (idx < 4 * HU) {
    const int u = idx >> 2, g = idx & 3;
    dst[idx] = bih[g * HU + u] + bhh[g * HU + u];
  }
}

__global__ void conv_bf(const float* __restrict__ src, unsigned short* __restrict__ dst,
                        long n) {
  for (long i = (long)blockIdx.x * blockDim.x + threadIdx.x; i < n;
       i += (long)gridDim.x * blockDim.x)
    dst[i] = f2bu(src[i]);
}

__global__ void conv_fp8(const float* __restrict__ src, unsigned char* __restrict__ dst,
                         long n2) {
  for (long i = (long)blockIdx.x * blockDim.x + threadIdx.x; i < n2;
       i += (long)gridDim.x * blockDim.x) {
    const int d = __builtin_amdgcn_cvt_pk_fp8_f32(src[i * 2], src[i * 2 + 1], 0, false);
    *reinterpret_cast<unsigned short*>(dst + i * 2) = (unsigned short)(d & 0xFFFF);
  }
}

__global__ void prep_w3(const float* __restrict__ W3, unsigned short* __restrict__ dst) {
  const int i = blockIdx.x * blockDim.x + threadIdx.x;
  if (i < 64 * 256) {
    const int r = i >> 8;
    dst[i] = (r < NOUT) ? f2bu(W3[i]) : 0;
  }
}

__global__ void lengths_k(const int* x, int* len) {
  const int n = blockIdx.x * blockDim.x + threadIdx.x;
  if (n < NW) {
    int c = 0;
#pragma unroll
    for (int l = 0; l < LC; ++l) c += (x[(size_t)n * LC + l] != 0) ? 1 : 0;
    len[n] = c;
  }
}

__global__ void zero_k(int* p, int n) {
  const int i = blockIdx.x * blockDim.x + threadIdx.x;
  if (i < n) p[i] = 0;
}

__global__ void sentinel_k(float* out, int n) {
  const int i = blockIdx.x * blockDim.x + threadIdx.x;
  if (i < n) out[i] = 1000.0f;
}

// ---------------------------------------------------------------------------
extern "C" void kernel_launch(void* const* d_in, const int* in_sizes, int n_in,
                              void* d_out, int out_size, void* d_ws, size_t ws_size,
                              hipStream_t stream) {
  const int*   x     = (const int*)d_in[0];
  const float* emb   = (const float*)d_in[1];
  const float* cW_ih = (const float*)d_in[2];
  const float* cW_hh = (const float*)d_in[3];
  const float* cb_ih = (const float*)d_in[4];
  const float* cb_hh = (const float*)d_in[5];
  const float* fW_ih = (const float*)d_in[6];
  const float* fW_hh = (const float*)d_in[7];
  const float* fb_ih = (const float*)d_in[8];
  const float* fb_hh = (const float*)d_in[9];
  const float* bW_ih = (const float*)d_in[10];
  const float* bW_hh = (const float*)d_in[11];
  const float* bb_ih = (const float*)d_in[12];
  const float* bb_hh = (const float*)d_in[13];
  const float* W1 = (const float*)d_in[14];
  const float* b1 = (const float*)d_in[15];
  const float* W2 = (const float*)d_in[16];
  const float* b2 = (const float*)d_in[17];
  const float* W3 = (const float*)d_in[18];
  const float* b3 = (const float*)d_in[19];
  float* out = (float*)d_out;
  (void)in_sizes; (void)n_in;

  char* ws = (char*)d_ws;
  size_t off = 0;
  auto alloc = [&](size_t bytes) -> char* {
    char* p = ws + off;
    off += (bytes + 255) & ~(size_t)255;
    return p;
  };
  const int NFLAG = 2 * SEQ * 32 * FPAD + 32;   // flags + negotiation tail
  int*            len_  = (int*)alloc((size_t)NW * 4);
  int*            aflag = (int*)alloc((size_t)NFLAG * 4);
  unsigned char*  emb8  = (unsigned char*)alloc((size_t)100 * EDIM);
  unsigned char*  Wc8   = (unsigned char*)alloc((size_t)1024 * 320);
  unsigned short* Wf_i  = (unsigned short*)alloc((size_t)2048 * 256 * 2);
  unsigned short* Wb_i  = (unsigned short*)alloc((size_t)2048 * 256 * 2);
  unsigned char*  Wf8   = (unsigned char*)alloc((size_t)2048 * 512);
  unsigned char*  Wb8   = (unsigned char*)alloc((size_t)2048 * 512);
  unsigned short* W1b   = (unsigned short*)alloc((size_t)256 * 1024 * 2);
  unsigned short* W2b   = (unsigned short*)alloc((size_t)256 * 256 * 2);
  unsigned short* W3p   = (unsigned short*)alloc((size_t)64 * 256 * 2);
  float*          bcT   = (float*)alloc(1024 * 4);
  float*          bf_i  = (float*)alloc(2048 * 4);
  float*          bb_i  = (float*)alloc(2048 * 4);
  unsigned short* lastT = (unsigned short*)alloc((size_t)NW * HC * 2);       // 8MB
  unsigned char*  hbL8  = (unsigned char*)alloc((size_t)2 * 2 * 32 * 128 * 16);
  unsigned short* hsW   = (unsigned short*)alloc((size_t)2 * 32 * 128 * 128 * 16 * 2);
  unsigned short* h1    = (unsigned short*)alloc((size_t)NW * HC * 2);       // 8MB
  unsigned short* h2    = (unsigned short*)alloc((size_t)NW * HC * 2);       // 8MB

  if (off > ws_size) {
    sentinel_k<<<(out_size + 255) / 256, 256, 0, stream>>>(out, out_size);
    return;
  }

  auto cdiv = [](long a, long b) { return (int)((a + b - 1) / b); };

  // ---- prep ----
  prep_wc8<<<640, 256, 0, stream>>>(cW_ih, cW_hh, Wc8, HC, EDIM, HC);
  prep_wx<<<1024, 256, 0, stream>>>(fW_ih, Wf_i, HW, HC);
  prep_wx<<<1024, 256, 0, stream>>>(bW_ih, Wb_i, HW, HC);
  prep_w8<<<2048, 256, 0, stream>>>(fW_hh, Wf8, HW, HW);
  prep_w8<<<2048, 256, 0, stream>>>(bW_hh, Wb8, HW, HW);
  prep_biasT<<<cdiv(1024, 256), 256, 0, stream>>>(cb_ih, cb_hh, bcT, HC);
  prep_bias<<<cdiv(2048, 256), 256, 0, stream>>>(fb_ih, fb_hh, bf_i, HW);
  prep_bias<<<cdiv(2048, 256), 256, 0, stream>>>(bb_ih, bb_hh, bb_i, HW);
  conv_fp8<<<13, 256, 0, stream>>>(emb, emb8, 100L * EDIM / 2);
  conv_bf<<<1024, 256, 0, stream>>>(W1, W1b, 256L * 1024);
  conv_bf<<<256, 256, 0, stream>>>(W2, W2b, 256L * 256);
  prep_w3<<<64, 256, 0, stream>>>(W3, W3p);
  lengths_k<<<cdiv(NW, 256), 256, 0, stream>>>(x, len_);
  zero_k<<<cdiv(NFLAG, 256), 256, 0, stream>>>(aflag, NFLAG);

  // ---- persistent char LSTM (1 launch, full-fp8) ----
  char_lstm<<<NW / 64, 512, 0, stream>>>(x, emb8, Wc8, bcT, lastT, len_);

  // ---- persistent word BiLSTM (256 blocks, XCD-pinned + negotiated) ----
  word_lstm<<<256, 256, 0, stream>>>(lastT, Wf_i, Wb_i, Wf8, Wb8, bf_i, bb_i,
                                     hbL8, hsW, aflag);

  // ---- MLP + fused logits/log_softmax ----
  mlp1_gemm<<<dim3(4, 128), 256, 0, stream>>>(hsW, W1b, b1, h1);
  mlp_gemm<<<dim3(4, 128), 256, 0, stream>>>(h1, 256, W2b, 256, b2, h2, 256, 8, 1);
  logits_fused<<<NW / 128, 256, 0, stream>>>(h2, W3p, b3, out);
}

// Round 23
// 1125.776 us; speedup vs baseline: 1.9902x; 1.1473x over previous
//
#include <hip/hip_runtime.h>
#include <hip/hip_bf16.h>
#include <math.h>

typedef __hip_bfloat16 bf16;
typedef __attribute__((ext_vector_type(8))) short bf16x8;   // 8 bf16 = 4 VGPR
typedef __attribute__((ext_vector_type(4))) float f32x4;
typedef long i64t;                                          // 8 fp8 = 2 VGPR

#define NW   16384
#define LC   20
#define EDIM 64
#define HC   256
#define HW   512
#define SEQ  128
#define NOUT 50
#define FPAD 16      // ints per flag (64B line)

// ---- fast transcendentals ----
#define LOG2E 1.4426950408889634f
__device__ __forceinline__ float fex2(float x) {
  float r; asm("v_exp_f32 %0, %1" : "=v"(r) : "v"(x)); return r;
}
__device__ __forceinline__ float frcp(float x) {
  float r; asm("v_rcp_f32 %0, %1" : "=v"(r) : "v"(x)); return r;
}
__device__ __forceinline__ float flog2(float x) {
  float r; asm("v_log_f32 %0, %1" : "=v"(r) : "v"(x)); return r;
}
__device__ __forceinline__ float fsig(float x) { return frcp(1.f + fex2(-LOG2E * x)); }
__device__ __forceinline__ float ftanh(float x) {
  return 1.f - 2.f * frcp(1.f + fex2(2.f * LOG2E * x));
}

__device__ __forceinline__ unsigned short f2bu(float f) {
  bf16 h = __float2bfloat16(f);
  return *reinterpret_cast<unsigned short*>(&h);
}
__device__ __forceinline__ bf16x8 ld8(const unsigned short* p) {
  return *reinterpret_cast<const bf16x8*>(p);
}
__device__ __forceinline__ float fp8_to_f32(unsigned int b) {  // byte 0 of b
  float r; asm("v_cvt_f32_fp8 %0, %1" : "=v"(r) : "v"(b)); return r;
}
// Scope-switchable coherent ops. fast=true: sc0 only (XCD-L2 coherent);
// fast=false: sc0 sc1 (LLC, device-wide correct).
__device__ __forceinline__ i64t ld8x(const unsigned char* p, bool f) {
  i64t r;
  if (f) asm volatile("global_load_dwordx2 %0, %1, off sc0" : "=v"(r) : "v"(p));
  else   asm volatile("global_load_dwordx2 %0, %1, off sc0 sc1" : "=v"(r) : "v"(p));
  return r;
}
__device__ __forceinline__ void st8x(unsigned char* p, i64t v, bool f) {
  if (f) asm volatile("global_store_dwordx2 %0, %1, off sc0" :: "v"(p), "v"(v) : "memory");
  else   asm volatile("global_store_dwordx2 %0, %1, off sc0 sc1" :: "v"(p), "v"(v) : "memory");
}
__device__ __forceinline__ int ldflagx(const int* p, bool f) {
  int r;
  if (f) asm volatile("global_load_dword %0, %1, off sc0" : "=v"(r) : "v"(p));
  else   asm volatile("global_load_dword %0, %1, off sc0 sc1" : "=v"(r) : "v"(p));
  return r;
}
__device__ __forceinline__ void stflagx(int* p, int v, bool f) {
  if (f) asm volatile("global_store_dword %0, %1, off sc0" :: "v"(p), "v"(v) : "memory");
  else   asm volatile("global_store_dword %0, %1, off sc0 sc1" :: "v"(p), "v"(v) : "memory");
}
#define MFMA(a, b, c)  __builtin_amdgcn_mfma_f32_16x16x32_bf16(a, b, c, 0, 0, 0)
#define MFMA8(a, b, c) __builtin_amdgcn_mfma_f32_16x16x32_fp8_fp8(a, b, c, 0, 0, 0)

// ---------------------------------------------------------------------------
// Persistent char LSTM, FULL FP8 (r21-proven, FROZEN).
// ---------------------------------------------------------------------------
__global__ __launch_bounds__(512, 1) void char_lstm(
    const int* __restrict__ x, const unsigned char* __restrict__ emb8,
    const unsigned char* __restrict__ Wc8, const float* __restrict__ bcT,
    unsigned short* __restrict__ lastT, const int* __restrict__ len) {
  __shared__ unsigned char Hs8[2][64][264];
  __shared__ _Float16 Cs[256][66];
  __shared__ int lenS[64];
  const int tid = threadIdx.x;
  const int w = tid >> 6, l = tid & 63;
  const int l16 = l & 15, lk8 = (l >> 4) * 8, q = l >> 4;
  const int w0 = blockIdx.x * 64;
  if (tid < 64) lenS[tid] = len[w0 + tid];

  for (int t = 0; t < LC; ++t) {
    const int cur = t & 1, nxt = cur ^ 1;
    int xi[4];
#pragma unroll
    for (int wh = 0; wh < 4; ++wh) xi[wh] = x[(w0 + wh * 16 + l16) * LC + t];
#pragma unroll
    for (int c = 0; c < 2; ++c) {
      const int chg = w * 2 + c;
      const int cc0 = chg * 64;
      f32x4 acc[4][4] = {};
#pragma unroll
      for (int kk = 0; kk < 2; ++kk) {          // K 0..63: embedding (fp8)
        const int k = kk * 32 + lk8;
        const unsigned char* wp = Wc8 + (size_t)(cc0 + l16) * 320 + k;
        i64t bv8[4];
#pragma unroll
        for (int g = 0; g < 4; ++g)
          bv8[g] = *reinterpret_cast<const i64t*>(wp + g * 16 * 320);
#pragma unroll
        for (int wh = 0; wh < 4; ++wh) {
          i64t a8 = *reinterpret_cast<const i64t*>(emb8 + (size_t)xi[wh] * 64 + k);
#pragma unroll
          for (int g = 0; g < 4; ++g) acc[wh][g] = MFMA8(bv8[g], a8, acc[wh][g]);
        }
      }
      if (t > 0) {
#pragma unroll
        for (int kk = 2; kk < 10; ++kk) {       // K 64..319: h(t-1) fp8
          const int k = kk * 32 + lk8;
          const unsigned char* wp = Wc8 + (size_t)(cc0 + l16) * 320 + k;
          i64t bv8[4];
#pragma unroll
          for (int g = 0; g < 4; ++g)
            bv8[g] = *reinterpret_cast<const i64t*>(wp + g * 16 * 320);
#pragma unroll
          for (int wh = 0; wh < 4; ++wh) {
            i64t a8 = *reinterpret_cast<const i64t*>(&Hs8[cur][wh * 16 + l16][k - 64]);
#pragma unroll
            for (int g = 0; g < 4; ++g) acc[wh][g] = MFMA8(bv8[g], a8, acc[wh][g]);
          }
        }
      }
      float4 bb4[4];
#pragma unroll
      for (int e = 0; e < 4; ++e)
        bb4[e] = *reinterpret_cast<const float4*>(bcT + (chg * 16 + q * 4 + e) * 4);
      const int uoff = chg * 16 + q * 4;
#pragma unroll
      for (int wh = 0; wh < 4; ++wh) {
        const int wd = wh * 16 + l16;
        float hv[4];
#pragma unroll
        for (int e = 0; e < 4; ++e) {
          const int ug = chg * 16 + q * 4 + e;
          const float gi = acc[wh][0][e] + bb4[e].x;
          const float gf = acc[wh][1][e] + bb4[e].y;
          const float gg = acc[wh][2][e] + bb4[e].z;
          const float go = acc[wh][3][e] + bb4[e].w;
          const float cprev = t ? (float)Cs[ug][wd] : 0.f;
          const float ccv = fsig(gf) * cprev + fsig(gi) * ftanh(gg);
          Cs[ug][wd] = (_Float16)ccv;
          hv[e] = fsig(go) * ftanh(ccv);
        }
        const int d0 = __builtin_amdgcn_cvt_pk_fp8_f32(hv[0], hv[1], 0, false);
        const int d1 = __builtin_amdgcn_cvt_pk_fp8_f32(hv[2], hv[3], 0, false);
        const unsigned int pk = (unsigned int)(d0 & 0xFFFF) |
                                ((unsigned int)(d1 & 0xFFFF) << 16);
        *reinterpret_cast<unsigned int*>(&Hs8[nxt][wd][uoff]) = pk;
      }
    }
    __syncthreads();
    {
      const int wd = tid >> 3, sub = tid & 7;
      const int myl = lenS[wd];
      if (myl == t + 1 || (myl == 0 && t == 0)) {
        const int n = w0 + wd;
        const int lrow = ((n & 127) * 128 + (n >> 7)) * HC;
        if (myl == 0) {
          bf16x8 z = {};
#pragma unroll
          for (int j = 0; j < 4; ++j)
            *reinterpret_cast<bf16x8*>(lastT + lrow + sub * 32 + j * 8) = z;
        } else {
#pragma unroll
          for (int j = 0; j < 4; ++j) {
            unsigned int v0 = *reinterpret_cast<unsigned int*>(
                &Hs8[nxt][wd][sub * 32 + j * 8]);
            unsigned int v1 = *reinterpret_cast<unsigned int*>(
                &Hs8[nxt][wd][sub * 32 + j * 8 + 4]);
            union { unsigned short s[8]; bf16x8 v; } o;
#pragma unroll
            for (int b = 0; b < 4; ++b) {
              o.s[b]     = f2bu(fp8_to_f32((v0 >> (8 * b)) & 0xFF));
              o.s[4 + b] = f2bu(fp8_to_f32((v1 >> (8 * b)) & 0xFF));
            }
            *reinterpret_cast<bf16x8*>(lastT + lrow + sub * 32 + j * 8) = o.v;
          }
        }
      }
    }
  }
}

// ---------------------------------------------------------------------------
// Persistent word BiLSTM, XCD-pinned + 512 THREADS (8 waves = 2 waves/SIMD):
// each wave owns 16 batches (one A-fragment) -> per-wave MFMA/LDS-read serial
// work halved and MFMA/ds_read co-schedule across waves. 256 blocks launched,
// only bx%8<2 active (one XCD per dir); runtime negotiation picks sc0-only
// (XCD L2) vs sc0sc1 (LLC) exchange.
// ---------------------------------------------------------------------------
__global__ __launch_bounds__(512, 1) void word_lstm(
    const unsigned short* __restrict__ lastT,   // [pos][128][HC] bf16
    const unsigned short* __restrict__ W16,     // bf16 gate-major x-part (fwd)
    const unsigned short* __restrict__ W16b,    // (bwd)
    const unsigned char* __restrict__ W8f,      // fp8 gate-major h-part (fwd)
    const unsigned char* __restrict__ W8b,      // (bwd)
    const float* __restrict__ bfi, const float* __restrict__ bbi,
    unsigned char* __restrict__ hbL8,   // [2][2][32][128][16] fp8
    unsigned short* __restrict__ hsW,   // [2][32][128 pos][128 b][16] bf16
    int* __restrict__ aflag) {          // [2][SEQ][32][FPAD] + negotiation tail
  const int bx = blockIdx.x;
  if ((bx & 7) > 1) return;             // 192 idle blocks exit
  __shared__ unsigned short Wlds16[64 * 256];   // 32 KB x-part bf16
  __shared__ unsigned char  Wlds8[64 * 512];    // 32 KB h-part fp8
  __shared__ unsigned short ht[128][24];        // 6 KB bf16 transpose
  __shared__ unsigned char  ht8[128][24];       // 3 KB fp8 transpose
  __shared__ int fastS;
  const int tid = threadIdx.x;
  const int w = tid >> 6, l = tid & 63;         // w 0..7
  const int l16 = l & 15, lk8 = (l >> 4) * 8, q = l >> 4;
  const int dir = bx & 7;               // 0 fwd, 1 bwd
  const int nb = bx >> 3;               // 0..31
  const int c0 = nb * 64;
  const unsigned short* Wx = dir ? W16b : W16;
  const unsigned char*  Wh = dir ? W8b : W8f;
  const float* bias = dir ? bbi : bfi;
  // ---- XCD negotiation (one-time) ----
  int* negcnt = aflag + (size_t)2 * SEQ * 32 * FPAD;   // [0]; xcnt at +16
  if (tid == 0) {
    const int xcc = __builtin_amdgcn_s_getreg(20 | (31 << 11)) & 7;  // HW_REG_XCC_ID
    int* xc = negcnt + 16 + dir * 8 + xcc;
    __hip_atomic_fetch_add(xc, 1, __ATOMIC_RELAXED, __HIP_MEMORY_SCOPE_AGENT);
    __hip_atomic_fetch_add(negcnt, 1, __ATOMIC_RELAXED, __HIP_MEMORY_SCOPE_AGENT);
    while (__hip_atomic_load(negcnt, __ATOMIC_RELAXED, __HIP_MEMORY_SCOPE_AGENT) < 64)
      __builtin_amdgcn_s_sleep(2);
    fastS = (__hip_atomic_load(xc, __ATOMIC_RELAXED, __HIP_MEMORY_SCOPE_AGENT) == 32);
  }
  // ---- stage weights into LDS (512 threads) ----
  for (int ci = tid; ci < 64 * 32; ci += 512) {
    const int col = ci >> 5, kc = (ci & 31) * 8;
    const int kcs = kc ^ ((col & 15) * 8);
    *reinterpret_cast<bf16x8*>(&Wlds16[col * 256 + kcs]) =
        ld8(Wx + (size_t)(c0 + col) * 256 + kc);
  }
  for (int ci = tid; ci < 64 * 64; ci += 512) {
    const int col = ci >> 6, kb = (ci & 63) * 8;
    const int kbs = kb ^ ((col & 15) * 8);
    *reinterpret_cast<i64t*>(&Wlds8[col * 512 + kbs]) =
        *reinterpret_cast<const i64t*>(Wh + (size_t)(c0 + col) * 512 + kb);
  }
  const float b0 = bias[c0 + 0 * 16 + l16];
  const float b1 = bias[c0 + 1 * 16 + l16];
  const float b2 = bias[c0 + 2 * 16 + l16];
  const float b3 = bias[c0 + 3 * 16 + l16];
  const int ksw = l16 * 8;
  float cst[4];                         // 4 batches per thread
#pragma unroll
  for (int i = 0; i < 4; ++i) cst[i] = 0.f;
  __syncthreads();                      // Wlds + fastS ready
  const bool fast = (fastS != 0);
  const int bt = w * 16 + l16;          // wave's batch fragment row

  for (int t = 0; t < SEQ; ++t) {
    const int cur = t & 1;
    const int pos = dir ? (SEQ - 1 - t) : t;
    // ---- x-part: plain cached lastT loads, bf16 MFMA (32/wave) ----
    f32x4 acc[4] = {};
#pragma unroll
    for (int kk = 0; kk < 8; ++kk) {
      const int k = kk * 32 + lk8;
      bf16x8 a0 = ld8(lastT + ((size_t)pos * 128 + bt) * HC + k);
      const int ks = k ^ ksw;
#pragma unroll
      for (int nn = 0; nn < 4; ++nn) {
        bf16x8 bv = ld8(&Wlds16[(l16 + nn * 16) * 256 + ks]);
        acc[nn] = MFMA(a0, bv, acc[nn]);
      }
    }
    if (t > 0) {
      if (w == 0) {                      // flag-barrier wait for step t-1
        const int* fp = aflag + (size_t)(dir * SEQ + (t - 1)) * 32 * FPAD;
        for (;;) {
          int v = 1;
          if (l < 32) v = ldflagx(fp + l * FPAD, fast);
          if (__ballot(v != 0) == ~0ull) break;
          __builtin_amdgcn_s_sleep(1);
        }
      }
      __syncthreads();
      // ---- h loads (fp8, scope-matched) + fp8 MFMA (64/wave) ----
      i64t af8[16];
      const unsigned char* hp =
          hbL8 + (size_t)(((cur ^ 1) * 2 + dir) * 32) * 128 * 16;
#pragma unroll
      for (int kk = 0; kk < 16; ++kk) {
        const int u = kk * 32 + lk8;
        const int nbs = u >> 4, ul = u & 15;
        af8[kk] = ld8x(hp + ((size_t)nbs * 128 + bt) * 16 + ul, fast);
      }
      asm volatile("s_waitcnt vmcnt(0)" ::: "memory");
      __builtin_amdgcn_sched_barrier(0);   // rule #18
#pragma unroll
      for (int kk = 0; kk < 16; ++kk) {
        const int ks8 = (kk * 32 + lk8) ^ ksw;
#pragma unroll
        for (int nn = 0; nn < 4; ++nn) {
          i64t w8 = *reinterpret_cast<const i64t*>(
              &Wlds8[(l16 + nn * 16) * 512 + ks8]);
          acc[nn] = MFMA8(af8[kk], w8, acc[nn]);
        }
      }
    }
    // ---- in-register LSTM update (thread: unit nb*16+l16, 4 batches) ----
    float hvf[4];
    int bats[4];
#pragma unroll
    for (int e = 0; e < 4; ++e) {
      const float gi = acc[0][e] + b0;
      const float gf = acc[1][e] + b1;
      const float gg = acc[2][e] + b2;
      const float go = acc[3][e] + b3;
      const float ccv = fsig(gf) * cst[e] + fsig(gi) * ftanh(gg);
      cst[e] = ccv;
      const float hv = fsig(go) * ftanh(ccv);
      const int bat = w * 16 + q * 4 + e;       // 0..127
      ht[bat][l16] = f2bu(hv);
      hvf[e] = hv; bats[e] = bat;
    }
    {
      const int d0 = __builtin_amdgcn_cvt_pk_fp8_f32(hvf[0], hvf[1], 0, false);
      const int d1 = __builtin_amdgcn_cvt_pk_fp8_f32(hvf[2], hvf[3], 0, false);
      ht8[bats[0]][l16] = (unsigned char)(d0 & 255);
      ht8[bats[1]][l16] = (unsigned char)((d0 >> 8) & 255);
      ht8[bats[2]][l16] = (unsigned char)(d1 & 255);
      ht8[bats[3]][l16] = (unsigned char)((d1 >> 8) & 255);
    }
    __syncthreads();
    // ---- coalesced write-back (256 threads); hbL8 -> drain -> flag ----
    if (tid < 256) {
      const int ub = tid >> 1, uh = tid & 1;
      i64t hv8 = *reinterpret_cast<const i64t*>(&ht8[ub][uh * 8]);
      st8x(hbL8 + (size_t)((cur * 2 + dir) * 32 + nb) * 128 * 16
               + ub * 16 + uh * 8, hv8, fast);
    }
    if (t < SEQ - 1) {
      asm volatile("s_waitcnt vmcnt(0)" ::: "memory");
      __syncthreads();
      if (tid == 0)
        stflagx(aflag + ((size_t)(dir * SEQ + t) * 32 + nb) * FPAD, 1, fast);
    }
    // hsW store AFTER the flag: off the cross-block critical chain
    if (tid < 256) {
      const int ub = tid >> 1, uh = tid & 1;
      bf16x8 hv = ld8(&ht[ub][uh * 8]);
      *reinterpret_cast<bf16x8*>(
          hsW + (((size_t)(dir * 32 + nb) * 128 + pos) * 128 + ub) * 16 + uh * 8) = hv;
    }
  }
}

// ---------------------------------------------------------------------------
// MLP layer 1 (frozen)
// ---------------------------------------------------------------------------
__global__ __launch_bounds__(256) void mlp1_gemm(
    const unsigned short* __restrict__ hsW, const unsigned short* __restrict__ W1b,
    const float* __restrict__ bias, unsigned short* __restrict__ out) {
  const int tid = threadIdx.x;
  const int w = tid >> 6, l = tid & 63;
  const int l16 = l & 15, lk8 = (l >> 4) * 8;
  const int by = blockIdx.y;
  const int row0 = by * 128 + w * 32;
  const int col0 = blockIdx.x * 64;
  f32x4 acc[2][4] = {};
  for (int kk = 0; kk < 32; ++kk) {
    const int k = kk * 32 + lk8;
    const int dirk = k >> 9, u = k & 511, nbs = u >> 4, ul = u & 15;
    const int p0 = w * 32 + l16, p1 = p0 + 16;
    bf16x8 a0 = ld8(hsW + (((size_t)(dirk * 32 + nbs) * 128 + p0) * 128 + by) * 16 + ul);
    bf16x8 a1 = ld8(hsW + (((size_t)(dirk * 32 + nbs) * 128 + p1) * 128 + by) * 16 + ul);
    const unsigned short* wp = W1b + (size_t)(col0 + l16) * 1024 + k;
#pragma unroll
    for (int nn = 0; nn < 4; ++nn) {
      bf16x8 bv = ld8(wp + nn * 16 * 1024);
      acc[0][nn] = MFMA(a0, bv, acc[0][nn]);
      acc[1][nn] = MFMA(a1, bv, acc[1][nn]);
    }
  }
  const int cr = (l >> 4) * 4;
#pragma unroll
  for (int m = 0; m < 2; ++m)
#pragma unroll
    for (int nn = 0; nn < 4; ++nn)
#pragma unroll
      for (int e = 0; e < 4; ++e) {
        const int r = row0 + m * 16 + cr + e;
        const int c = col0 + nn * 16 + l16;
        out[(size_t)r * 256 + c] = f2bu(fmaxf(acc[m][nn][e] + bias[c], 0.f));
      }
}

// ---------------------------------------------------------------------------
// MLP layer 2 (frozen)
// ---------------------------------------------------------------------------
__global__ __launch_bounds__(256) void mlp_gemm(
    const unsigned short* __restrict__ A, int lda,
    const unsigned short* __restrict__ W, int ldw,
    const float* __restrict__ bias, unsigned short* __restrict__ out,
    int ldo, int nk, int relu) {
  const int tid = threadIdx.x;
  const int w = tid >> 6, l = tid & 63;
  const int l16 = l & 15, lk8 = (l >> 4) * 8;
  const int row0 = blockIdx.y * 128 + w * 32;
  const int col0 = blockIdx.x * 64;
  f32x4 acc[2][4] = {};
  for (int kk = 0; kk < nk; ++kk) {
    const int k = kk * 32 + lk8;
    bf16x8 a0 = ld8(A + (size_t)(row0 + l16) * lda + k);
    bf16x8 a1 = ld8(A + (size_t)(row0 + 16 + l16) * lda + k);
    const unsigned short* wp = W + (size_t)(col0 + l16) * ldw + k;
    bf16x8 bb[4];
#pragma unroll
    for (int nn = 0; nn < 4; ++nn) bb[nn] = ld8(wp + nn * 16 * ldw);
#pragma unroll
    for (int nn = 0; nn < 4; ++nn) {
      acc[0][nn] = MFMA(a0, bb[nn], acc[0][nn]);
      acc[1][nn] = MFMA(a1, bb[nn], acc[1][nn]);
    }
  }
  const int cr = (l >> 4) * 4;
#pragma unroll
  for (int m = 0; m < 2; ++m)
#pragma unroll
    for (int nn = 0; nn < 4; ++nn)
#pragma unroll
      for (int e = 0; e < 4; ++e) {
        const int r = row0 + m * 16 + cr + e;
        const int c = col0 + nn * 16 + l16;
        float v = acc[m][nn][e] + bias[c];
        if (relu) v = fmaxf(v, 0.f);
        out[(size_t)r * ldo + c] = f2bu(v);
      }
}

// ---------------------------------------------------------------------------
// Logits + log_softmax (frozen)
// ---------------------------------------------------------------------------
__global__ __launch_bounds__(256) void logits_fused(
    const unsigned short* __restrict__ h2, const unsigned short* __restrict__ W3p,
    const float* __restrict__ b3, float* __restrict__ out) {
  __shared__ float gt[128][68];
  __shared__ float lseb[128];
  const int tid = threadIdx.x;
  const int w = tid >> 6, l = tid & 63;
  const int l16 = l & 15, lk8 = (l >> 4) * 8;
  const int r0 = blockIdx.x * 128;
  const int rr0 = w * 32 + l16, rr1 = rr0 + 16;
  f32x4 acc[2][4] = {};
#pragma unroll
  for (int kk = 0; kk < 8; ++kk) {
    const int k = kk * 32 + lk8;
    bf16x8 a0 = ld8(h2 + (size_t)(r0 + rr0) * 256 + k);
    bf16x8 a1 = ld8(h2 + (size_t)(r0 + rr1) * 256 + k);
#pragma unroll
    for (int nn = 0; nn < 4; ++nn) {
      bf16x8 bv = ld8(W3p + (size_t)(nn * 16 + l16) * 256 + k);
      acc[0][nn] = MFMA(a0, bv, acc[0][nn]);
      acc[1][nn] = MFMA(a1, bv, acc[1][nn]);
    }
  }
  const int cr = (l >> 4) * 4;
#pragma unroll
  for (int m = 0; m < 2; ++m)
#pragma unroll
    for (int nn = 0; nn < 4; ++nn)
#pragma unroll
      for (int e = 0; e < 4; ++e) {
        const int col = nn * 16 + l16;
        gt[w * 32 + m * 16 + cr + e][col] =
            acc[m][nn][e] + (col < NOUT ? b3[col] : 0.f);
      }
  __syncthreads();
  if (tid < 128) {
    float mx = -INFINITY;
#pragma unroll
    for (int j = 0; j < NOUT; ++j) mx = fmaxf(mx, gt[tid][j]);
    float s = 0.f;
#pragma unroll
    for (int j = 0; j < NOUT; ++j) s += fex2(LOG2E * (gt[tid][j] - mx));
    lseb[tid] = flog2(s) * 0.6931471805599453f + mx;
  }
  __syncthreads();
  for (int idx = tid; idx < 128 * NOUT; idx += 256) {
    const int r = idx / NOUT, j = idx - r * NOUT;
    out[(size_t)(r0 + r) * NOUT + j] = gt[r][j] - lseb[r];
  }
}

// ---------------------------------------------------------------------------
// Prep kernels
// ---------------------------------------------------------------------------
__global__ void prep_wx(const float* __restrict__ ih, unsigned short* __restrict__ dst,
                        int HU, int KI) {
  const long tot = (long)HU * 4 * KI;
  for (long idx = (long)blockIdx.x * blockDim.x + threadIdx.x; idx < tot;
       idx += (long)gridDim.x * blockDim.x) {
    const int row = (int)(idx / KI), k = (int)(idx % KI);
    const int chunk = row >> 6, c = row & 63;
    const int g = c >> 4, u = chunk * 16 + (c & 15);
    dst[idx] = f2bu(ih[(size_t)(g * HU + u) * KI + k]);
  }
}

__global__ void prep_wc8(const float* __restrict__ ih, const float* __restrict__ hh,
                         unsigned char* __restrict__ dst, int HU, int KI, int KH) {
  const int K = KI + KH;
  const long tot = (long)HU * 4 * (K / 2);
  for (long p = (long)blockIdx.x * blockDim.x + threadIdx.x; p < tot;
       p += (long)gridDim.x * blockDim.x) {
    const int row = (int)(p / (K / 2)), kp = (int)(p % (K / 2)) * 2;
    const int chunk = row >> 6, c = row & 63;
    const int g = c >> 4, u = chunk * 16 + (c & 15);
    const float a = (kp < KI) ? ih[(size_t)(g * HU + u) * KI + kp]
                              : hh[(size_t)(g * HU + u) * KH + (kp - KI)];
    const float b = (kp + 1 < KI) ? ih[(size_t)(g * HU + u) * KI + kp + 1]
                                  : hh[(size_t)(g * HU + u) * KH + (kp + 1 - KI)];
    const int d = __builtin_amdgcn_cvt_pk_fp8_f32(a, b, 0, false);
    *reinterpret_cast<unsigned short*>(dst + (size_t)row * K + kp) =
        (unsigned short)(d & 0xFFFF);
  }
}

__global__ void prep_w8(const float* __restrict__ hh, unsigned char* __restrict__ dst,
                        int HU, int KH) {
  const long tot = (long)HU * 4 * (KH / 2);
  for (long p = (long)blockIdx.x * blockDim.x + threadIdx.x; p < tot;
       p += (long)gridDim.x * blockDim.x) {
    const int row = (int)(p / (KH / 2)), kp = (int)(p % (KH / 2)) * 2;
    const int chunk = row >> 6, c = row & 63;
    const int g = c >> 4, u = chunk * 16 + (c & 15);
    const float a = hh[(size_t)(g * HU + u) * KH + kp];
    const float b = hh[(size_t)(g * HU + u) * KH + kp + 1];
    const int d = __builtin_amdgcn_cvt_pk_fp8_f32(a, b, 0, false);
    *reinterpret_cast<unsigned short*>(dst + (size_t)row * KH + kp) =
        (unsigned short)(d & 0xFFFF);
  }
}

__global__ void prep_bias(const float* bih, const float* bhh, float* dst, int HU) {
  const int idx = blockIdx.x * blockDim.x + threadIdx.x;
  if (idx < 4 * HU) {
    const int chunk = idx >> 6, c = idx & 63;
    const int g = c >> 4, u = chunk * 16 + (c & 15);
    dst[idx] = bih[g * HU + u] + bhh[g * HU + u];
  }
}

__global__ void prep_biasT(const float* bih, const float* bhh, float* dst, int HU) {
  const int idx = blockIdx.x * blockDim.x + threadIdx.x;
  if (idx < 4 * HU) {
    const int u = idx >> 2, g = idx & 3;
    dst[idx] = bih[g * HU + u] + bhh[g * HU + u];
  }
}

__global__ void conv_bf(const float* __restrict__ src, unsigned short* __restrict__ dst,
                        long n) {
  for (long i = (long)blockIdx.x * blockDim.x + threadIdx.x; i < n;
       i += (long)gridDim.x * blockDim.x)
    dst[i] = f2bu(src[i]);
}

__global__ void conv_fp8(const float* __restrict__ src, unsigned char* __restrict__ dst,
                         long n2) {
  for (long i = (long)blockIdx.x * blockDim.x + threadIdx.x; i < n2;
       i += (long)gridDim.x * blockDim.x) {
    const int d = __builtin_amdgcn_cvt_pk_fp8_f32(src[i * 2], src[i * 2 + 1], 0, false);
    *reinterpret_cast<unsigned short*>(dst + i * 2) = (unsigned short)(d & 0xFFFF);
  }
}

__global__ void prep_w3(const float* __restrict__ W3, unsigned short* __restrict__ dst) {
  const int i = blockIdx.x * blockDim.x + threadIdx.x;
  if (i < 64 * 256) {
    const int r = i >> 8;
    dst[i] = (r < NOUT) ? f2bu(W3[i]) : 0;
  }
}

__global__ void lengths_k(const int* x, int* len) {
  const int n = blockIdx.x * blockDim.x + threadIdx.x;
  if (n < NW) {
    int c = 0;
#pragma unroll
    for (int l = 0; l < LC; ++l) c += (x[(size_t)n * LC + l] != 0) ? 1 : 0;
    len[n] = c;
  }
}

__global__ void zero_k(int* p, int n) {
  const int i = blockIdx.x * blockDim.x + threadIdx.x;
  if (i < n) p[i] = 0;
}

__global__ void sentinel_k(float* out, int n) {
  const int i = blockIdx.x * blockDim.x + threadIdx.x;
  if (i < n) out[i] = 1000.0f;
}

// ---------------------------------------------------------------------------
extern "C" void kernel_launch(void* const* d_in, const int* in_sizes, int n_in,
                              void* d_out, int out_size, void* d_ws, size_t ws_size,
                              hipStream_t stream) {
  const int*   x     = (const int*)d_in[0];
  const float* emb   = (const float*)d_in[1];
  const float* cW_ih = (const float*)d_in[2];
  const float* cW_hh = (const float*)d_in[3];
  const float* cb_ih = (const float*)d_in[4];
  const float* cb_hh = (const float*)d_in[5];
  const float* fW_ih = (const float*)d_in[6];
  const float* fW_hh = (const float*)d_in[7];
  const float* fb_ih = (const float*)d_in[8];
  const float* fb_hh = (const float*)d_in[9];
  const float* bW_ih = (const float*)d_in[10];
  const float* bW_hh = (const float*)d_in[11];
  const float* bb_ih = (const float*)d_in[12];
  const float* bb_hh = (const float*)d_in[13];
  const float* W1 = (const float*)d_in[14];
  const float* b1 = (const float*)d_in[15];
  const float* W2 = (const float*)d_in[16];
  const float* b2 = (const float*)d_in[17];
  const float* W3 = (const float*)d_in[18];
  const float* b3 = (const float*)d_in[19];
  float* out = (float*)d_out;
  (void)in_sizes; (void)n_in;

  char* ws = (char*)d_ws;
  size_t off = 0;
  auto alloc = [&](size_t bytes) -> char* {
    char* p = ws + off;
    off += (bytes + 255) & ~(size_t)255;
    return p;
  };
  const int NFLAG = 2 * SEQ * 32 * FPAD + 32;   // flags + negotiation tail
  int*            len_  = (int*)alloc((size_t)NW * 4);
  int*            aflag = (int*)alloc((size_t)NFLAG * 4);
  unsigned char*  emb8  = (unsigned char*)alloc((size_t)100 * EDIM);
  unsigned char*  Wc8   = (unsigned char*)alloc((size_t)1024 * 320);
  unsigned short* Wf_i  = (unsigned short*)alloc((size_t)2048 * 256 * 2);
  unsigned short* Wb_i  = (unsigned short*)alloc((size_t)2048 * 256 * 2);
  unsigned char*  Wf8   = (unsigned char*)alloc((size_t)2048 * 512);
  unsigned char*  Wb8   = (unsigned char*)alloc((size_t)2048 * 512);
  unsigned short* W1b   = (unsigned short*)alloc((size_t)256 * 1024 * 2);
  unsigned short* W2b   = (unsigned short*)alloc((size_t)256 * 256 * 2);
  unsigned short* W3p   = (unsigned short*)alloc((size_t)64 * 256 * 2);
  float*          bcT   = (float*)alloc(1024 * 4);
  float*          bf_i  = (float*)alloc(2048 * 4);
  float*          bb_i  = (float*)alloc(2048 * 4);
  unsigned short* lastT = (unsigned short*)alloc((size_t)NW * HC * 2);       // 8MB
  unsigned char*  hbL8  = (unsigned char*)alloc((size_t)2 * 2 * 32 * 128 * 16);
  unsigned short* hsW   = (unsigned short*)alloc((size_t)2 * 32 * 128 * 128 * 16 * 2);
  unsigned short* h1    = (unsigned short*)alloc((size_t)NW * HC * 2);       // 8MB
  unsigned short* h2    = (unsigned short*)alloc((size_t)NW * HC * 2);       // 8MB

  if (off > ws_size) {
    sentinel_k<<<(out_size + 255) / 256, 256, 0, stream>>>(out, out_size);
    return;
  }

  auto cdiv = [](long a, long b) { return (int)((a + b - 1) / b); };

  // ---- prep ----
  prep_wc8<<<640, 256, 0, stream>>>(cW_ih, cW_hh, Wc8, HC, EDIM, HC);
  prep_wx<<<1024, 256, 0, stream>>>(fW_ih, Wf_i, HW, HC);
  prep_wx<<<1024, 256, 0, stream>>>(bW_ih, Wb_i, HW, HC);
  prep_w8<<<2048, 256, 0, stream>>>(fW_hh, Wf8, HW, HW);
  prep_w8<<<2048, 256, 0, stream>>>(bW_hh, Wb8, HW, HW);
  prep_biasT<<<cdiv(1024, 256), 256, 0, stream>>>(cb_ih, cb_hh, bcT, HC);
  prep_bias<<<cdiv(2048, 256), 256, 0, stream>>>(fb_ih, fb_hh, bf_i, HW);
  prep_bias<<<cdiv(2048, 256), 256, 0, stream>>>(bb_ih, bb_hh, bb_i, HW);
  conv_fp8<<<13, 256, 0, stream>>>(emb, emb8, 100L * EDIM / 2);
  conv_bf<<<1024, 256, 0, stream>>>(W1, W1b, 256L * 1024);
  conv_bf<<<256, 256, 0, stream>>>(W2, W2b, 256L * 256);
  prep_w3<<<64, 256, 0, stream>>>(W3, W3p);
  lengths_k<<<cdiv(NW, 256), 256, 0, stream>>>(x, len_);
  zero_k<<<cdiv(NFLAG, 256), 256, 0, stream>>>(aflag, NFLAG);

  // ---- persistent char LSTM (1 launch, full-fp8) ----
  char_lstm<<<NW / 64, 512, 0, stream>>>(x, emb8, Wc8, bcT, lastT, len_);

  // ---- persistent word BiLSTM (256 blocks x 512 thr, XCD-pinned) ----
  word_lstm<<<256, 512, 0, stream>>>(lastT, Wf_i, Wb_i, Wf8, Wb8, bf_i, bb_i,
                                     hbL8, hsW, aflag);

  // ---- MLP + fused logits/log_softmax ----
  mlp1_gemm<<<dim3(4, 128), 256, 0, stream>>>(hsW, W1b, b1, h1);
  mlp_gemm<<<dim3(4, 128), 256, 0, stream>>>(h1, 256, W2b, 256, b2, h2, 256, 8, 1);
  logits_fused<<<NW / 128, 256, 0, stream>>>(h2, W3p, b3, out);
}